// Round 2
// baseline (1549.797 us; speedup 1.0000x reference)
//
#include <hip/hip_runtime.h>
#include <cstdint>
#include <cstddef>

#define SL 2048
#define BS 2
#define NH 32
#define HD 128
#define HS 4096
#define NTOK 4096  // BS*SL

typedef __attribute__((ext_vector_type(8))) short short8;
typedef __attribute__((ext_vector_type(4))) float f32x4;
typedef __attribute__((ext_vector_type(4))) unsigned short u16x4;
typedef __attribute__((ext_vector_type(8))) unsigned short u16x8;

static __device__ __forceinline__ unsigned short f2bf(float f) {
    unsigned int u = __builtin_bit_cast(unsigned int, f);
    u = u + 0x7FFFu + ((u >> 16) & 1u);   // RNE
    return (unsigned short)(u >> 16);
}
static __device__ __forceinline__ float bf2f(unsigned short h) {
    unsigned int u = ((unsigned int)h) << 16;
    return __builtin_bit_cast(float, u);
}

static __device__ __forceinline__ f32x4 mfma16(short8 a, short8 b, f32x4 c) {
    return __builtin_amdgcn_mfma_f32_16x16x32_bf16(a, b, c, 0, 0, 0);
}

static __device__ __forceinline__ void gload_lds16(const void* g, void* dst) {
    __builtin_amdgcn_global_load_lds(
        (const __attribute__((address_space(1))) unsigned int*)g,
        (__attribute__((address_space(3))) unsigned int*)dst,
        16, 0, 0);
}

// ---------------- fp32 -> bf16 convert (X) ----------------
__global__ void k_convert(const float* __restrict__ in, unsigned short* __restrict__ out, int n8) {
    int stride = gridDim.x * blockDim.x;
    for (int i = blockIdx.x * blockDim.x + threadIdx.x; i < n8; i += stride) {
        const f32x4* p = (const f32x4*)in + (size_t)i * 2;
        f32x4 a = p[0], b = p[1];
        u16x8 o;
        o[0] = f2bf(a[0]); o[1] = f2bf(a[1]); o[2] = f2bf(a[2]); o[3] = f2bf(a[3]);
        o[4] = f2bf(b[0]); o[5] = f2bf(b[1]); o[6] = f2bf(b[2]); o[7] = f2bf(b[3]);
        *((u16x8*)out + i) = o;
    }
}

// ---------------- fp32 W[k][n] -> bf16 Wt[n][k] ----------------
__global__ void k_transpose_w(const float* __restrict__ w, unsigned short* __restrict__ wt) {
    __shared__ float t[32][33];
    int r0 = blockIdx.y << 5, c0 = blockIdx.x << 5;
    int tr = threadIdx.x >> 3;
    int tc = (threadIdx.x & 7) << 2;
    f32x4 v = *(const f32x4*)(w + (size_t)(r0 + tr) * HS + c0 + tc);
    t[tr][tc + 0] = v[0]; t[tr][tc + 1] = v[1]; t[tr][tc + 2] = v[2]; t[tr][tc + 3] = v[3];
    __syncthreads();
    u16x4 o;
    o[0] = f2bf(t[tc + 0][tr]); o[1] = f2bf(t[tc + 1][tr]);
    o[2] = f2bf(t[tc + 2][tr]); o[3] = f2bf(t[tc + 3][tr]);
    *(u16x4*)(wt + (size_t)(c0 + tr) * HS + r0 + tc) = o;
}

// ---------------- bf16 GEMM: C[M][N] = A[M][K] * Bt[N][K]^T ----------------
template <typename OutT>
__global__ __launch_bounds__(256) void k_gemm(
    const unsigned short* __restrict__ A,
    const unsigned short* __restrict__ Bt,
    OutT* __restrict__ C,
    int M, int N, int K)
{
    __shared__ unsigned short As[128 * 32];
    __shared__ unsigned short Bs[128 * 32];
    int tiles_n = N >> 7;
    int tm = blockIdx.x / tiles_n, tn = blockIdx.x % tiles_n;
    int tid = threadIdx.x;
    int lane = tid & 63, wave = tid >> 6;
    int wr = wave >> 1, wc = wave & 1;
    int l15 = lane & 15, kh = lane >> 4;
    f32x4 acc[4][4] = {};
    int row0 = tm << 7, col0 = tn << 7;
    int srow = tid >> 2, scg = (tid & 3) << 3;
    const unsigned short* Abase = A + (size_t)(row0 + srow) * K + scg;
    const unsigned short* Bbase = Bt + (size_t)(col0 + srow) * K + scg;
    char* AsW = (char*)As + (wave << 10);
    char* BsW = (char*)Bs + (wave << 10);
    for (int k0 = 0; k0 < K; k0 += 32) {
        gload_lds16(Abase + k0, AsW);
        gload_lds16(Abase + (size_t)64 * K + k0, AsW + 4096);
        gload_lds16(Bbase + k0, BsW);
        gload_lds16(Bbase + (size_t)64 * K + k0, BsW + 4096);
        __syncthreads();
        short8 af[4], bfr[4];
        #pragma unroll
        for (int i = 0; i < 4; i++) af[i] = *(const short8*)(As + (wr * 64 + i * 16 + l15) * 32 + kh * 8);
        #pragma unroll
        for (int j = 0; j < 4; j++) bfr[j] = *(const short8*)(Bs + (wc * 64 + j * 16 + l15) * 32 + kh * 8);
        #pragma unroll
        for (int i = 0; i < 4; i++)
            #pragma unroll
            for (int j = 0; j < 4; j++)
                acc[i][j] = mfma16(af[i], bfr[j], acc[i][j]);
        __syncthreads();
    }
    #pragma unroll
    for (int i = 0; i < 4; i++)
        #pragma unroll
        for (int j = 0; j < 4; j++)
            #pragma unroll
            for (int r = 0; r < 4; r++) {
                int row = row0 + wr * 64 + i * 16 + kh * 4 + r;
                int col = col0 + wc * 64 + j * 16 + l15;
                float v = acc[i][j][r];
                if constexpr (sizeof(OutT) == 2) C[(size_t)row * N + col] = (OutT)f2bf(v);
                else                             C[(size_t)row * N + col] = v;
            }
}

// ---------------- RoPE on Q (pre-scaled by 1/sqrt(hd)) and K in place ----------------
__global__ void k_rope(unsigned short* __restrict__ Q, unsigned short* __restrict__ K) {
    const float SCALE = 0.08838834764831845f;  // 1/sqrt(128)
    int i = blockIdx.x * blockDim.x + threadIdx.x;  // quad index, grid exact
    int q4 = i & 15;
    int head = (i >> 4) & (NH - 1);
    int tok = i >> 9;
    int s = tok & (SL - 1);
    int d0 = q4 << 2;
    size_t base = (size_t)tok * HS + head * HD;
    float cs[4], sn[4];
    #pragma unroll
    for (int j = 0; j < 4; j++) {
        float invf = expf(-(float)(d0 + j) * 0.14391156831212787f);  // ln(1e4)/64
        float ang = (float)s * invf;
        sn[j] = sinf(ang); cs[j] = cosf(ang);
    }
    {
        u16x4 lo = *(u16x4*)(Q + base + d0);
        u16x4 hi = *(u16x4*)(Q + base + d0 + 64);
        u16x4 nlo, nhi;
        #pragma unroll
        for (int j = 0; j < 4; j++) {
            float x0 = bf2f(lo[j]), x1 = bf2f(hi[j]);
            nlo[j] = f2bf((x0 * cs[j] - x1 * sn[j]) * SCALE);
            nhi[j] = f2bf((x1 * cs[j] + x0 * sn[j]) * SCALE);
        }
        *(u16x4*)(Q + base + d0) = nlo;
        *(u16x4*)(Q + base + d0 + 64) = nhi;
    }
    {
        u16x4 lo = *(u16x4*)(K + base + d0);
        u16x4 hi = *(u16x4*)(K + base + d0 + 64);
        u16x4 nlo, nhi;
        #pragma unroll
        for (int j = 0; j < 4; j++) {
            float x0 = bf2f(lo[j]), x1 = bf2f(hi[j]);
            nlo[j] = f2bf(x0 * cs[j] - x1 * sn[j]);
            nhi[j] = f2bf(x1 * cs[j] + x0 * sn[j]);
        }
        *(u16x4*)(K + base + d0) = nlo;
        *(u16x4*)(K + base + d0 + 64) = nhi;
    }
}

// ---------------- V (tok, h*128+d) -> Vt ((b,h), d, s) ----------------
__global__ void k_transpose_v(const unsigned short* __restrict__ V, unsigned short* __restrict__ Vt) {
    __shared__ unsigned short t[32][36];
    int bh = blockIdx.z; int b = bh >> 5, h = bh & 31;
    int s0 = blockIdx.x << 5, d0 = blockIdx.y << 5;
    int tr = threadIdx.x >> 3, tc = (threadIdx.x & 7) << 2;
    u16x4 v = *(const u16x4*)(V + (size_t)(b * SL + s0 + tr) * HS + h * HD + d0 + tc);
    t[tr][tc + 0] = v[0]; t[tr][tc + 1] = v[1]; t[tr][tc + 2] = v[2]; t[tr][tc + 3] = v[3];
    __syncthreads();
    u16x4 o;
    o[0] = t[tc + 0][tr]; o[1] = t[tc + 1][tr]; o[2] = t[tc + 2][tr]; o[3] = t[tc + 3][tr];
    *(u16x4*)(Vt + ((size_t)(b * NH + h) * HD + d0 + tr) * SL + s0 + tc) = o;
}

// ---------------- causal flash attention v2 ----------------
// 4 waves x 32 q-rows (QBLK=128), KVBLK=64. K double-buffered in LDS
// (async stage, counted vmcnt). V read direct from global (L2-resident).
__global__ __launch_bounds__(256) void k_attn(
    const unsigned short* __restrict__ Q,
    const unsigned short* __restrict__ Kb,
    const unsigned short* __restrict__ Vt,
    unsigned short* __restrict__ O)
{
    __shared__ unsigned short Ks[2][64 * 128];  // [buf][kk][d], chunk-swizzled
    __shared__ unsigned short Ps[4][32][72];    // per-wave P, [qrow][kcol], padded (144B rows)
    int qt = (int)(gridDim.x - 1) - (int)blockIdx.x;  // descending qt: big blocks first
    int bh = blockIdx.y;
    int b = bh >> 5, h = bh & 31;
    int tid = threadIdx.x, lane = tid & 63, wave = tid >> 6;
    int l15 = lane & 15, kh = lane >> 4;
    int qrow0 = (qt << 7) + (wave << 5);  // 32 rows per wave
    short8 qf[2][4];
    #pragma unroll
    for (int rg = 0; rg < 2; ++rg) {
        const unsigned short* qp = Q + ((size_t)(b * SL) + qrow0 + rg * 16 + l15) * HS + h * HD + kh * 8;
        #pragma unroll
        for (int f = 0; f < 4; ++f) qf[rg][f] = *(const short8*)(qp + f * 32);
    }
    f32x4 oacc[2][8] = {};
    float m[2][4], lsum[2][4];
    #pragma unroll
    for (int rg = 0; rg < 2; ++rg)
        #pragma unroll
        for (int r = 0; r < 4; ++r) { m[rg][r] = -1e30f; lsum[rg][r] = 0.f; }
    int ksrow = tid >> 4, kchunk = tid & 15;
    const unsigned short* Kbase = Kb + (size_t)(b * SL) * HS + h * HD;
    const unsigned short* Vbase = Vt + (size_t)(b * NH + h) * HD * (size_t)SL;
    int ktmax = (qt << 1) + 1;

    // prologue: stage kt=0 into buf 0
    {
        char* dstw = (char*)Ks[0] + (wave << 10);
        #pragma unroll
        for (int c = 0; c < 4; ++c) {
            int kr = c * 16 + ksrow;
            gload_lds16(Kbase + (size_t)kr * HS + ((kchunk ^ (kr & 7)) << 3), dstw + c * 4096);
        }
    }
    int buf = 0;
    for (int kt = 0; kt <= ktmax; ++kt) {
        if (kt < ktmax) {
            char* dstw = (char*)Ks[buf ^ 1] + (wave << 10);
            #pragma unroll
            for (int c = 0; c < 4; ++c) {
                int kr = c * 16 + ksrow;
                gload_lds16(Kbase + (size_t)(((kt + 1) << 6) + kr) * HS + ((kchunk ^ (kr & 7)) << 3),
                            dstw + c * 4096);
            }
            asm volatile("s_waitcnt vmcnt(4)" ::: "memory");
        } else {
            asm volatile("s_waitcnt vmcnt(0)" ::: "memory");
        }
        __syncthreads();
        if ((kt << 6) <= qrow0 + 31) {  // tile has at least one unmasked element for this wave
            // ---- S = Q K^T (16 K-frag reads feed 32 MFMAs) ----
            f32x4 sfr[2][4];
            const char* kb = (const char*)Ks[buf];
            #pragma unroll
            for (int c = 0; c < 4; ++c) {
                f32x4 a0 = {}, a1 = {};
                int krow = c * 16 + l15;
                #pragma unroll
                for (int f = 0; f < 4; ++f) {
                    short8 kf = *(const short8*)(kb + krow * 256 + ((((f << 2) + kh) ^ (krow & 7)) << 4));
                    a0 = mfma16(qf[0][f], kf, a0);
                    a1 = mfma16(qf[1][f], kf, a1);
                }
                sfr[0][c] = a0; sfr[1][c] = a1;
            }
            // ---- mask (diagonal tiles only) + row max ----
            float pm[2][4];
            #pragma unroll
            for (int rg = 0; rg < 2; ++rg)
                #pragma unroll
                for (int r = 0; r < 4; ++r) pm[rg][r] = -1e30f;
            bool domask = ((kt << 6) + 63) > qrow0;
            if (domask) {
                #pragma unroll
                for (int c = 0; c < 4; ++c) {
                    int kkg = (kt << 6) + c * 16 + l15;
                    #pragma unroll
                    for (int rg = 0; rg < 2; ++rg)
                        #pragma unroll
                        for (int r = 0; r < 4; ++r) {
                            int qg = qrow0 + rg * 16 + kh * 4 + r;
                            float v = sfr[rg][c][r];
                            v = (kkg > qg) ? -1e30f : v;
                            sfr[rg][c][r] = v;
                            pm[rg][r] = fmaxf(pm[rg][r], v);
                        }
                }
            } else {
                #pragma unroll
                for (int c = 0; c < 4; ++c)
                    #pragma unroll
                    for (int rg = 0; rg < 2; ++rg)
                        #pragma unroll
                        for (int r = 0; r < 4; ++r) pm[rg][r] = fmaxf(pm[rg][r], sfr[rg][c][r]);
            }
            #pragma unroll
            for (int off = 1; off < 16; off <<= 1)
                #pragma unroll
                for (int rg = 0; rg < 2; ++rg)
                    #pragma unroll
                    for (int r = 0; r < 4; ++r) pm[rg][r] = fmaxf(pm[rg][r], __shfl_xor(pm[rg][r], off, 64));
            // ---- defer-max (T13): rescale only if a row max grew by > 8 ----
            bool ok = true;
            #pragma unroll
            for (int rg = 0; rg < 2; ++rg)
                #pragma unroll
                for (int r = 0; r < 4; ++r) ok = ok && (pm[rg][r] <= m[rg][r] + 8.0f);
            if (!__all(ok)) {
                #pragma unroll
                for (int rg = 0; rg < 2; ++rg)
                    #pragma unroll
                    for (int r = 0; r < 4; ++r) {
                        float mn = fmaxf(m[rg][r], pm[rg][r]);
                        float alpha = __expf(m[rg][r] - mn);
                        m[rg][r] = mn;
                        lsum[rg][r] *= alpha;
                        #pragma unroll
                        for (int db = 0; db < 8; ++db) oacc[rg][db][r] *= alpha;
                    }
            }
            // ---- P = exp(S - m), row sums ----
            float rs[2][4] = {};
            #pragma unroll
            for (int c = 0; c < 4; ++c)
                #pragma unroll
                for (int rg = 0; rg < 2; ++rg)
                    #pragma unroll
                    for (int r = 0; r < 4; ++r) {
                        float p = __expf(sfr[rg][c][r] - m[rg][r]);
                        sfr[rg][c][r] = p;
                        rs[rg][r] += p;
                    }
            #pragma unroll
            for (int off = 1; off < 16; off <<= 1)
                #pragma unroll
                for (int rg = 0; rg < 2; ++rg)
                    #pragma unroll
                    for (int r = 0; r < 4; ++r) rs[rg][r] += __shfl_xor(rs[rg][r], off, 64);
            #pragma unroll
            for (int rg = 0; rg < 2; ++rg)
                #pragma unroll
                for (int r = 0; r < 4; ++r) lsum[rg][r] += rs[rg][r];
            // ---- P -> per-wave LDS (transpose to PV A-frag layout) ----
            #pragma unroll
            for (int c = 0; c < 4; ++c)
                #pragma unroll
                for (int rg = 0; rg < 2; ++rg)
                    #pragma unroll
                    for (int r = 0; r < 4; ++r)
                        Ps[wave][rg * 16 + kh * 4 + r][c * 16 + l15] = f2bf(sfr[rg][c][r]);
            short8 pa[2][2];
            #pragma unroll
            for (int rg = 0; rg < 2; ++rg)
                #pragma unroll
                for (int f = 0; f < 2; ++f)
                    pa[rg][f] = *(const short8*)(&Ps[wave][rg * 16 + l15][f * 32 + kh * 8]);
            // ---- PV: V B-frags direct from global (L2-resident) ----
            #pragma unroll
            for (int db = 0; db < 8; ++db) {
                const unsigned short* vp = Vbase + (size_t)(db * 16 + l15) * SL + (kt << 6) + kh * 8;
                short8 v0 = *(const short8*)(vp);
                short8 v1 = *(const short8*)(vp + 32);
                oacc[0][db] = mfma16(pa[0][0], v0, oacc[0][db]);
                oacc[0][db] = mfma16(pa[0][1], v1, oacc[0][db]);
                oacc[1][db] = mfma16(pa[1][0], v0, oacc[1][db]);
                oacc[1][db] = mfma16(pa[1][1], v1, oacc[1][db]);
            }
        }
        __syncthreads();
        buf ^= 1;
    }
    #pragma unroll
    for (int rg = 0; rg < 2; ++rg)
        #pragma unroll
        for (int db = 0; db < 8; ++db)
            #pragma unroll
            for (int r = 0; r < 4; ++r) {
                int qg = qrow0 + rg * 16 + kh * 4 + r;
                float v = oacc[rg][db][r] / lsum[rg][r];
                O[((size_t)(b * SL) + qg) * HS + h * HD + db * 16 + l15] = f2bf(v);
            }
}

extern "C" void kernel_launch(void* const* d_in, const int* in_sizes, int n_in,
                              void* d_out, int out_size, void* d_ws, size_t ws_size,
                              hipStream_t stream)
{
    const float* X  = (const float*)d_in[0];
    const float* Wq = (const float*)d_in[1];
    const float* Wk = (const float*)d_in[2];
    const float* Wv = (const float*)d_in[3];
    const float* Wo = (const float*)d_in[4];
    float* out = (float*)d_out;
    const size_t SLAB = (size_t)NTOK * HS * 2;  // 32 MiB per bf16 slab
    char* ws = (char*)d_ws;
    unsigned short* Xb  = (unsigned short*)(ws + 0 * SLAB);
    unsigned short* Wqt = (unsigned short*)(ws + 1 * SLAB);
    unsigned short* Wkt = (unsigned short*)(ws + 2 * SLAB);
    unsigned short* Wvt = (unsigned short*)(ws + 3 * SLAB);
    unsigned short* Wot = (unsigned short*)(ws + 4 * SLAB);
    unsigned short* Qb  = (unsigned short*)(ws + 5 * SLAB);
    unsigned short* Kbb = (unsigned short*)(ws + 6 * SLAB);
    unsigned short* Vb  = (unsigned short*)(ws + 7 * SLAB);
    unsigned short* Vtb = Xb;   // alias: Xb dead after V projection
    unsigned short* Ob  = Wqt;  // alias: Wqt dead after Q projection

    k_convert<<<2048, 256, 0, stream>>>(X, Xb, NTOK * HS / 8);
    dim3 tg(128, 128);
    k_transpose_w<<<tg, 256, 0, stream>>>(Wq, Wqt);
    k_transpose_w<<<tg, 256, 0, stream>>>(Wk, Wkt);
    k_transpose_w<<<tg, 256, 0, stream>>>(Wv, Wvt);
    k_transpose_w<<<tg, 256, 0, stream>>>(Wo, Wot);
    k_gemm<unsigned short><<<1024, 256, 0, stream>>>(Xb, Wqt, Qb, NTOK, HS, HS);
    k_gemm<unsigned short><<<1024, 256, 0, stream>>>(Xb, Wkt, Kbb, NTOK, HS, HS);
    k_gemm<unsigned short><<<1024, 256, 0, stream>>>(Xb, Wvt, Vb, NTOK, HS, HS);
    k_rope<<<NTOK * NH * 16 / 256, 256, 0, stream>>>(Qb, Kbb);
    k_transpose_v<<<dim3(SL / 32, HD / 32, BS * NH), 256, 0, stream>>>(Vb, Vtb);
    k_attn<<<dim3(SL / 128, BS * NH), 256, 0, stream>>>(Qb, Kbb, Vtb, Ob);
    k_gemm<float><<<1024, 256, 0, stream>>>(Ob, Wot, out, NTOK, HS, HS);
}

// Round 3
// 1457.919 us; speedup vs baseline: 1.0630x; 1.0630x over previous
//
#include <hip/hip_runtime.h>
#include <cstdint>
#include <cstddef>

#define SL 2048
#define BS 2
#define NH 32
#define HD 128
#define HS 4096
#define NTOK 4096   // BS*SL
#define LDQ 12288   // fused QKV row stride (3*HS)

typedef __attribute__((ext_vector_type(8))) short short8;
typedef __attribute__((ext_vector_type(4))) float f32x4;
typedef __attribute__((ext_vector_type(4))) unsigned short u16x4;
typedef __attribute__((ext_vector_type(8))) unsigned short u16x8;

static __device__ __forceinline__ unsigned short f2bf(float f) {
    unsigned int u = __builtin_bit_cast(unsigned int, f);
    u = u + 0x7FFFu + ((u >> 16) & 1u);   // RNE
    return (unsigned short)(u >> 16);
}
static __device__ __forceinline__ float bf2f(unsigned short h) {
    unsigned int u = ((unsigned int)h) << 16;
    return __builtin_bit_cast(float, u);
}

static __device__ __forceinline__ f32x4 mfma16(short8 a, short8 b, f32x4 c) {
    return __builtin_amdgcn_mfma_f32_16x16x32_bf16(a, b, c, 0, 0, 0);
}

static __device__ __forceinline__ void gload_lds16(const void* g, void* dst) {
    __builtin_amdgcn_global_load_lds(
        (const __attribute__((address_space(1))) unsigned int*)g,
        (__attribute__((address_space(3))) unsigned int*)dst,
        16, 0, 0);
}

// ---------------- fp32 -> bf16 convert (X) ----------------
__global__ void k_convert(const float* __restrict__ in, unsigned short* __restrict__ out, int n8) {
    int stride = gridDim.x * blockDim.x;
    for (int i = blockIdx.x * blockDim.x + threadIdx.x; i < n8; i += stride) {
        const f32x4* p = (const f32x4*)in + (size_t)i * 2;
        f32x4 a = p[0], b = p[1];
        u16x8 o;
        o[0] = f2bf(a[0]); o[1] = f2bf(a[1]); o[2] = f2bf(a[2]); o[3] = f2bf(a[3]);
        o[4] = f2bf(b[0]); o[5] = f2bf(b[1]); o[6] = f2bf(b[2]); o[7] = f2bf(b[3]);
        *((u16x8*)out + i) = o;
    }
}

// ---------------- fp32 W[k][n] -> bf16 Wt[n][k] ----------------
__global__ void k_transpose_w(const float* __restrict__ w, unsigned short* __restrict__ wt) {
    __shared__ float t[32][33];
    int r0 = blockIdx.y << 5, c0 = blockIdx.x << 5;
    int tr = threadIdx.x >> 3;
    int tc = (threadIdx.x & 7) << 2;
    f32x4 v = *(const f32x4*)(w + (size_t)(r0 + tr) * HS + c0 + tc);
    t[tr][tc + 0] = v[0]; t[tr][tc + 1] = v[1]; t[tr][tc + 2] = v[2]; t[tr][tc + 3] = v[3];
    __syncthreads();
    u16x4 o;
    o[0] = f2bf(t[tc + 0][tr]); o[1] = f2bf(t[tc + 1][tr]);
    o[2] = f2bf(t[tc + 2][tr]); o[3] = f2bf(t[tc + 3][tr]);
    *(u16x4*)(wt + (size_t)(c0 + tr) * HS + r0 + tc) = o;
}

// ---------------- bf16 GEMM: C[M][N] = A[M][K] * Bt[N][K]^T (XCD-swizzled) ----------------
template <typename OutT>
__global__ __launch_bounds__(256) void k_gemm(
    const unsigned short* __restrict__ A,
    const unsigned short* __restrict__ Bt,
    OutT* __restrict__ C,
    int M, int N, int K)
{
    __shared__ unsigned short As[128 * 32];
    __shared__ unsigned short Bs[128 * 32];
    int tiles_n = N >> 7;
    int bid = blockIdx.x;
    int q8 = gridDim.x >> 3;                    // gridDim.x % 8 == 0 always here
    bid = (bid & 7) * q8 + (bid >> 3);          // bijective XCD swizzle (T1)
    int tm = bid / tiles_n, tn = bid % tiles_n;
    int tid = threadIdx.x;
    int lane = tid & 63, wave = tid >> 6;
    int wr = wave >> 1, wc = wave & 1;
    int l15 = lane & 15, kh = lane >> 4;
    f32x4 acc[4][4] = {};
    int row0 = tm << 7, col0 = tn << 7;
    int srow = tid >> 2, scg = (tid & 3) << 3;
    const unsigned short* Abase = A + (size_t)(row0 + srow) * K + scg;
    const unsigned short* Bbase = Bt + (size_t)(col0 + srow) * K + scg;
    char* AsW = (char*)As + (wave << 10);
    char* BsW = (char*)Bs + (wave << 10);
    for (int k0 = 0; k0 < K; k0 += 32) {
        gload_lds16(Abase + k0, AsW);
        gload_lds16(Abase + (size_t)64 * K + k0, AsW + 4096);
        gload_lds16(Bbase + k0, BsW);
        gload_lds16(Bbase + (size_t)64 * K + k0, BsW + 4096);
        __syncthreads();
        short8 af[4], bfr[4];
        #pragma unroll
        for (int i = 0; i < 4; i++) af[i] = *(const short8*)(As + (wr * 64 + i * 16 + l15) * 32 + kh * 8);
        #pragma unroll
        for (int j = 0; j < 4; j++) bfr[j] = *(const short8*)(Bs + (wc * 64 + j * 16 + l15) * 32 + kh * 8);
        #pragma unroll
        for (int i = 0; i < 4; i++)
            #pragma unroll
            for (int j = 0; j < 4; j++)
                acc[i][j] = mfma16(af[i], bfr[j], acc[i][j]);
        __syncthreads();
    }
    #pragma unroll
    for (int i = 0; i < 4; i++)
        #pragma unroll
        for (int j = 0; j < 4; j++)
            #pragma unroll
            for (int r = 0; r < 4; r++) {
                int row = row0 + wr * 64 + i * 16 + kh * 4 + r;
                int col = col0 + wc * 64 + j * 16 + l15;
                float v = acc[i][j][r];
                if constexpr (sizeof(OutT) == 2) C[(size_t)row * N + col] = (OutT)f2bf(v);
                else                             C[(size_t)row * N + col] = v;
            }
}

// ---------------- RoPE on Q (pre-scaled by 1/sqrt(hd)) and K, in the fused QKV buffer ----------------
__global__ void k_rope(unsigned short* __restrict__ QKV) {
    const float SCALE = 0.08838834764831845f;  // 1/sqrt(128)
    int i = blockIdx.x * blockDim.x + threadIdx.x;  // quad index, grid exact
    int q4 = i & 15;
    int head = (i >> 4) & (NH - 1);
    int tok = i >> 9;
    int s = tok & (SL - 1);
    int d0 = q4 << 2;
    size_t base = (size_t)tok * LDQ + head * HD;
    unsigned short* Q = QKV + base;
    unsigned short* K = QKV + base + HS;
    float cs[4], sn[4];
    #pragma unroll
    for (int j = 0; j < 4; j++) {
        float invf = expf(-(float)(d0 + j) * 0.14391156831212787f);  // ln(1e4)/64
        float ang = (float)s * invf;
        sn[j] = sinf(ang); cs[j] = cosf(ang);
    }
    {
        u16x4 lo = *(u16x4*)(Q + d0);
        u16x4 hi = *(u16x4*)(Q + d0 + 64);
        u16x4 nlo, nhi;
        #pragma unroll
        for (int j = 0; j < 4; j++) {
            float x0 = bf2f(lo[j]), x1 = bf2f(hi[j]);
            nlo[j] = f2bf((x0 * cs[j] - x1 * sn[j]) * SCALE);
            nhi[j] = f2bf((x1 * cs[j] + x0 * sn[j]) * SCALE);
        }
        *(u16x4*)(Q + d0) = nlo;
        *(u16x4*)(Q + d0 + 64) = nhi;
    }
    {
        u16x4 lo = *(u16x4*)(K + d0);
        u16x4 hi = *(u16x4*)(K + d0 + 64);
        u16x4 nlo, nhi;
        #pragma unroll
        for (int j = 0; j < 4; j++) {
            float x0 = bf2f(lo[j]), x1 = bf2f(hi[j]);
            nlo[j] = f2bf(x0 * cs[j] - x1 * sn[j]);
            nhi[j] = f2bf(x1 * cs[j] + x0 * sn[j]);
        }
        *(u16x4*)(K + d0) = nlo;
        *(u16x4*)(K + d0 + 64) = nhi;
    }
}

// ---------------- V (from QKV) -> Vt ((b,h), d, s) ----------------
__global__ void k_transpose_v(const unsigned short* __restrict__ QKV, unsigned short* __restrict__ Vt) {
    __shared__ unsigned short t[32][36];
    int bh = blockIdx.z; int b = bh >> 5, h = bh & 31;
    int s0 = blockIdx.x << 5, d0 = blockIdx.y << 5;
    int tr = threadIdx.x >> 3, tc = (threadIdx.x & 7) << 2;
    u16x4 v = *(const u16x4*)(QKV + (size_t)(b * SL + s0 + tr) * LDQ + 2 * HS + h * HD + d0 + tc);
    t[tr][tc + 0] = v[0]; t[tr][tc + 1] = v[1]; t[tr][tc + 2] = v[2]; t[tr][tc + 3] = v[3];
    __syncthreads();
    u16x4 o;
    o[0] = t[tc + 0][tr]; o[1] = t[tc + 1][tr]; o[2] = t[tc + 2][tr]; o[3] = t[tc + 3][tr];
    *(u16x4*)(Vt + ((size_t)(b * NH + h) * HD + d0 + tr) * SL + s0 + tc) = o;
}

// ---------------- causal flash attention v3 ----------------
// R1 structure (4 waves x 16 q-rows, QBLK=64), plus:
//  - no V LDS staging (V from global/L2, pipelined in PV under VGPR cap)
//  - 2-phase K pipeline: stage(kt+1) issued after the post-QK barrier
//  - no barrier around per-wave Ps transpose
//  - diag-only mask, defer-max (T13), descending qt, setprio around MFMA
__global__ __launch_bounds__(256, 4) void k_attn(
    const unsigned short* __restrict__ QKV,
    const unsigned short* __restrict__ Vt,
    unsigned short* __restrict__ O)
{
    __shared__ unsigned short Ks[64 * 128];   // [kk][d], chunk-swizzled (16B chunk ^ row&7)
    __shared__ unsigned short Ps[4][16][68];  // per-wave P transpose, +4 pad (2-way banks)
    int qt = (int)(gridDim.x - 1) - (int)blockIdx.x;  // big blocks first
    int bh = blockIdx.y;
    int b = bh >> 5, h = bh & 31;
    int tid = threadIdx.x, lane = tid & 63, wave = tid >> 6;
    int l15 = lane & 15, kh = lane >> 4;
    int qrow0 = (qt << 6) + (wave << 4);
    short8 qf[4];
    {
        const unsigned short* qp = QKV + ((size_t)(b * SL) + qrow0 + l15) * LDQ + h * HD + kh * 8;
        #pragma unroll
        for (int f = 0; f < 4; ++f) qf[f] = *(const short8*)(qp + f * 32);
    }
    f32x4 oacc[8] = {};
    float m[4] = {-1e30f, -1e30f, -1e30f, -1e30f};
    float lsum[4] = {0.f, 0.f, 0.f, 0.f};
    int ksrow = tid >> 4, kchunk = tid & 15;
    const unsigned short* Kbase = QKV + HS + (size_t)(b * SL) * LDQ + h * HD;
    const unsigned short* Vbase = Vt + (size_t)(b * NH + h) * HD * (size_t)SL;
    char* KsW = (char*)Ks + (wave << 10);
    // prologue: stage kt=0
    #pragma unroll
    for (int c = 0; c < 4; ++c) {
        int kr = c * 16 + ksrow;
        gload_lds16(Kbase + (size_t)kr * LDQ + ((kchunk ^ (kr & 7)) << 3), KsW + c * 4096);
    }
    for (int kt = 0; kt <= qt; ++kt) {
        __syncthreads();   // staged K(kt) ready (implicit vmcnt drain) + Ks write-safe
        // ---- S = Q K^T ----
        f32x4 sfr[4];
        __builtin_amdgcn_s_setprio(1);
        #pragma unroll
        for (int c = 0; c < 4; ++c) {
            f32x4 acc = {};
            int krow = c * 16 + l15;
            #pragma unroll
            for (int f = 0; f < 4; ++f) {
                short8 kf = *(const short8*)((const char*)Ks + krow * 256 + ((((f << 2) + kh) ^ (krow & 7)) << 4));
                acc = mfma16(qf[f], kf, acc);
            }
            sfr[c] = acc;
        }
        __builtin_amdgcn_s_setprio(0);
        __syncthreads();   // all waves done reading Ks
        if (kt < qt) {     // stage next K; latency hides under softmax+PV
            #pragma unroll
            for (int c = 0; c < 4; ++c) {
                int kr = c * 16 + ksrow;
                gload_lds16(Kbase + (size_t)(((kt + 1) << 6) + kr) * LDQ + ((kchunk ^ (kr & 7)) << 3),
                            KsW + c * 4096);
            }
        }
        // ---- mask (diag tile only) + row max ----
        float pm[4] = {-1e30f, -1e30f, -1e30f, -1e30f};
        if (kt == qt) {
            #pragma unroll
            for (int c = 0; c < 4; ++c) {
                int kkg = (kt << 6) + c * 16 + l15;
                #pragma unroll
                for (int r = 0; r < 4; ++r) {
                    int qg = qrow0 + kh * 4 + r;
                    float v = sfr[c][r];
                    v = (kkg > qg) ? -1e30f : v;
                    sfr[c][r] = v;
                    pm[r] = fmaxf(pm[r], v);
                }
            }
        } else {
            #pragma unroll
            for (int c = 0; c < 4; ++c)
                #pragma unroll
                for (int r = 0; r < 4; ++r) pm[r] = fmaxf(pm[r], sfr[c][r]);
        }
        #pragma unroll
        for (int off = 1; off < 16; off <<= 1)
            #pragma unroll
            for (int r = 0; r < 4; ++r) pm[r] = fmaxf(pm[r], __shfl_xor(pm[r], off, 64));
        // ---- defer-max (T13) ----
        bool ok = true;
        #pragma unroll
        for (int r = 0; r < 4; ++r) ok = ok && (pm[r] <= m[r] + 8.0f);
        if (!__all(ok)) {
            #pragma unroll
            for (int r = 0; r < 4; ++r) {
                float mn = fmaxf(m[r], pm[r]);
                float alpha = __expf(m[r] - mn);
                m[r] = mn;
                lsum[r] *= alpha;
                #pragma unroll
                for (int db = 0; db < 8; ++db) oacc[db][r] *= alpha;
            }
        }
        // ---- P = exp(S - m), row sums ----
        float rs[4] = {0.f, 0.f, 0.f, 0.f};
        #pragma unroll
        for (int c = 0; c < 4; ++c)
            #pragma unroll
            for (int r = 0; r < 4; ++r) {
                float p = __expf(sfr[c][r] - m[r]);
                sfr[c][r] = p;
                rs[r] += p;
            }
        #pragma unroll
        for (int off = 1; off < 16; off <<= 1)
            #pragma unroll
            for (int r = 0; r < 4; ++r) rs[r] += __shfl_xor(rs[r], off, 64);
        #pragma unroll
        for (int r = 0; r < 4; ++r) lsum[r] += rs[r];
        // ---- P -> per-wave LDS transpose (no barrier: same-wave RAW) ----
        #pragma unroll
        for (int c = 0; c < 4; ++c)
            #pragma unroll
            for (int r = 0; r < 4; ++r)
                Ps[wave][kh * 4 + r][c * 16 + l15] = f2bf(sfr[c][r]);
        short8 pa0 = *(const short8*)(&Ps[wave][l15][kh * 8]);
        short8 pa1 = *(const short8*)(&Ps[wave][l15][32 + kh * 8]);
        // ---- PV: V B-frags direct from global (L2-resident), compiler-pipelined ----
        __builtin_amdgcn_s_setprio(1);
        #pragma unroll
        for (int db = 0; db < 8; ++db) {
            const unsigned short* vp = Vbase + (size_t)(db * 16 + l15) * SL + (kt << 6) + kh * 8;
            short8 v0 = *(const short8*)(vp);
            short8 v1 = *(const short8*)(vp + 32);
            oacc[db] = mfma16(pa0, v0, oacc[db]);
            oacc[db] = mfma16(pa1, v1, oacc[db]);
        }
        __builtin_amdgcn_s_setprio(0);
    }
    #pragma unroll
    for (int db = 0; db < 8; ++db)
        #pragma unroll
        for (int r = 0; r < 4; ++r) {
            int qg = qrow0 + kh * 4 + r;
            float v = oacc[db][r] / lsum[r];
            O[((size_t)(b * SL) + qg) * HS + h * HD + db * 16 + l15] = f2bf(v);
        }
}

extern "C" void kernel_launch(void* const* d_in, const int* in_sizes, int n_in,
                              void* d_out, int out_size, void* d_ws, size_t ws_size,
                              hipStream_t stream)
{
    const float* X  = (const float*)d_in[0];
    const float* Wq = (const float*)d_in[1];
    const float* Wk = (const float*)d_in[2];
    const float* Wv = (const float*)d_in[3];
    const float* Wo = (const float*)d_in[4];
    float* out = (float*)d_out;
    const size_t SLAB = (size_t)NTOK * HS * 2;  // 32 MiB per bf16 slab
    char* ws = (char*)d_ws;
    unsigned short* Xb  = (unsigned short*)(ws + 0 * SLAB);
    unsigned short* Wqt = (unsigned short*)(ws + 1 * SLAB);  // Wqt|Wkt|Wvt contiguous = fused B^T
    unsigned short* Wkt = (unsigned short*)(ws + 2 * SLAB);
    unsigned short* Wvt = (unsigned short*)(ws + 3 * SLAB);
    unsigned short* Wot = (unsigned short*)(ws + 4 * SLAB);
    unsigned short* QKV = (unsigned short*)(ws + 5 * SLAB);  // 96 MiB: [4096][12288]
    unsigned short* Vtb = Xb;   // alias: Xb dead after fused QKV GEMM
    unsigned short* Ob  = Wqt;  // alias: W*t dead after fused QKV GEMM

    k_convert<<<2048, 256, 0, stream>>>(X, Xb, NTOK * HS / 8);
    dim3 tg(128, 128);
    k_transpose_w<<<tg, 256, 0, stream>>>(Wq, Wqt);
    k_transpose_w<<<tg, 256, 0, stream>>>(Wk, Wkt);
    k_transpose_w<<<tg, 256, 0, stream>>>(Wv, Wvt);
    k_transpose_w<<<tg, 256, 0, stream>>>(Wo, Wot);
    // fused QKV projection: C[4096][12288] = Xb * [Wqt|Wkt|Wvt]^T
    k_gemm<unsigned short><<<3072, 256, 0, stream>>>(Xb, Wqt, QKV, NTOK, 3 * HS, HS);
    k_rope<<<NTOK * NH * 16 / 256, 256, 0, stream>>>(QKV);
    k_transpose_v<<<dim3(SL / 32, HD / 32, BS * NH), 256, 0, stream>>>(QKV, Vtb);
    k_attn<<<dim3(SL / 64, BS * NH), 256, 0, stream>>>(QKV, Vtb, Ob);
    k_gemm<float><<<1024, 256, 0, stream>>>(Ob, Wot, out, NTOK, HS, HS);
}

// Round 4
// 1171.922 us; speedup vs baseline: 1.3224x; 1.2440x over previous
//
#include <hip/hip_runtime.h>
#include <cstdint>
#include <cstddef>

#define SL 2048
#define BS 2
#define NH 32
#define HD 128
#define HS 4096
#define NTOK 4096   // BS*SL
#define LDQ 12288   // fused QKV row stride (3*HS)

typedef __attribute__((ext_vector_type(8))) short short8;
typedef __attribute__((ext_vector_type(4))) float f32x4;
typedef __attribute__((ext_vector_type(4))) unsigned short u16x4;
typedef __attribute__((ext_vector_type(8))) unsigned short u16x8;

static __device__ __forceinline__ unsigned short f2bf(float f) {
    unsigned int u = __builtin_bit_cast(unsigned int, f);
    u = u + 0x7FFFu + ((u >> 16) & 1u);   // RNE
    return (unsigned short)(u >> 16);
}
static __device__ __forceinline__ float bf2f(unsigned short h) {
    unsigned int u = ((unsigned int)h) << 16;
    return __builtin_bit_cast(float, u);
}

static __device__ __forceinline__ f32x4 mfma16(short8 a, short8 b, f32x4 c) {
    return __builtin_amdgcn_mfma_f32_16x16x32_bf16(a, b, c, 0, 0, 0);
}

static __device__ __forceinline__ void gload_lds16(const void* g, void* dst) {
    __builtin_amdgcn_global_load_lds(
        (const __attribute__((address_space(1))) unsigned int*)g,
        (__attribute__((address_space(3))) unsigned int*)dst,
        16, 0, 0);
}

// ---------------- fp32 -> bf16 convert (X) ----------------
__global__ void k_convert(const float* __restrict__ in, unsigned short* __restrict__ out, int n8) {
    int stride = gridDim.x * blockDim.x;
    for (int i = blockIdx.x * blockDim.x + threadIdx.x; i < n8; i += stride) {
        const f32x4* p = (const f32x4*)in + (size_t)i * 2;
        f32x4 a = p[0], b = p[1];
        u16x8 o;
        o[0] = f2bf(a[0]); o[1] = f2bf(a[1]); o[2] = f2bf(a[2]); o[3] = f2bf(a[3]);
        o[4] = f2bf(b[0]); o[5] = f2bf(b[1]); o[6] = f2bf(b[2]); o[7] = f2bf(b[3]);
        *((u16x8*)out + i) = o;
    }
}

// ---------------- fp32 W[k][n] -> bf16 Wt[n][k] ----------------
__global__ void k_transpose_w(const float* __restrict__ w, unsigned short* __restrict__ wt) {
    __shared__ float t[32][33];
    int r0 = blockIdx.y << 5, c0 = blockIdx.x << 5;
    int tr = threadIdx.x >> 3;
    int tc = (threadIdx.x & 7) << 2;
    f32x4 v = *(const f32x4*)(w + (size_t)(r0 + tr) * HS + c0 + tc);
    t[tr][tc + 0] = v[0]; t[tr][tc + 1] = v[1]; t[tr][tc + 2] = v[2]; t[tr][tc + 3] = v[3];
    __syncthreads();
    u16x4 o;
    o[0] = f2bf(t[tc + 0][tr]); o[1] = f2bf(t[tc + 1][tr]);
    o[2] = f2bf(t[tc + 2][tr]); o[3] = f2bf(t[tc + 3][tr]);
    *(u16x4*)(wt + (size_t)(c0 + tr) * HS + r0 + tc) = o;
}

// =====================================================================
// 256x256 8-phase bf16 GEMM (T2+T3+T4+T5): C[M][N] = A[M][K] * Bt[N][K]^T
// 512 threads = 8 waves (2M x 4N), BK=64, 128 KiB LDS double-buffered.
// LDS per buffer: A-half0 | A-half1 | B-half0 | B-half1 (16 KiB each,
// [128 rows][64 k] bf16, st_16x32 swizzle: colbyte ^= ((row>>2)&1)<<5,
// applied via inverse-swizzled global source + swizzled ds_read).
// Stage schedule (phase -> half-tile): 1:A1(2t+1) 2:B0(2t+2) 3:B1(2t+2)
// 4:A0(2t+2) 5:A1(2t+2) 6:B0(2t+3) 7:B1(2t+3) 8:A0(2t+3).
// vmcnt(6) at phases 4 & 8 retires exactly the next window's K-tile.
// =====================================================================
#define REG(b, w) ((b) * 65536 + (w) * 16384)   // w: 0=A0 1=A1 2=B0 3=B1

template <typename OutT>
__global__ __launch_bounds__(512, 2) void k_gemm256(
    const unsigned short* __restrict__ A,
    const unsigned short* __restrict__ Bt,
    OutT* __restrict__ C,
    int M, int N, int K)
{
    __shared__ char lds[131072];
    char* ldsb = lds;
    int tiles_n = N >> 8;
    int bid = blockIdx.x;
    int q8 = gridDim.x >> 3;               // grid % 8 == 0 here
    bid = (bid & 7) * q8 + (bid >> 3);     // XCD-contiguous tile chunks (T1)
    int tm = bid / tiles_n, tn = bid % tiles_n;
    int tid = threadIdx.x, lane = tid & 63, wave = tid >> 6;
    int l15 = lane & 15, kh = lane >> 4;
    int wm = wave >> 2, wn = wave & 3;
    int row0 = tm << 8, col0 = tn << 8;
    f32x4 acc[8][4] = {};

    // --- staging addresses (per thread): linear LDS dst, inverse-swz source
    int sr = tid >> 3;                      // row 0..63 (+64 for 2nd load)
    int scb = (tid & 7) << 4;               // colbyte 0..112
    int scol = (scb ^ (((sr >> 2) & 1) << 5)) >> 1;   // same for both loads
    const unsigned short* Abase0 = A + (size_t)(row0 + sr) * K + scol;
    const unsigned short* Bbase0 = Bt + (size_t)(col0 + sr) * K + scol;

    // --- fragment read bases (swizzled): rswz depends only on l15
    int rswz = ((l15 >> 2) & 1) << 5;
    int afb = wm * 16384 + l15 * 128 + ((kh * 16) ^ rswz);
    int bfb = 32768 + ((wn >> 1) * 16384) + (((wn & 1) * 64 + l15) * 128) + ((kh * 16) ^ rswz);

    short8 af[4][2], bfr[4][2];

#define STAGE(R, Gp) do { \
    gload_lds16((Gp),                ldsb + (R) + tid * 16); \
    gload_lds16((Gp) + (size_t)64 * K, ldsb + (R) + 8192 + tid * 16); } while (0)

#define READ_A(buf, g) { _Pragma("unroll") for (int mq = 0; mq < 4; ++mq) \
    _Pragma("unroll") for (int ks = 0; ks < 2; ++ks) \
        af[mq][ks] = *(const short8*)(ldsb + (buf) * 65536 + afb + (g) * 8192 + mq * 2048 + ks * 64); }

#define READ_B(buf) { _Pragma("unroll") for (int n = 0; n < 4; ++n) \
    _Pragma("unroll") for (int ks = 0; ks < 2; ++ks) \
        bfr[n][ks] = *(const short8*)(ldsb + (buf) * 65536 + bfb + n * 2048 + ks * 64); }

#define MFMA_Q(g, nh) { _Pragma("unroll") for (int mq = 0; mq < 4; ++mq) \
    _Pragma("unroll") for (int n2 = 0; n2 < 2; ++n2) { \
        acc[(g)*4+mq][(nh)*2+n2] = mfma16(af[mq][0], bfr[(nh)*2+n2][0], acc[(g)*4+mq][(nh)*2+n2]); \
        acc[(g)*4+mq][(nh)*2+n2] = mfma16(af[mq][1], bfr[(nh)*2+n2][1], acc[(g)*4+mq][(nh)*2+n2]); } }

#define LGKM0() do { asm volatile("s_waitcnt lgkmcnt(0)" ::: "memory"); \
                     __builtin_amdgcn_sched_barrier(0); } while (0)
#define BAR() __builtin_amdgcn_s_barrier()

    // --- prologue: tile0 (buf0) fully + tile1 (buf1) B0,B1,A0
    STAGE(REG(0, 2), Bbase0);
    STAGE(REG(0, 3), Bbase0 + (size_t)128 * K);
    STAGE(REG(0, 0), Abase0);
    STAGE(REG(0, 1), Abase0 + (size_t)128 * K);
    STAGE(REG(1, 2), Bbase0 + 64);
    STAGE(REG(1, 3), Bbase0 + (size_t)128 * K + 64);
    STAGE(REG(1, 0), Abase0 + 64);
    asm volatile("s_waitcnt vmcnt(6)" ::: "memory");
    BAR();

    int nkt = K >> 6;           // 64 K-tiles
    int niter = nkt >> 1;       // 32 iterations of 8 phases
    #pragma unroll 1
    for (int t = 0; t < niter; ++t) {
        int kt1 = 2 * t + 1, kt2 = 2 * t + 2, kt3 = 2 * t + 3;
        bool s2 = kt2 < nkt, s3 = kt3 < nkt;
        // ---- phase 1 (tile 2t, buf0) ----
        READ_B(0); READ_A(0, 0);
        STAGE(REG(1, 1), Abase0 + (size_t)128 * K + (size_t)kt1 * 64);
        BAR(); LGKM0();
        __builtin_amdgcn_s_setprio(1); MFMA_Q(0, 0); __builtin_amdgcn_s_setprio(0);
        BAR();
        // ---- phase 2 ----
        if (s2) STAGE(REG(0, 2), Bbase0 + (size_t)kt2 * 64);
        BAR();
        __builtin_amdgcn_s_setprio(1); MFMA_Q(0, 1); __builtin_amdgcn_s_setprio(0);
        BAR();
        // ---- phase 3 ----
        READ_A(0, 1);
        if (s2) STAGE(REG(0, 3), Bbase0 + (size_t)128 * K + (size_t)kt2 * 64);
        BAR(); LGKM0();
        __builtin_amdgcn_s_setprio(1); MFMA_Q(1, 0); __builtin_amdgcn_s_setprio(0);
        BAR();
        // ---- phase 4 ----
        if (s2) STAGE(REG(0, 0), Abase0 + (size_t)kt2 * 64);
        BAR();
        __builtin_amdgcn_s_setprio(1); MFMA_Q(1, 1); __builtin_amdgcn_s_setprio(0);
        if (s2) { asm volatile("s_waitcnt vmcnt(6)" ::: "memory"); }
        else    { asm volatile("s_waitcnt vmcnt(0)" ::: "memory"); }
        BAR();
        // ---- phase 5 (tile 2t+1, buf1) ----
        READ_B(1); READ_A(1, 0);
        if (s2) STAGE(REG(0, 1), Abase0 + (size_t)128 * K + (size_t)kt2 * 64);
        BAR(); LGKM0();
        __builtin_amdgcn_s_setprio(1); MFMA_Q(0, 0); __builtin_amdgcn_s_setprio(0);
        BAR();
        // ---- phase 6 ----
        if (s3) STAGE(REG(1, 2), Bbase0 + (size_t)kt3 * 64);
        BAR();
        __builtin_amdgcn_s_setprio(1); MFMA_Q(0, 1); __builtin_amdgcn_s_setprio(0);
        BAR();
        // ---- phase 7 ----
        READ_A(1, 1);
        if (s3) STAGE(REG(1, 3), Bbase0 + (size_t)128 * K + (size_t)kt3 * 64);
        BAR(); LGKM0();
        __builtin_amdgcn_s_setprio(1); MFMA_Q(1, 0); __builtin_amdgcn_s_setprio(0);
        BAR();
        // ---- phase 8 ----
        if (s3) STAGE(REG(1, 0), Abase0 + (size_t)kt3 * 64);
        BAR();
        __builtin_amdgcn_s_setprio(1); MFMA_Q(1, 1); __builtin_amdgcn_s_setprio(0);
        if (s3) { asm volatile("s_waitcnt vmcnt(6)" ::: "memory"); }
        else    { asm volatile("s_waitcnt vmcnt(0)" ::: "memory"); }
        BAR();
    }

    #pragma unroll
    for (int m = 0; m < 8; ++m)
        #pragma unroll
        for (int n = 0; n < 4; ++n)
            #pragma unroll
            for (int rr = 0; rr < 4; ++rr) {
                int row = row0 + wm * 128 + m * 16 + kh * 4 + rr;
                int col = col0 + wn * 64 + n * 16 + l15;
                float v = acc[m][n][rr];
                if constexpr (sizeof(OutT) == 2) C[(size_t)row * N + col] = (OutT)f2bf(v);
                else                             C[(size_t)row * N + col] = v;
            }
#undef STAGE
#undef READ_A
#undef READ_B
#undef MFMA_Q
#undef LGKM0
#undef BAR
}

// ---------------- RoPE on Q (pre-scaled by 1/sqrt(hd)) and K, in the fused QKV buffer ----------------
__global__ void k_rope(unsigned short* __restrict__ QKV) {
    const float SCALE = 0.08838834764831845f;  // 1/sqrt(128)
    int i = blockIdx.x * blockDim.x + threadIdx.x;  // quad index, grid exact
    int q4 = i & 15;
    int head = (i >> 4) & (NH - 1);
    int tok = i >> 9;
    int s = tok & (SL - 1);
    int d0 = q4 << 2;
    size_t base = (size_t)tok * LDQ + head * HD;
    unsigned short* Q = QKV + base;
    unsigned short* K = QKV + base + HS;
    float cs[4], sn[4];
    #pragma unroll
    for (int j = 0; j < 4; j++) {
        float invf = expf(-(float)(d0 + j) * 0.14391156831212787f);  // ln(1e4)/64
        float ang = (float)s * invf;
        sn[j] = sinf(ang); cs[j] = cosf(ang);
    }
    {
        u16x4 lo = *(u16x4*)(Q + d0);
        u16x4 hi = *(u16x4*)(Q + d0 + 64);
        u16x4 nlo, nhi;
        #pragma unroll
        for (int j = 0; j < 4; j++) {
            float x0 = bf2f(lo[j]), x1 = bf2f(hi[j]);
            nlo[j] = f2bf((x0 * cs[j] - x1 * sn[j]) * SCALE);
            nhi[j] = f2bf((x1 * cs[j] + x0 * sn[j]) * SCALE);
        }
        *(u16x4*)(Q + d0) = nlo;
        *(u16x4*)(Q + d0 + 64) = nhi;
    }
    {
        u16x4 lo = *(u16x4*)(K + d0);
        u16x4 hi = *(u16x4*)(K + d0 + 64);
        u16x4 nlo, nhi;
        #pragma unroll
        for (int j = 0; j < 4; j++) {
            float x0 = bf2f(lo[j]), x1 = bf2f(hi[j]);
            nlo[j] = f2bf(x0 * cs[j] - x1 * sn[j]);
            nhi[j] = f2bf(x1 * cs[j] + x0 * sn[j]);
        }
        *(u16x4*)(K + d0) = nlo;
        *(u16x4*)(K + d0 + 64) = nhi;
    }
}

// ---------------- V (from QKV) -> Vt ((b,h), d, s) ----------------
__global__ void k_transpose_v(const unsigned short* __restrict__ QKV, unsigned short* __restrict__ Vt) {
    __shared__ unsigned short t[32][36];
    int bh = blockIdx.z; int b = bh >> 5, h = bh & 31;
    int s0 = blockIdx.x << 5, d0 = blockIdx.y << 5;
    int tr = threadIdx.x >> 3, tc = (threadIdx.x & 7) << 2;
    u16x4 v = *(const u16x4*)(QKV + (size_t)(b * SL + s0 + tr) * LDQ + 2 * HS + h * HD + d0 + tc);
    t[tr][tc + 0] = v[0]; t[tr][tc + 1] = v[1]; t[tr][tc + 2] = v[2]; t[tr][tc + 3] = v[3];
    __syncthreads();
    u16x4 o;
    o[0] = t[tc + 0][tr]; o[1] = t[tc + 1][tr]; o[2] = t[tc + 2][tr]; o[3] = t[tc + 3][tr];
    *(u16x4*)(Vt + ((size_t)(b * NH + h) * HD + d0 + tr) * SL + s0 + tc) = o;
}

// ---------------- causal flash attention (unchanged from R3) ----------------
__global__ __launch_bounds__(256, 4) void k_attn(
    const unsigned short* __restrict__ QKV,
    const unsigned short* __restrict__ Vt,
    unsigned short* __restrict__ O)
{
    __shared__ unsigned short Ks[64 * 128];   // [kk][d], chunk-swizzled (16B chunk ^ row&7)
    __shared__ unsigned short Ps[4][16][68];  // per-wave P transpose, +4 pad
    int qt = (int)(gridDim.x - 1) - (int)blockIdx.x;  // big blocks first
    int bh = blockIdx.y;
    int b = bh >> 5, h = bh & 31;
    int tid = threadIdx.x, lane = tid & 63, wave = tid >> 6;
    int l15 = lane & 15, kh = lane >> 4;
    int qrow0 = (qt << 6) + (wave << 4);
    short8 qf[4];
    {
        const unsigned short* qp = QKV + ((size_t)(b * SL) + qrow0 + l15) * LDQ + h * HD + kh * 8;
        #pragma unroll
        for (int f = 0; f < 4; ++f) qf[f] = *(const short8*)(qp + f * 32);
    }
    f32x4 oacc[8] = {};
    float m[4] = {-1e30f, -1e30f, -1e30f, -1e30f};
    float lsum[4] = {0.f, 0.f, 0.f, 0.f};
    int ksrow = tid >> 4, kchunk = tid & 15;
    const unsigned short* Kbase = QKV + HS + (size_t)(b * SL) * LDQ + h * HD;
    const unsigned short* Vbase = Vt + (size_t)(b * NH + h) * HD * (size_t)SL;
    char* KsW = (char*)Ks + (wave << 10);
    #pragma unroll
    for (int c = 0; c < 4; ++c) {
        int kr = c * 16 + ksrow;
        gload_lds16(Kbase + (size_t)kr * LDQ + ((kchunk ^ (kr & 7)) << 3), KsW + c * 4096);
    }
    for (int kt = 0; kt <= qt; ++kt) {
        __syncthreads();
        f32x4 sfr[4];
        __builtin_amdgcn_s_setprio(1);
        #pragma unroll
        for (int c = 0; c < 4; ++c) {
            f32x4 acc = {};
            int krow = c * 16 + l15;
            #pragma unroll
            for (int f = 0; f < 4; ++f) {
                short8 kf = *(const short8*)((const char*)Ks + krow * 256 + ((((f << 2) + kh) ^ (krow & 7)) << 4));
                acc = mfma16(qf[f], kf, acc);
            }
            sfr[c] = acc;
        }
        __builtin_amdgcn_s_setprio(0);
        __syncthreads();
        if (kt < qt) {
            #pragma unroll
            for (int c = 0; c < 4; ++c) {
                int kr = c * 16 + ksrow;
                gload_lds16(Kbase + (size_t)(((kt + 1) << 6) + kr) * LDQ + ((kchunk ^ (kr & 7)) << 3),
                            KsW + c * 4096);
            }
        }
        float pm[4] = {-1e30f, -1e30f, -1e30f, -1e30f};
        if (kt == qt) {
            #pragma unroll
            for (int c = 0; c < 4; ++c) {
                int kkg = (kt << 6) + c * 16 + l15;
                #pragma unroll
                for (int r = 0; r < 4; ++r) {
                    int qg = qrow0 + kh * 4 + r;
                    float v = sfr[c][r];
                    v = (kkg > qg) ? -1e30f : v;
                    sfr[c][r] = v;
                    pm[r] = fmaxf(pm[r], v);
                }
            }
        } else {
            #pragma unroll
            for (int c = 0; c < 4; ++c)
                #pragma unroll
                for (int r = 0; r < 4; ++r) pm[r] = fmaxf(pm[r], sfr[c][r]);
        }
        #pragma unroll
        for (int off = 1; off < 16; off <<= 1)
            #pragma unroll
            for (int r = 0; r < 4; ++r) pm[r] = fmaxf(pm[r], __shfl_xor(pm[r], off, 64));
        bool ok = true;
        #pragma unroll
        for (int r = 0; r < 4; ++r) ok = ok && (pm[r] <= m[r] + 8.0f);
        if (!__all(ok)) {
            #pragma unroll
            for (int r = 0; r < 4; ++r) {
                float mn = fmaxf(m[r], pm[r]);
                float alpha = __expf(m[r] - mn);
                m[r] = mn;
                lsum[r] *= alpha;
                #pragma unroll
                for (int db = 0; db < 8; ++db) oacc[db][r] *= alpha;
            }
        }
        float rs[4] = {0.f, 0.f, 0.f, 0.f};
        #pragma unroll
        for (int c = 0; c < 4; ++c)
            #pragma unroll
            for (int r = 0; r < 4; ++r) {
                float p = __expf(sfr[c][r] - m[r]);
                sfr[c][r] = p;
                rs[r] += p;
            }
        #pragma unroll
        for (int off = 1; off < 16; off <<= 1)
            #pragma unroll
            for (int r = 0; r < 4; ++r) rs[r] += __shfl_xor(rs[r], off, 64);
        #pragma unroll
        for (int r = 0; r < 4; ++r) lsum[r] += rs[r];
        #pragma unroll
        for (int c = 0; c < 4; ++c)
            #pragma unroll
            for (int r = 0; r < 4; ++r)
                Ps[wave][kh * 4 + r][c * 16 + l15] = f2bf(sfr[c][r]);
        short8 pa0 = *(const short8*)(&Ps[wave][l15][kh * 8]);
        short8 pa1 = *(const short8*)(&Ps[wave][l15][32 + kh * 8]);
        __builtin_amdgcn_s_setprio(1);
        #pragma unroll
        for (int db = 0; db < 8; ++db) {
            const unsigned short* vp = Vbase + (size_t)(db * 16 + l15) * SL + (kt << 6) + kh * 8;
            short8 v0 = *(const short8*)(vp);
            short8 v1 = *(const short8*)(vp + 32);
            oacc[db] = mfma16(pa0, v0, oacc[db]);
            oacc[db] = mfma16(pa1, v1, oacc[db]);
        }
        __builtin_amdgcn_s_setprio(0);
    }
    #pragma unroll
    for (int db = 0; db < 8; ++db)
        #pragma unroll
        for (int r = 0; r < 4; ++r) {
            int qg = qrow0 + kh * 4 + r;
            float v = oacc[db][r] / lsum[r];
            O[((size_t)(b * SL) + qg) * HS + h * HD + db * 16 + l15] = f2bf(v);
        }
}

extern "C" void kernel_launch(void* const* d_in, const int* in_sizes, int n_in,
                              void* d_out, int out_size, void* d_ws, size_t ws_size,
                              hipStream_t stream)
{
    const float* X  = (const float*)d_in[0];
    const float* Wq = (const float*)d_in[1];
    const float* Wk = (const float*)d_in[2];
    const float* Wv = (const float*)d_in[3];
    const float* Wo = (const float*)d_in[4];
    float* out = (float*)d_out;
    const size_t SLAB = (size_t)NTOK * HS * 2;  // 32 MiB per bf16 slab
    char* ws = (char*)d_ws;
    unsigned short* Xb  = (unsigned short*)(ws + 0 * SLAB);
    unsigned short* Wqt = (unsigned short*)(ws + 1 * SLAB);  // Wqt|Wkt|Wvt contiguous = fused B^T
    unsigned short* Wkt = (unsigned short*)(ws + 2 * SLAB);
    unsigned short* Wvt = (unsigned short*)(ws + 3 * SLAB);
    unsigned short* Wot = (unsigned short*)(ws + 4 * SLAB);
    unsigned short* QKV = (unsigned short*)(ws + 5 * SLAB);  // 96 MiB: [4096][12288]
    unsigned short* Vtb = Xb;   // alias: Xb dead after fused QKV GEMM
    unsigned short* Ob  = Wqt;  // alias: W*t dead after fused QKV GEMM

    k_convert<<<2048, 256, 0, stream>>>(X, Xb, NTOK * HS / 8);
    dim3 tg(128, 128);
    k_transpose_w<<<tg, 256, 0, stream>>>(Wq, Wqt);
    k_transpose_w<<<tg, 256, 0, stream>>>(Wk, Wkt);
    k_transpose_w<<<tg, 256, 0, stream>>>(Wv, Wvt);
    k_transpose_w<<<tg, 256, 0, stream>>>(Wo, Wot);
    // fused QKV projection: C[4096][12288] = Xb * [Wqt|Wkt|Wvt]^T  (16x48=768 tiles)
    k_gemm256<unsigned short><<<768, 512, 0, stream>>>(Xb, Wqt, QKV, NTOK, 3 * HS, HS);
    k_rope<<<NTOK * NH * 16 / 256, 256, 0, stream>>>(QKV);
    k_transpose_v<<<dim3(SL / 32, HD / 32, BS * NH), 256, 0, stream>>>(QKV, Vtb);
    k_attn<<<dim3(SL / 64, BS * NH), 256, 0, stream>>>(QKV, Vtb, Ob);
    // output projection: out[4096][4096] = Ob * Wot^T  (16x16=256 tiles)
    k_gemm256<float><<<256, 512, 0, stream>>>(Ob, Wot, out, NTOK, HS, HS);
}

// Round 5
// 924.793 us; speedup vs baseline: 1.6758x; 1.2672x over previous
//
#include <hip/hip_runtime.h>
#include <cstdint>
#include <cstddef>

#define SL 2048
#define BS 2
#define NH 32
#define HD 128
#define HS 4096
#define NTOK 4096   // BS*SL
#define LDQ 12288   // fused QKV row stride (3*HS)

typedef __attribute__((ext_vector_type(8))) short short8;
typedef __attribute__((ext_vector_type(4))) float f32x4;
typedef __attribute__((ext_vector_type(4))) unsigned short u16x4;
typedef __attribute__((ext_vector_type(8))) unsigned short u16x8;

static __device__ __forceinline__ unsigned short f2bf(float f) {
    unsigned int u = __builtin_bit_cast(unsigned int, f);
    u = u + 0x7FFFu + ((u >> 16) & 1u);   // RNE
    return (unsigned short)(u >> 16);
}
static __device__ __forceinline__ float bf2f(unsigned short h) {
    unsigned int u = ((unsigned int)h) << 16;
    return __builtin_bit_cast(float, u);
}

static __device__ __forceinline__ f32x4 mfma16(short8 a, short8 b, f32x4 c) {
    return __builtin_amdgcn_mfma_f32_16x16x32_bf16(a, b, c, 0, 0, 0);
}

static __device__ __forceinline__ void gload_lds16(const void* g, void* dst) {
    __builtin_amdgcn_global_load_lds(
        (const __attribute__((address_space(1))) unsigned int*)g,
        (__attribute__((address_space(3))) unsigned int*)dst,
        16, 0, 0);
}

// ---------------- fp32 -> bf16 convert (X) ----------------
__global__ void k_convert(const float* __restrict__ in, unsigned short* __restrict__ out, int n8) {
    int stride = gridDim.x * blockDim.x;
    for (int i = blockIdx.x * blockDim.x + threadIdx.x; i < n8; i += stride) {
        const f32x4* p = (const f32x4*)in + (size_t)i * 2;
        f32x4 a = p[0], b = p[1];
        u16x8 o;
        o[0] = f2bf(a[0]); o[1] = f2bf(a[1]); o[2] = f2bf(a[2]); o[3] = f2bf(a[3]);
        o[4] = f2bf(b[0]); o[5] = f2bf(b[1]); o[6] = f2bf(b[2]); o[7] = f2bf(b[3]);
        *((u16x8*)out + i) = o;
    }
}

// ---------------- fp32 W[k][n] -> bf16 Wt[n][k], 4 matrices in one launch ----------------
__global__ void k_transpose_w4(const float* __restrict__ w0, const float* __restrict__ w1,
                               const float* __restrict__ w2, const float* __restrict__ w3,
                               unsigned short* __restrict__ wtbase) {
    __shared__ float t[32][33];
    int z = blockIdx.z;
    const float* w = (z == 0) ? w0 : (z == 1) ? w1 : (z == 2) ? w2 : w3;
    unsigned short* wt = wtbase + (size_t)z * HS * HS;
    int r0 = blockIdx.y << 5, c0 = blockIdx.x << 5;
    int tr = threadIdx.x >> 3;
    int tc = (threadIdx.x & 7) << 2;
    f32x4 v = *(const f32x4*)(w + (size_t)(r0 + tr) * HS + c0 + tc);
    t[tr][tc + 0] = v[0]; t[tr][tc + 1] = v[1]; t[tr][tc + 2] = v[2]; t[tr][tc + 3] = v[3];
    __syncthreads();
    u16x4 o;
    o[0] = f2bf(t[tc + 0][tr]); o[1] = f2bf(t[tc + 1][tr]);
    o[2] = f2bf(t[tc + 2][tr]); o[3] = f2bf(t[tc + 3][tr]);
    *(u16x4*)(wt + (size_t)(c0 + tr) * HS + r0 + tc) = o;
}

// =====================================================================
// 256x256 8-phase bf16 GEMM (T2+T3+T4+T5): C[M][N] = A[M][K] * Bt[N][K]^T
// (unchanged from round 4 — verified)
// =====================================================================
#define REG(b, w) ((b) * 65536 + (w) * 16384)   // w: 0=A0 1=A1 2=B0 3=B1

template <typename OutT>
__global__ __launch_bounds__(512, 2) void k_gemm256(
    const unsigned short* __restrict__ A,
    const unsigned short* __restrict__ Bt,
    OutT* __restrict__ C,
    int M, int N, int K)
{
    __shared__ char lds[131072];
    char* ldsb = lds;
    int tiles_n = N >> 8;
    int bid = blockIdx.x;
    int q8 = gridDim.x >> 3;               // grid % 8 == 0 here
    bid = (bid & 7) * q8 + (bid >> 3);     // XCD-contiguous tile chunks (T1)
    int tm = bid / tiles_n, tn = bid % tiles_n;
    int tid = threadIdx.x, lane = tid & 63, wave = tid >> 6;
    int l15 = lane & 15, kh = lane >> 4;
    int wm = wave >> 2, wn = wave & 3;
    int row0 = tm << 8, col0 = tn << 8;
    f32x4 acc[8][4] = {};

    int sr = tid >> 3;
    int scb = (tid & 7) << 4;
    int scol = (scb ^ (((sr >> 2) & 1) << 5)) >> 1;
    const unsigned short* Abase0 = A + (size_t)(row0 + sr) * K + scol;
    const unsigned short* Bbase0 = Bt + (size_t)(col0 + sr) * K + scol;

    int rswz = ((l15 >> 2) & 1) << 5;
    int afb = wm * 16384 + l15 * 128 + ((kh * 16) ^ rswz);
    int bfb = 32768 + ((wn >> 1) * 16384) + (((wn & 1) * 64 + l15) * 128) + ((kh * 16) ^ rswz);

    short8 af[4][2], bfr[4][2];

#define STAGE(R, Gp) do { \
    gload_lds16((Gp),                ldsb + (R) + tid * 16); \
    gload_lds16((Gp) + (size_t)64 * K, ldsb + (R) + 8192 + tid * 16); } while (0)

#define READ_A(buf, g) { _Pragma("unroll") for (int mq = 0; mq < 4; ++mq) \
    _Pragma("unroll") for (int ks = 0; ks < 2; ++ks) \
        af[mq][ks] = *(const short8*)(ldsb + (buf) * 65536 + afb + (g) * 8192 + mq * 2048 + ks * 64); }

#define READ_B(buf) { _Pragma("unroll") for (int n = 0; n < 4; ++n) \
    _Pragma("unroll") for (int ks = 0; ks < 2; ++ks) \
        bfr[n][ks] = *(const short8*)(ldsb + (buf) * 65536 + bfb + n * 2048 + ks * 64); }

#define MFMA_Q(g, nh) { _Pragma("unroll") for (int mq = 0; mq < 4; ++mq) \
    _Pragma("unroll") for (int n2 = 0; n2 < 2; ++n2) { \
        acc[(g)*4+mq][(nh)*2+n2] = mfma16(af[mq][0], bfr[(nh)*2+n2][0], acc[(g)*4+mq][(nh)*2+n2]); \
        acc[(g)*4+mq][(nh)*2+n2] = mfma16(af[mq][1], bfr[(nh)*2+n2][1], acc[(g)*4+mq][(nh)*2+n2]); } }

#define LGKM0() do { asm volatile("s_waitcnt lgkmcnt(0)" ::: "memory"); \
                     __builtin_amdgcn_sched_barrier(0); } while (0)
#define BAR() __builtin_amdgcn_s_barrier()

    STAGE(REG(0, 2), Bbase0);
    STAGE(REG(0, 3), Bbase0 + (size_t)128 * K);
    STAGE(REG(0, 0), Abase0);
    STAGE(REG(0, 1), Abase0 + (size_t)128 * K);
    STAGE(REG(1, 2), Bbase0 + 64);
    STAGE(REG(1, 3), Bbase0 + (size_t)128 * K + 64);
    STAGE(REG(1, 0), Abase0 + 64);
    asm volatile("s_waitcnt vmcnt(6)" ::: "memory");
    BAR();

    int nkt = K >> 6;
    int niter = nkt >> 1;
    #pragma unroll 1
    for (int t = 0; t < niter; ++t) {
        int kt1 = 2 * t + 1, kt2 = 2 * t + 2, kt3 = 2 * t + 3;
        bool s2 = kt2 < nkt, s3 = kt3 < nkt;
        READ_B(0); READ_A(0, 0);
        STAGE(REG(1, 1), Abase0 + (size_t)128 * K + (size_t)kt1 * 64);
        BAR(); LGKM0();
        __builtin_amdgcn_s_setprio(1); MFMA_Q(0, 0); __builtin_amdgcn_s_setprio(0);
        BAR();
        if (s2) STAGE(REG(0, 2), Bbase0 + (size_t)kt2 * 64);
        BAR();
        __builtin_amdgcn_s_setprio(1); MFMA_Q(0, 1); __builtin_amdgcn_s_setprio(0);
        BAR();
        READ_A(0, 1);
        if (s2) STAGE(REG(0, 3), Bbase0 + (size_t)128 * K + (size_t)kt2 * 64);
        BAR(); LGKM0();
        __builtin_amdgcn_s_setprio(1); MFMA_Q(1, 0); __builtin_amdgcn_s_setprio(0);
        BAR();
        if (s2) STAGE(REG(0, 0), Abase0 + (size_t)kt2 * 64);
        BAR();
        __builtin_amdgcn_s_setprio(1); MFMA_Q(1, 1); __builtin_amdgcn_s_setprio(0);
        if (s2) { asm volatile("s_waitcnt vmcnt(6)" ::: "memory"); }
        else    { asm volatile("s_waitcnt vmcnt(0)" ::: "memory"); }
        BAR();
        READ_B(1); READ_A(1, 0);
        if (s2) STAGE(REG(0, 1), Abase0 + (size_t)128 * K + (size_t)kt2 * 64);
        BAR(); LGKM0();
        __builtin_amdgcn_s_setprio(1); MFMA_Q(0, 0); __builtin_amdgcn_s_setprio(0);
        BAR();
        if (s3) STAGE(REG(1, 2), Bbase0 + (size_t)kt3 * 64);
        BAR();
        __builtin_amdgcn_s_setprio(1); MFMA_Q(0, 1); __builtin_amdgcn_s_setprio(0);
        BAR();
        READ_A(1, 1);
        if (s3) STAGE(REG(1, 3), Bbase0 + (size_t)128 * K + (size_t)kt3 * 64);
        BAR(); LGKM0();
        __builtin_amdgcn_s_setprio(1); MFMA_Q(1, 0); __builtin_amdgcn_s_setprio(0);
        BAR();
        if (s3) STAGE(REG(1, 0), Abase0 + (size_t)kt3 * 64);
        BAR();
        __builtin_amdgcn_s_setprio(1); MFMA_Q(1, 1); __builtin_amdgcn_s_setprio(0);
        if (s3) { asm volatile("s_waitcnt vmcnt(6)" ::: "memory"); }
        else    { asm volatile("s_waitcnt vmcnt(0)" ::: "memory"); }
        BAR();
    }

    #pragma unroll
    for (int m = 0; m < 8; ++m)
        #pragma unroll
        for (int n = 0; n < 4; ++n)
            #pragma unroll
            for (int rr = 0; rr < 4; ++rr) {
                int row = row0 + wm * 128 + m * 16 + kh * 4 + rr;
                int col = col0 + wn * 64 + n * 16 + l15;
                float v = acc[m][n][rr];
                if constexpr (sizeof(OutT) == 2) C[(size_t)row * N + col] = (OutT)f2bf(v);
                else                             C[(size_t)row * N + col] = v;
            }
#undef STAGE
#undef READ_A
#undef READ_B
#undef MFMA_Q
#undef LGKM0
#undef BAR
}

// ---------------- RoPE on Q (pre-scaled by 1/sqrt(hd)) and K, in the fused QKV buffer ----------------
__global__ void k_rope(unsigned short* __restrict__ QKV) {
    const float SCALE = 0.08838834764831845f;  // 1/sqrt(128)
    int i = blockIdx.x * blockDim.x + threadIdx.x;
    int q4 = i & 15;
    int head = (i >> 4) & (NH - 1);
    int tok = i >> 9;
    int s = tok & (SL - 1);
    int d0 = q4 << 2;
    size_t base = (size_t)tok * LDQ + head * HD;
    unsigned short* Q = QKV + base;
    unsigned short* K = QKV + base + HS;
    float cs[4], sn[4];
    #pragma unroll
    for (int j = 0; j < 4; j++) {
        float invf = expf(-(float)(d0 + j) * 0.14391156831212787f);  // ln(1e4)/64
        float ang = (float)s * invf;
        sn[j] = sinf(ang); cs[j] = cosf(ang);
    }
    {
        u16x4 lo = *(u16x4*)(Q + d0);
        u16x4 hi = *(u16x4*)(Q + d0 + 64);
        u16x4 nlo, nhi;
        #pragma unroll
        for (int j = 0; j < 4; j++) {
            float x0 = bf2f(lo[j]), x1 = bf2f(hi[j]);
            nlo[j] = f2bf((x0 * cs[j] - x1 * sn[j]) * SCALE);
            nhi[j] = f2bf((x1 * cs[j] + x0 * sn[j]) * SCALE);
        }
        *(u16x4*)(Q + d0) = nlo;
        *(u16x4*)(Q + d0 + 64) = nhi;
    }
    {
        u16x4 lo = *(u16x4*)(K + d0);
        u16x4 hi = *(u16x4*)(K + d0 + 64);
        u16x4 nlo, nhi;
        #pragma unroll
        for (int j = 0; j < 4; j++) {
            float x0 = bf2f(lo[j]), x1 = bf2f(hi[j]);
            nlo[j] = f2bf(x0 * cs[j] - x1 * sn[j]);
            nhi[j] = f2bf(x1 * cs[j] + x0 * sn[j]);
        }
        *(u16x4*)(K + d0) = nlo;
        *(u16x4*)(K + d0 + 64) = nhi;
    }
}

// ---------------- V (from QKV) -> Vt ((b,h), d, s) ----------------
__global__ void k_transpose_v(const unsigned short* __restrict__ QKV, unsigned short* __restrict__ Vt) {
    __shared__ unsigned short t[32][36];
    int bh = blockIdx.z; int b = bh >> 5, h = bh & 31;
    int s0 = blockIdx.x << 5, d0 = blockIdx.y << 5;
    int tr = threadIdx.x >> 3, tc = (threadIdx.x & 7) << 2;
    u16x4 v = *(const u16x4*)(QKV + (size_t)(b * SL + s0 + tr) * LDQ + 2 * HS + h * HD + d0 + tc);
    t[tr][tc + 0] = v[0]; t[tr][tc + 1] = v[1]; t[tr][tc + 2] = v[2]; t[tr][tc + 3] = v[3];
    __syncthreads();
    u16x4 o;
    o[0] = t[tc + 0][tr]; o[1] = t[tc + 1][tr]; o[2] = t[tc + 2][tr]; o[3] = t[tc + 3][tr];
    *(u16x4*)(Vt + ((size_t)(b * NH + h) * HD + d0 + tr) * SL + s0 + tc) = o;
}

// ---------------- causal flash attention v5 ----------------
// R1 skeleton (4 waves x 16 q-rows, K+V staged in LDS) with:
//  - V double-buffered, K single-buffered, both staged AFTER the post-QK
//    barrier -> stage latency hides under softmax+PV; 2 barriers/iter
//  - Ps shrunk to [4][16][36] (two-chunk P transpose) -> 53.8 KB LDS,
//    3 blocks/CU
//  - diag-only mask, defer-max (T13), pre-scaled Q, descending qt, setprio
__global__ __launch_bounds__(256, 4) void k_attn(
    const unsigned short* __restrict__ QKV,
    const unsigned short* __restrict__ Vt,
    unsigned short* __restrict__ O)
{
    __shared__ unsigned short Ks[64 * 128];      // [kk][d], chunk-swizzled
    __shared__ unsigned short Vs[2][128 * 64];   // [buf][d][kk], chunk-swizzled
    __shared__ unsigned short Ps[4][16][36];     // per-wave P transpose, 2 chunks of 32 cols
    int qt = (int)(gridDim.x - 1) - (int)blockIdx.x;  // big blocks first
    int bh = blockIdx.y;
    int b = bh >> 5, h = bh & 31;
    int tid = threadIdx.x, lane = tid & 63, wave = tid >> 6;
    int l15 = lane & 15, kh = lane >> 4;
    int qrow0 = (qt << 6) + (wave << 4);
    short8 qf[4];
    {
        const unsigned short* qp = QKV + ((size_t)(b * SL) + qrow0 + l15) * LDQ + h * HD + kh * 8;
        #pragma unroll
        for (int f = 0; f < 4; ++f) qf[f] = *(const short8*)(qp + f * 32);
    }
    f32x4 oacc[8] = {};
    float m[4] = {-1e30f, -1e30f, -1e30f, -1e30f};
    float lsum[4] = {0.f, 0.f, 0.f, 0.f};
    int ksrow = tid >> 4, kchunk = tid & 15;
    int vsrow = tid >> 3, vchunk = tid & 7;
    const unsigned short* Kbase = QKV + HS + (size_t)(b * SL) * LDQ + h * HD;
    const unsigned short* Vbase = Vt + (size_t)(b * NH + h) * HD * (size_t)SL;
    char* KsW = (char*)Ks + (wave << 10);

    // prologue: stage K(0) and V(0)
    #pragma unroll
    for (int c = 0; c < 4; ++c) {
        int kr = c * 16 + ksrow;
        gload_lds16(Kbase + (size_t)kr * LDQ + ((kchunk ^ (kr & 7)) << 3), KsW + c * 4096);
        int vr = c * 32 + vsrow;
        gload_lds16(Vbase + (size_t)vr * SL + ((vchunk ^ (vr & 7)) << 3),
                    (char*)Vs[0] + (wave << 10) + c * 4096);
    }
    int buf = 0;
    for (int kt = 0; kt <= qt; ++kt) {
        __syncthreads();   // drains stages issued last iter (vmcnt0 implicit)
        // ---- S = Q K^T ----
        f32x4 sfr[4];
        __builtin_amdgcn_s_setprio(1);
        #pragma unroll
        for (int c = 0; c < 4; ++c) {
            f32x4 acc = {};
            int krow = c * 16 + l15;
            #pragma unroll
            for (int f = 0; f < 4; ++f) {
                short8 kf = *(const short8*)((const char*)Ks + krow * 256 + ((((f << 2) + kh) ^ (krow & 7)) << 4));
                acc = mfma16(qf[f], kf, acc);
            }
            sfr[c] = acc;
        }
        __builtin_amdgcn_s_setprio(0);
        __syncthreads();   // all waves done reading Ks
        if (kt < qt) {     // stage next K (over Ks) and next V (other buf);
                           // latency hides under softmax+PV, drains at next top barrier
            #pragma unroll
            for (int c = 0; c < 4; ++c) {
                int kr = c * 16 + ksrow;
                gload_lds16(Kbase + (size_t)(((kt + 1) << 6) + kr) * LDQ + ((kchunk ^ (kr & 7)) << 3),
                            KsW + c * 4096);
                int vr = c * 32 + vsrow;
                gload_lds16(Vbase + (size_t)vr * SL + ((kt + 1) << 6) + ((vchunk ^ (vr & 7)) << 3),
                            (char*)Vs[buf ^ 1] + (wave << 10) + c * 4096);
            }
        }
        // ---- mask (diag tile only) + row max ----
        float pm[4] = {-1e30f, -1e30f, -1e30f, -1e30f};
        if (kt == qt) {
            #pragma unroll
            for (int c = 0; c < 4; ++c) {
                int kkg = (kt << 6) + c * 16 + l15;
                #pragma unroll
                for (int r = 0; r < 4; ++r) {
                    int qg = qrow0 + kh * 4 + r;
                    float v = sfr[c][r];
                    v = (kkg > qg) ? -1e30f : v;
                    sfr[c][r] = v;
                    pm[r] = fmaxf(pm[r], v);
                }
            }
        } else {
            #pragma unroll
            for (int c = 0; c < 4; ++c)
                #pragma unroll
                for (int r = 0; r < 4; ++r) pm[r] = fmaxf(pm[r], sfr[c][r]);
        }
        #pragma unroll
        for (int off = 1; off < 16; off <<= 1)
            #pragma unroll
            for (int r = 0; r < 4; ++r) pm[r] = fmaxf(pm[r], __shfl_xor(pm[r], off, 64));
        // ---- defer-max (T13) ----
        bool ok = true;
        #pragma unroll
        for (int r = 0; r < 4; ++r) ok = ok && (pm[r] <= m[r] + 8.0f);
        if (!__all(ok)) {
            #pragma unroll
            for (int r = 0; r < 4; ++r) {
                float mn = fmaxf(m[r], pm[r]);
                float alpha = __expf(m[r] - mn);
                m[r] = mn;
                lsum[r] *= alpha;
                #pragma unroll
                for (int db = 0; db < 8; ++db) oacc[db][r] *= alpha;
            }
        }
        // ---- P = exp(S - m), row sums ----
        float rs[4] = {0.f, 0.f, 0.f, 0.f};
        #pragma unroll
        for (int c = 0; c < 4; ++c)
            #pragma unroll
            for (int r = 0; r < 4; ++r) {
                float p = __expf(sfr[c][r] - m[r]);
                sfr[c][r] = p;
                rs[r] += p;
            }
        #pragma unroll
        for (int off = 1; off < 16; off <<= 1)
            #pragma unroll
            for (int r = 0; r < 4; ++r) rs[r] += __shfl_xor(rs[r], off, 64);
        #pragma unroll
        for (int r = 0; r < 4; ++r) lsum[r] += rs[r];
        // ---- P -> per-wave LDS transpose, two chunks (same-wave DS in-order) ----
        short8 pa[2];
        #pragma unroll
        for (int half = 0; half < 2; ++half) {
            #pragma unroll
            for (int c = 0; c < 2; ++c)
                #pragma unroll
                for (int r = 0; r < 4; ++r)
                    Ps[wave][kh * 4 + r][c * 16 + l15] = f2bf(sfr[half * 2 + c][r]);
            pa[half] = *(const short8*)(&Ps[wave][l15][kh * 8]);
        }
        // ---- PV from Vs[buf] ----
        const char* vb = (const char*)Vs[buf];
        __builtin_amdgcn_s_setprio(1);
        #pragma unroll
        for (int db = 0; db < 8; ++db) {
            int vrow = db * 16 + l15;
            #pragma unroll
            for (int f = 0; f < 2; ++f) {
                short8 vf = *(const short8*)(vb + vrow * 128 + ((((f << 2) + kh) ^ (vrow & 7)) << 4));
                oacc[db] = mfma16(pa[f], vf, oacc[db]);
            }
        }
        __builtin_amdgcn_s_setprio(0);
        buf ^= 1;
    }
    #pragma unroll
    for (int db = 0; db < 8; ++db)
        #pragma unroll
        for (int r = 0; r < 4; ++r) {
            int qg = qrow0 + kh * 4 + r;
            float v = oacc[db][r] / lsum[r];
            O[((size_t)(b * SL) + qg) * HS + h * HD + db * 16 + l15] = f2bf(v);
        }
}

extern "C" void kernel_launch(void* const* d_in, const int* in_sizes, int n_in,
                              void* d_out, int out_size, void* d_ws, size_t ws_size,
                              hipStream_t stream)
{
    const float* X  = (const float*)d_in[0];
    const float* Wq = (const float*)d_in[1];
    const float* Wk = (const float*)d_in[2];
    const float* Wv = (const float*)d_in[3];
    const float* Wo = (const float*)d_in[4];
    float* out = (float*)d_out;
    const size_t SLAB = (size_t)NTOK * HS * 2;  // 32 MiB per bf16 slab
    char* ws = (char*)d_ws;
    unsigned short* Xb  = (unsigned short*)(ws + 0 * SLAB);
    unsigned short* Wqt = (unsigned short*)(ws + 1 * SLAB);  // Wqt|Wkt|Wvt contiguous = fused B^T
    unsigned short* Wot = (unsigned short*)(ws + 4 * SLAB);
    unsigned short* QKV = (unsigned short*)(ws + 5 * SLAB);  // 96 MiB: [4096][12288]
    unsigned short* Vtb = Xb;   // alias: Xb dead after fused QKV GEMM
    unsigned short* Ob  = Wqt;  // alias: W*t dead after fused QKV GEMM

    k_convert<<<2048, 256, 0, stream>>>(X, Xb, NTOK * HS / 8);
    k_transpose_w4<<<dim3(128, 128, 4), 256, 0, stream>>>(Wq, Wk, Wv, Wo, Wqt);
    // fused QKV projection: C[4096][12288] = Xb * [Wqt|Wkt|Wvt]^T  (16x48=768 tiles)
    k_gemm256<unsigned short><<<768, 512, 0, stream>>>(Xb, Wqt, QKV, NTOK, 3 * HS, HS);
    k_rope<<<NTOK * NH * 16 / 256, 256, 0, stream>>>(QKV);
    k_transpose_v<<<dim3(SL / 32, HD / 32, BS * NH), 256, 0, stream>>>(QKV, Vtb);
    k_attn<<<dim3(SL / 64, BS * NH), 256, 0, stream>>>(QKV, Vtb, Ob);
    // output projection: out[4096][4096] = Ob * Wot^T  (16x16=256 tiles)
    k_gemm256<float><<<256, 512, 0, stream>>>(Ob, Wot, out, NTOK, HS, HS);
}

// Round 6
// 875.983 us; speedup vs baseline: 1.7692x; 1.0557x over previous
//
#include <hip/hip_runtime.h>
#include <cstdint>
#include <cstddef>

#define SL 2048
#define BS 2
#define NH 32
#define HD 128
#define HS 4096
#define NTOK 4096   // BS*SL
#define LDQ 12288   // fused QKV row stride (3*HS)

typedef __attribute__((ext_vector_type(8))) short short8;
typedef __attribute__((ext_vector_type(4))) float f32x4;
typedef __attribute__((ext_vector_type(4))) unsigned short u16x4;
typedef __attribute__((ext_vector_type(8))) unsigned short u16x8;

static __device__ __forceinline__ unsigned short f2bf(float f) {
    unsigned int u = __builtin_bit_cast(unsigned int, f);
    u = u + 0x7FFFu + ((u >> 16) & 1u);   // RNE
    return (unsigned short)(u >> 16);
}
static __device__ __forceinline__ float bf2f(unsigned short h) {
    unsigned int u = ((unsigned int)h) << 16;
    return __builtin_bit_cast(float, u);
}

static __device__ __forceinline__ f32x4 mfma16(short8 a, short8 b, f32x4 c) {
    return __builtin_amdgcn_mfma_f32_16x16x32_bf16(a, b, c, 0, 0, 0);
}

static __device__ __forceinline__ void gload_lds16(const void* g, void* dst) {
    __builtin_amdgcn_global_load_lds(
        (const __attribute__((address_space(1))) unsigned int*)g,
        (__attribute__((address_space(3))) unsigned int*)dst,
        16, 0, 0);
}

// ---------------- fp32 -> bf16 convert (X) ----------------
__global__ void k_convert(const float* __restrict__ in, unsigned short* __restrict__ out, int n8) {
    int stride = gridDim.x * blockDim.x;
    for (int i = blockIdx.x * blockDim.x + threadIdx.x; i < n8; i += stride) {
        const f32x4* p = (const f32x4*)in + (size_t)i * 2;
        f32x4 a = p[0], b = p[1];
        u16x8 o;
        o[0] = f2bf(a[0]); o[1] = f2bf(a[1]); o[2] = f2bf(a[2]); o[3] = f2bf(a[3]);
        o[4] = f2bf(b[0]); o[5] = f2bf(b[1]); o[6] = f2bf(b[2]); o[7] = f2bf(b[3]);
        *((u16x8*)out + i) = o;
    }
}

// ---------------- fp32 W[k][n] -> bf16 Wt[n][k], 4 matrices in one launch ----------------
__global__ void k_transpose_w4(const float* __restrict__ w0, const float* __restrict__ w1,
                               const float* __restrict__ w2, const float* __restrict__ w3,
                               unsigned short* __restrict__ wtbase) {
    __shared__ float t[32][33];
    int z = blockIdx.z;
    const float* w = (z == 0) ? w0 : (z == 1) ? w1 : (z == 2) ? w2 : w3;
    unsigned short* wt = wtbase + (size_t)z * HS * HS;
    int r0 = blockIdx.y << 5, c0 = blockIdx.x << 5;
    int tr = threadIdx.x >> 3;
    int tc = (threadIdx.x & 7) << 2;
    f32x4 v = *(const f32x4*)(w + (size_t)(r0 + tr) * HS + c0 + tc);
    t[tr][tc + 0] = v[0]; t[tr][tc + 1] = v[1]; t[tr][tc + 2] = v[2]; t[tr][tc + 3] = v[3];
    __syncthreads();
    u16x4 o;
    o[0] = f2bf(t[tc + 0][tr]); o[1] = f2bf(t[tc + 1][tr]);
    o[2] = f2bf(t[tc + 2][tr]); o[3] = f2bf(t[tc + 3][tr]);
    *(u16x4*)(wt + (size_t)(c0 + tr) * HS + r0 + tc) = o;
}

// =====================================================================
// 256x256 8-phase bf16 GEMM (T2+T3+T4+T5): C[M][N] = A[M][K] * Bt[N][K]^T
// LDS tiles [128 rows][128 B]; FULL row swizzle: colbyte ^= (row&7)<<4
// (spreads each 8-lane read group across all eight 16B slots -> 2 lanes/bank,
// free per m136). Applied via inverse-swizzled global source (linear
// global_load_lds dst) + swizzled ds_read; k-slice offset XORed, not added.
// =====================================================================
#define REG(b, w) ((b) * 65536 + (w) * 16384)   // w: 0=A0 1=A1 2=B0 3=B1

template <typename OutT>
__global__ __launch_bounds__(512, 2) void k_gemm256(
    const unsigned short* __restrict__ A,
    const unsigned short* __restrict__ Bt,
    OutT* __restrict__ C,
    int M, int N, int K)
{
    __shared__ char lds[131072];
    char* ldsb = lds;
    int tiles_n = N >> 8;
    int bid = blockIdx.x;
    int q8 = gridDim.x >> 3;               // grid % 8 == 0 here
    bid = (bid & 7) * q8 + (bid >> 3);     // XCD-contiguous tile chunks (T1)
    int tm = bid / tiles_n, tn = bid % tiles_n;
    int tid = threadIdx.x, lane = tid & 63, wave = tid >> 6;
    int l15 = lane & 15, kh = lane >> 4;
    int wm = wave >> 2, wn = wave & 3;
    int row0 = tm << 8, col0 = tn << 8;
    f32x4 acc[8][4] = {};

    // staging: linear LDS dst (row sr, colbyte scb), inverse-swizzled source.
    // rows sr and sr+64 share (row&7), so one scol serves both halves.
    int sr = tid >> 3;
    int scb = (tid & 7) << 4;
    int scol = (scb ^ ((sr & 7) << 4)) >> 1;
    const unsigned short* Abase0 = A + (size_t)(row0 + sr) * K + scol;
    const unsigned short* Bbase0 = Bt + (size_t)(col0 + sr) * K + scol;

    // fragment read bases: read row ≡ l15 (mod 8) for every sub-read
    int rswz = (l15 & 7) << 4;
    int afb = wm * 16384 + l15 * 128 + ((kh * 16) ^ rswz);
    int bfb = 32768 + ((wn >> 1) * 16384) + (((wn & 1) * 64 + l15) * 128) + ((kh * 16) ^ rswz);

    short8 af[4][2], bfr[4][2];

#define STAGE(R, Gp) do { \
    gload_lds16((Gp),                ldsb + (R) + tid * 16); \
    gload_lds16((Gp) + (size_t)64 * K, ldsb + (R) + 8192 + tid * 16); } while (0)

#define READ_A(buf, g) { _Pragma("unroll") for (int mq = 0; mq < 4; ++mq) \
    _Pragma("unroll") for (int ks = 0; ks < 2; ++ks) \
        af[mq][ks] = *(const short8*)(ldsb + (buf) * 65536 + ((afb + (g) * 8192 + mq * 2048) ^ (ks * 64))); }

#define READ_B(buf) { _Pragma("unroll") for (int n = 0; n < 4; ++n) \
    _Pragma("unroll") for (int ks = 0; ks < 2; ++ks) \
        bfr[n][ks] = *(const short8*)(ldsb + (buf) * 65536 + ((bfb + n * 2048) ^ (ks * 64))); }

#define MFMA_Q(g, nh) { _Pragma("unroll") for (int mq = 0; mq < 4; ++mq) \
    _Pragma("unroll") for (int n2 = 0; n2 < 2; ++n2) { \
        acc[(g)*4+mq][(nh)*2+n2] = mfma16(af[mq][0], bfr[(nh)*2+n2][0], acc[(g)*4+mq][(nh)*2+n2]); \
        acc[(g)*4+mq][(nh)*2+n2] = mfma16(af[mq][1], bfr[(nh)*2+n2][1], acc[(g)*4+mq][(nh)*2+n2]); } }

#define LGKM0() do { asm volatile("s_waitcnt lgkmcnt(0)" ::: "memory"); \
                     __builtin_amdgcn_sched_barrier(0); } while (0)
#define BAR() __builtin_amdgcn_s_barrier()

    STAGE(REG(0, 2), Bbase0);
    STAGE(REG(0, 3), Bbase0 + (size_t)128 * K);
    STAGE(REG(0, 0), Abase0);
    STAGE(REG(0, 1), Abase0 + (size_t)128 * K);
    STAGE(REG(1, 2), Bbase0 + 64);
    STAGE(REG(1, 3), Bbase0 + (size_t)128 * K + 64);
    STAGE(REG(1, 0), Abase0 + 64);
    asm volatile("s_waitcnt vmcnt(6)" ::: "memory");
    BAR();

    int nkt = K >> 6;
    int niter = nkt >> 1;
    #pragma unroll 1
    for (int t = 0; t < niter; ++t) {
        int kt1 = 2 * t + 1, kt2 = 2 * t + 2, kt3 = 2 * t + 3;
        bool s2 = kt2 < nkt, s3 = kt3 < nkt;
        READ_B(0); READ_A(0, 0);
        STAGE(REG(1, 1), Abase0 + (size_t)128 * K + (size_t)kt1 * 64);
        BAR(); LGKM0();
        __builtin_amdgcn_s_setprio(1); MFMA_Q(0, 0); __builtin_amdgcn_s_setprio(0);
        BAR();
        if (s2) STAGE(REG(0, 2), Bbase0 + (size_t)kt2 * 64);
        BAR();
        __builtin_amdgcn_s_setprio(1); MFMA_Q(0, 1); __builtin_amdgcn_s_setprio(0);
        BAR();
        READ_A(0, 1);
        if (s2) STAGE(REG(0, 3), Bbase0 + (size_t)128 * K + (size_t)kt2 * 64);
        BAR(); LGKM0();
        __builtin_amdgcn_s_setprio(1); MFMA_Q(1, 0); __builtin_amdgcn_s_setprio(0);
        BAR();
        if (s2) STAGE(REG(0, 0), Abase0 + (size_t)kt2 * 64);
        BAR();
        __builtin_amdgcn_s_setprio(1); MFMA_Q(1, 1); __builtin_amdgcn_s_setprio(0);
        if (s2) { asm volatile("s_waitcnt vmcnt(6)" ::: "memory"); }
        else    { asm volatile("s_waitcnt vmcnt(0)" ::: "memory"); }
        BAR();
        READ_B(1); READ_A(1, 0);
        if (s2) STAGE(REG(0, 1), Abase0 + (size_t)128 * K + (size_t)kt2 * 64);
        BAR(); LGKM0();
        __builtin_amdgcn_s_setprio(1); MFMA_Q(0, 0); __builtin_amdgcn_s_setprio(0);
        BAR();
        if (s3) STAGE(REG(1, 2), Bbase0 + (size_t)kt3 * 64);
        BAR();
        __builtin_amdgcn_s_setprio(1); MFMA_Q(0, 1); __builtin_amdgcn_s_setprio(0);
        BAR();
        READ_A(1, 1);
        if (s3) STAGE(REG(1, 3), Bbase0 + (size_t)128 * K + (size_t)kt3 * 64);
        BAR(); LGKM0();
        __builtin_amdgcn_s_setprio(1); MFMA_Q(1, 0); __builtin_amdgcn_s_setprio(0);
        BAR();
        if (s3) STAGE(REG(1, 0), Abase0 + (size_t)kt3 * 64);
        BAR();
        __builtin_amdgcn_s_setprio(1); MFMA_Q(1, 1); __builtin_amdgcn_s_setprio(0);
        if (s3) { asm volatile("s_waitcnt vmcnt(6)" ::: "memory"); }
        else    { asm volatile("s_waitcnt vmcnt(0)" ::: "memory"); }
        BAR();
    }

    #pragma unroll
    for (int m = 0; m < 8; ++m)
        #pragma unroll
        for (int n = 0; n < 4; ++n)
            #pragma unroll
            for (int rr = 0; rr < 4; ++rr) {
                int row = row0 + wm * 128 + m * 16 + kh * 4 + rr;
                int col = col0 + wn * 64 + n * 16 + l15;
                float v = acc[m][n][rr];
                if constexpr (sizeof(OutT) == 2) C[(size_t)row * N + col] = (OutT)f2bf(v);
                else                             C[(size_t)row * N + col] = v;
            }
#undef STAGE
#undef READ_A
#undef READ_B
#undef MFMA_Q
#undef LGKM0
#undef BAR
}

// ---------------- RoPE on Q (pre-scaled by 1/sqrt(hd)) and K, in the fused QKV buffer ----------------
__global__ void k_rope(unsigned short* __restrict__ QKV) {
    const float SCALE = 0.08838834764831845f;  // 1/sqrt(128)
    int i = blockIdx.x * blockDim.x + threadIdx.x;
    int q4 = i & 15;
    int head = (i >> 4) & (NH - 1);
    int tok = i >> 9;
    int s = tok & (SL - 1);
    int d0 = q4 << 2;
    size_t base = (size_t)tok * LDQ + head * HD;
    unsigned short* Q = QKV + base;
    unsigned short* K = QKV + base + HS;
    float cs[4], sn[4];
    #pragma unroll
    for (int j = 0; j < 4; j++) {
        float invf = expf(-(float)(d0 + j) * 0.14391156831212787f);  // ln(1e4)/64
        float ang = (float)s * invf;
        sn[j] = sinf(ang); cs[j] = cosf(ang);
    }
    {
        u16x4 lo = *(u16x4*)(Q + d0);
        u16x4 hi = *(u16x4*)(Q + d0 + 64);
        u16x4 nlo, nhi;
        #pragma unroll
        for (int j = 0; j < 4; j++) {
            float x0 = bf2f(lo[j]), x1 = bf2f(hi[j]);
            nlo[j] = f2bf((x0 * cs[j] - x1 * sn[j]) * SCALE);
            nhi[j] = f2bf((x1 * cs[j] + x0 * sn[j]) * SCALE);
        }
        *(u16x4*)(Q + d0) = nlo;
        *(u16x4*)(Q + d0 + 64) = nhi;
    }
    {
        u16x4 lo = *(u16x4*)(K + d0);
        u16x4 hi = *(u16x4*)(K + d0 + 64);
        u16x4 nlo, nhi;
        #pragma unroll
        for (int j = 0; j < 4; j++) {
            float x0 = bf2f(lo[j]), x1 = bf2f(hi[j]);
            nlo[j] = f2bf(x0 * cs[j] - x1 * sn[j]);
            nhi[j] = f2bf(x1 * cs[j] + x0 * sn[j]);
        }
        *(u16x4*)(K + d0) = nlo;
        *(u16x4*)(K + d0 + 64) = nhi;
    }
}

// ---------------- V (from QKV) -> Vt ((b,h), d, s) ----------------
__global__ void k_transpose_v(const unsigned short* __restrict__ QKV, unsigned short* __restrict__ Vt) {
    __shared__ unsigned short t[32][36];
    int bh = blockIdx.z; int b = bh >> 5, h = bh & 31;
    int s0 = blockIdx.x << 5, d0 = blockIdx.y << 5;
    int tr = threadIdx.x >> 3, tc = (threadIdx.x & 7) << 2;
    u16x4 v = *(const u16x4*)(QKV + (size_t)(b * SL + s0 + tr) * LDQ + 2 * HS + h * HD + d0 + tc);
    t[tr][tc + 0] = v[0]; t[tr][tc + 1] = v[1]; t[tr][tc + 2] = v[2]; t[tr][tc + 3] = v[3];
    __syncthreads();
    u16x4 o;
    o[0] = t[tc + 0][tr]; o[1] = t[tc + 1][tr]; o[2] = t[tc + 2][tr]; o[3] = t[tc + 3][tr];
    *(u16x4*)(Vt + ((size_t)(b * NH + h) * HD + d0 + tr) * SL + s0 + tc) = o;
}

// ---------------- causal flash attention v5 (unchanged from round 5) ----------------
__global__ __launch_bounds__(256, 4) void k_attn(
    const unsigned short* __restrict__ QKV,
    const unsigned short* __restrict__ Vt,
    unsigned short* __restrict__ O)
{
    __shared__ unsigned short Ks[64 * 128];      // [kk][d], chunk-swizzled
    __shared__ unsigned short Vs[2][128 * 64];   // [buf][d][kk], chunk-swizzled
    __shared__ unsigned short Ps[4][16][36];     // per-wave P transpose, 2 chunks of 32 cols
    int qt = (int)(gridDim.x - 1) - (int)blockIdx.x;  // big blocks first
    int bh = blockIdx.y;
    int b = bh >> 5, h = bh & 31;
    int tid = threadIdx.x, lane = tid & 63, wave = tid >> 6;
    int l15 = lane & 15, kh = lane >> 4;
    int qrow0 = (qt << 6) + (wave << 4);
    short8 qf[4];
    {
        const unsigned short* qp = QKV + ((size_t)(b * SL) + qrow0 + l15) * LDQ + h * HD + kh * 8;
        #pragma unroll
        for (int f = 0; f < 4; ++f) qf[f] = *(const short8*)(qp + f * 32);
    }
    f32x4 oacc[8] = {};
    float m[4] = {-1e30f, -1e30f, -1e30f, -1e30f};
    float lsum[4] = {0.f, 0.f, 0.f, 0.f};
    int ksrow = tid >> 4, kchunk = tid & 15;
    int vsrow = tid >> 3, vchunk = tid & 7;
    const unsigned short* Kbase = QKV + HS + (size_t)(b * SL) * LDQ + h * HD;
    const unsigned short* Vbase = Vt + (size_t)(b * NH + h) * HD * (size_t)SL;
    char* KsW = (char*)Ks + (wave << 10);

    #pragma unroll
    for (int c = 0; c < 4; ++c) {
        int kr = c * 16 + ksrow;
        gload_lds16(Kbase + (size_t)kr * LDQ + ((kchunk ^ (kr & 7)) << 3), KsW + c * 4096);
        int vr = c * 32 + vsrow;
        gload_lds16(Vbase + (size_t)vr * SL + ((vchunk ^ (vr & 7)) << 3),
                    (char*)Vs[0] + (wave << 10) + c * 4096);
    }
    int buf = 0;
    for (int kt = 0; kt <= qt; ++kt) {
        __syncthreads();
        f32x4 sfr[4];
        __builtin_amdgcn_s_setprio(1);
        #pragma unroll
        for (int c = 0; c < 4; ++c) {
            f32x4 acc = {};
            int krow = c * 16 + l15;
            #pragma unroll
            for (int f = 0; f < 4; ++f) {
                short8 kf = *(const short8*)((const char*)Ks + krow * 256 + ((((f << 2) + kh) ^ (krow & 7)) << 4));
                acc = mfma16(qf[f], kf, acc);
            }
            sfr[c] = acc;
        }
        __builtin_amdgcn_s_setprio(0);
        __syncthreads();
        if (kt < qt) {
            #pragma unroll
            for (int c = 0; c < 4; ++c) {
                int kr = c * 16 + ksrow;
                gload_lds16(Kbase + (size_t)(((kt + 1) << 6) + kr) * LDQ + ((kchunk ^ (kr & 7)) << 3),
                            KsW + c * 4096);
                int vr = c * 32 + vsrow;
                gload_lds16(Vbase + (size_t)vr * SL + ((kt + 1) << 6) + ((vchunk ^ (vr & 7)) << 3),
                            (char*)Vs[buf ^ 1] + (wave << 10) + c * 4096);
            }
        }
        float pm[4] = {-1e30f, -1e30f, -1e30f, -1e30f};
        if (kt == qt) {
            #pragma unroll
            for (int c = 0; c < 4; ++c) {
                int kkg = (kt << 6) + c * 16 + l15;
                #pragma unroll
                for (int r = 0; r < 4; ++r) {
                    int qg = qrow0 + kh * 4 + r;
                    float v = sfr[c][r];
                    v = (kkg > qg) ? -1e30f : v;
                    sfr[c][r] = v;
                    pm[r] = fmaxf(pm[r], v);
                }
            }
        } else {
            #pragma unroll
            for (int c = 0; c < 4; ++c)
                #pragma unroll
                for (int r = 0; r < 4; ++r) pm[r] = fmaxf(pm[r], sfr[c][r]);
        }
        #pragma unroll
        for (int off = 1; off < 16; off <<= 1)
            #pragma unroll
            for (int r = 0; r < 4; ++r) pm[r] = fmaxf(pm[r], __shfl_xor(pm[r], off, 64));
        bool ok = true;
        #pragma unroll
        for (int r = 0; r < 4; ++r) ok = ok && (pm[r] <= m[r] + 8.0f);
        if (!__all(ok)) {
            #pragma unroll
            for (int r = 0; r < 4; ++r) {
                float mn = fmaxf(m[r], pm[r]);
                float alpha = __expf(m[r] - mn);
                m[r] = mn;
                lsum[r] *= alpha;
                #pragma unroll
                for (int db = 0; db < 8; ++db) oacc[db][r] *= alpha;
            }
        }
        float rs[4] = {0.f, 0.f, 0.f, 0.f};
        #pragma unroll
        for (int c = 0; c < 4; ++c)
            #pragma unroll
            for (int r = 0; r < 4; ++r) {
                float p = __expf(sfr[c][r] - m[r]);
                sfr[c][r] = p;
                rs[r] += p;
            }
        #pragma unroll
        for (int off = 1; off < 16; off <<= 1)
            #pragma unroll
            for (int r = 0; r < 4; ++r) rs[r] += __shfl_xor(rs[r], off, 64);
        #pragma unroll
        for (int r = 0; r < 4; ++r) lsum[r] += rs[r];
        short8 pa[2];
        #pragma unroll
        for (int half = 0; half < 2; ++half) {
            #pragma unroll
            for (int c = 0; c < 2; ++c)
                #pragma unroll
                for (int r = 0; r < 4; ++r)
                    Ps[wave][kh * 4 + r][c * 16 + l15] = f2bf(sfr[half * 2 + c][r]);
            pa[half] = *(const short8*)(&Ps[wave][l15][kh * 8]);
        }
        const char* vb = (const char*)Vs[buf];
        __builtin_amdgcn_s_setprio(1);
        #pragma unroll
        for (int db = 0; db < 8; ++db) {
            int vrow = db * 16 + l15;
            #pragma unroll
            for (int f = 0; f < 2; ++f) {
                short8 vf = *(const short8*)(vb + vrow * 128 + ((((f << 2) + kh) ^ (vrow & 7)) << 4));
                oacc[db] = mfma16(pa[f], vf, oacc[db]);
            }
        }
        __builtin_amdgcn_s_setprio(0);
        buf ^= 1;
    }
    #pragma unroll
    for (int db = 0; db < 8; ++db)
        #pragma unroll
        for (int r = 0; r < 4; ++r) {
            int qg = qrow0 + kh * 4 + r;
            float v = oacc[db][r] / lsum[r];
            O[((size_t)(b * SL) + qg) * HS + h * HD + db * 16 + l15] = f2bf(v);
        }
}

extern "C" void kernel_launch(void* const* d_in, const int* in_sizes, int n_in,
                              void* d_out, int out_size, void* d_ws, size_t ws_size,
                              hipStream_t stream)
{
    const float* X  = (const float*)d_in[0];
    const float* Wq = (const float*)d_in[1];
    const float* Wk = (const float*)d_in[2];
    const float* Wv = (const float*)d_in[3];
    const float* Wo = (const float*)d_in[4];
    float* out = (float*)d_out;
    const size_t SLAB = (size_t)NTOK * HS * 2;  // 32 MiB per bf16 slab
    char* ws = (char*)d_ws;
    unsigned short* Xb  = (unsigned short*)(ws + 0 * SLAB);
    unsigned short* Wqt = (unsigned short*)(ws + 1 * SLAB);  // Wqt|Wkt|Wvt contiguous = fused B^T
    unsigned short* Wot = (unsigned short*)(ws + 4 * SLAB);
    unsigned short* QKV = (unsigned short*)(ws + 5 * SLAB);  // 96 MiB: [4096][12288]
    unsigned short* Vtb = Xb;   // alias: Xb dead after fused QKV GEMM
    unsigned short* Ob  = Wqt;  // alias: W*t dead after fused QKV GEMM

    k_convert<<<2048, 256, 0, stream>>>(X, Xb, NTOK * HS / 8);
    k_transpose_w4<<<dim3(128, 128, 4), 256, 0, stream>>>(Wq, Wk, Wv, Wo, Wqt);
    // fused QKV projection: C[4096][12288] = Xb * [Wqt|Wkt|Wvt]^T  (16x48=768 tiles)
    k_gemm256<unsigned short><<<768, 512, 0, stream>>>(Xb, Wqt, QKV, NTOK, 3 * HS, HS);
    k_rope<<<NTOK * NH * 16 / 256, 256, 0, stream>>>(QKV);
    k_transpose_v<<<dim3(SL / 32, HD / 32, BS * NH), 256, 0, stream>>>(QKV, Vtb);
    k_attn<<<dim3(SL / 64, BS * NH), 256, 0, stream>>>(QKV, Vtb, Ob);
    // output projection: out[4096][4096] = Ob * Wot^T  (16x16=256 tiles)
    k_gemm256<float><<<256, 512, 0, stream>>>(Ob, Wot, out, NTOK, HS, HS);
}

// Round 9
// 870.879 us; speedup vs baseline: 1.7796x; 1.0059x over previous
//
#include <hip/hip_runtime.h>
#include <cstdint>
#include <cstddef>

#define SL 2048
#define BS 2
#define NH 32
#define HD 128
#define HS 4096
#define NTOK 4096   // BS*SL
#define LDQ 12288   // fused QKV row stride (3*HS)

typedef __attribute__((ext_vector_type(8))) short short8;
typedef __attribute__((ext_vector_type(4))) float f32x4;
typedef __attribute__((ext_vector_type(4))) unsigned short u16x4;
typedef __attribute__((ext_vector_type(8))) unsigned short u16x8;

static __device__ __forceinline__ unsigned short f2bf(float f) {
    unsigned int u = __builtin_bit_cast(unsigned int, f);
    u = u + 0x7FFFu + ((u >> 16) & 1u);   // RNE
    return (unsigned short)(u >> 16);
}
static __device__ __forceinline__ float bf2f(unsigned short h) {
    unsigned int u = ((unsigned int)h) << 16;
    return __builtin_bit_cast(float, u);
}
static __device__ __forceinline__ float fexp2(float x) {
    return __builtin_amdgcn_exp2f(x);   // v_exp_f32 (base-2)
}

static __device__ __forceinline__ f32x4 mfma16(short8 a, short8 b, f32x4 c) {
    return __builtin_amdgcn_mfma_f32_16x16x32_bf16(a, b, c, 0, 0, 0);
}

static __device__ __forceinline__ void gload_lds16(const void* g, void* dst) {
    __builtin_amdgcn_global_load_lds(
        (const __attribute__((address_space(1))) unsigned int*)g,
        (__attribute__((address_space(3))) unsigned int*)dst,
        16, 0, 0);
}

// ---------------- fp32 -> bf16 convert (X) ----------------
__global__ void k_convert(const float* __restrict__ in, unsigned short* __restrict__ out, int n8) {
    int stride = gridDim.x * blockDim.x;
    for (int i = blockIdx.x * blockDim.x + threadIdx.x; i < n8; i += stride) {
        const f32x4* p = (const f32x4*)in + (size_t)i * 2;
        f32x4 a = p[0], b = p[1];
        u16x8 o;
        o[0] = f2bf(a[0]); o[1] = f2bf(a[1]); o[2] = f2bf(a[2]); o[3] = f2bf(a[3]);
        o[4] = f2bf(b[0]); o[5] = f2bf(b[1]); o[6] = f2bf(b[2]); o[7] = f2bf(b[3]);
        *((u16x8*)out + i) = o;
    }
}

// ---------------- fp32 W[k][n] -> bf16 Wt[n][k], 4 matrices in one launch ----------------
__global__ void k_transpose_w4(const float* __restrict__ w0, const float* __restrict__ w1,
                               const float* __restrict__ w2, const float* __restrict__ w3,
                               unsigned short* __restrict__ wtbase) {
    __shared__ float t[32][33];
    int z = blockIdx.z;
    const float* w = (z == 0) ? w0 : (z == 1) ? w1 : (z == 2) ? w2 : w3;
    unsigned short* wt = wtbase + (size_t)z * HS * HS;
    int r0 = blockIdx.y << 5, c0 = blockIdx.x << 5;
    int tr = threadIdx.x >> 3;
    int tc = (threadIdx.x & 7) << 2;
    f32x4 v = *(const f32x4*)(w + (size_t)(r0 + tr) * HS + c0 + tc);
    t[tr][tc + 0] = v[0]; t[tr][tc + 1] = v[1]; t[tr][tc + 2] = v[2]; t[tr][tc + 3] = v[3];
    __syncthreads();
    u16x4 o;
    o[0] = f2bf(t[tc + 0][tr]); o[1] = f2bf(t[tc + 1][tr]);
    o[2] = f2bf(t[tc + 2][tr]); o[3] = f2bf(t[tc + 3][tr]);
    *(u16x4*)(wt + (size_t)(c0 + tr) * HS + r0 + tc) = o;
}

// =====================================================================
// 256x256 8-phase bf16 GEMM: C[M][N] = A[M][K] * Bt[N][K]^T
// ds_reads 12/4/8/0 per tile's 4 phases. Region liveness (wm/wn split!):
//   B0,B1 of buf read in ph1+ph2 (buf0) / ph5+ph6 (buf1)
//   A0,A1 of buf read in ph1+ph3 (buf0) / ph5+ph7 (buf1)
// Stage schedule (each stage >=1 phase after its region's last read):
//   ph1:A0(b1,2t+1) ph2:A1(b1,2t+1) ph3:B0(b0,2t+2) ph4:B1(b0,2t+2)
//   ph5:A0(b0,2t+2) ph6:A1(b0,2t+2) ph7:B0(b1,2t+3) ph8:B1(b1,2t+3)
// vmcnt(4) at ph4 retires through ph2 (buf1 tile complete before ph5);
// vmcnt(4) at ph8 retires through ph6 (buf0 tile complete before ph1').
// Full row swizzle colbyte ^= (row&7)<<4; conflicts measured 0.
// =====================================================================
#define REG(b, w) ((b) * 65536 + (w) * 16384)   // w: 0=A0 1=A1 2=B0 3=B1

template <typename OutT>
__global__ __launch_bounds__(512, 2) void k_gemm256(
    const unsigned short* __restrict__ A,
    const unsigned short* __restrict__ Bt,
    OutT* __restrict__ C,
    int M, int N, int K)
{
    __shared__ char lds[131072];
    char* ldsb = lds;
    int tiles_n = N >> 8;
    int bid = blockIdx.x;
    int q8 = gridDim.x >> 3;               // grid % 8 == 0 here
    bid = (bid & 7) * q8 + (bid >> 3);     // XCD-contiguous tile chunks (T1)
    int tm = bid / tiles_n, tn = bid % tiles_n;
    int tid = threadIdx.x, lane = tid & 63, wave = tid >> 6;
    int l15 = lane & 15, kh = lane >> 4;
    int wm = wave >> 2, wn = wave & 3;
    int row0 = tm << 8, col0 = tn << 8;
    f32x4 acc[8][4] = {};

    int sr = tid >> 3;
    int scb = (tid & 7) << 4;
    int scol = (scb ^ ((sr & 7) << 4)) >> 1;
    const unsigned short* Abase0 = A + (size_t)(row0 + sr) * K + scol;
    const unsigned short* Bbase0 = Bt + (size_t)(col0 + sr) * K + scol;

    int rswz = (l15 & 7) << 4;
    int afb = wm * 16384 + l15 * 128 + ((kh * 16) ^ rswz);
    int bfb = 32768 + ((wn >> 1) * 16384) + (((wn & 1) * 64 + l15) * 128) + ((kh * 16) ^ rswz);

    short8 af[4][2], bfr[4][2];

#define STAGE(R, Gp) do { \
    gload_lds16((Gp),                ldsb + (R) + tid * 16); \
    gload_lds16((Gp) + (size_t)64 * K, ldsb + (R) + 8192 + tid * 16); } while (0)

#define READ_A(buf, g) { _Pragma("unroll") for (int mq = 0; mq < 4; ++mq) \
    _Pragma("unroll") for (int ks = 0; ks < 2; ++ks) \
        af[mq][ks] = *(const short8*)(ldsb + (buf) * 65536 + ((afb + (g) * 8192 + mq * 2048) ^ (ks * 64))); }

#define READ_B2(buf, p) { _Pragma("unroll") for (int n = 2*(p); n < 2*(p)+2; ++n) \
    _Pragma("unroll") for (int ks = 0; ks < 2; ++ks) \
        bfr[n][ks] = *(const short8*)(ldsb + (buf) * 65536 + ((bfb + n * 2048) ^ (ks * 64))); }

#define MFMA_Q(g, nh) { _Pragma("unroll") for (int mq = 0; mq < 4; ++mq) \
    _Pragma("unroll") for (int n2 = 0; n2 < 2; ++n2) { \
        acc[(g)*4+mq][(nh)*2+n2] = mfma16(af[mq][0], bfr[(nh)*2+n2][0], acc[(g)*4+mq][(nh)*2+n2]); \
        acc[(g)*4+mq][(nh)*2+n2] = mfma16(af[mq][1], bfr[(nh)*2+n2][1], acc[(g)*4+mq][(nh)*2+n2]); } }

#define LGKM0() do { asm volatile("s_waitcnt lgkmcnt(0)" ::: "memory"); \
                     __builtin_amdgcn_sched_barrier(0); } while (0)
#define LGKM8() asm volatile("s_waitcnt lgkmcnt(8)" ::: "memory")
#define BAR() __builtin_amdgcn_s_barrier()
#define PRIO1() __builtin_amdgcn_s_setprio(1)
#define PRIO0() __builtin_amdgcn_s_setprio(0)

    // prologue: buf0 full tile0 + buf1 {B0,B1} of tile1 (12 loads)
    STAGE(REG(0, 2), Bbase0);
    STAGE(REG(0, 3), Bbase0 + (size_t)128 * K);
    STAGE(REG(0, 0), Abase0);
    STAGE(REG(0, 1), Abase0 + (size_t)128 * K);
    STAGE(REG(1, 2), Bbase0 + 64);
    STAGE(REG(1, 3), Bbase0 + (size_t)128 * K + 64);
    asm volatile("s_waitcnt vmcnt(4)" ::: "memory");
    BAR();

    int nkt = K >> 6;
    int niter = nkt >> 1;
    #pragma unroll 1
    for (int t = 0; t < niter; ++t) {
        int kt1 = 2 * t + 1, kt2 = 2 * t + 2, kt3 = 2 * t + 3;
        bool s2 = kt2 < nkt, s3 = kt3 < nkt;
        // ---- phase 1 (tile 2t, buf0): 12 ds_reads; stage A0(b1,kt1) ----
        READ_B2(0, 0); READ_A(0, 0);
        STAGE(REG(1, 0), Abase0 + (size_t)kt1 * 64);
        LGKM8();
        BAR(); LGKM0();
        PRIO1(); MFMA_Q(0, 0); PRIO0();
        BAR();
        // ---- phase 2: 4 ds_reads; stage A1(b1,kt1) ----
        READ_B2(0, 1);
        STAGE(REG(1, 1), Abase0 + (size_t)128 * K + (size_t)kt1 * 64);
        BAR(); LGKM0();
        PRIO1(); MFMA_Q(0, 1); PRIO0();
        BAR();
        // ---- phase 3: 8 ds_reads; stage B0(b0,kt2) ----
        READ_A(0, 1);
        if (s2) STAGE(REG(0, 2), Bbase0 + (size_t)kt2 * 64);
        BAR(); LGKM0();
        PRIO1(); MFMA_Q(1, 0); PRIO0();
        BAR();
        // ---- phase 4: 0 ds_reads; stage B1(b0,kt2); vmcnt ----
        if (s2) STAGE(REG(0, 3), Bbase0 + (size_t)128 * K + (size_t)kt2 * 64);
        BAR();
        PRIO1(); MFMA_Q(1, 1); PRIO0();
        if (s2) { asm volatile("s_waitcnt vmcnt(4)" ::: "memory"); }
        else    { asm volatile("s_waitcnt vmcnt(0)" ::: "memory"); }
        BAR();
        // ---- phase 5 (tile 2t+1, buf1): 12 ds_reads; stage A0(b0,kt2) ----
        READ_B2(1, 0); READ_A(1, 0);
        if (s2) STAGE(REG(0, 0), Abase0 + (size_t)kt2 * 64);
        LGKM8();
        BAR(); LGKM0();
        PRIO1(); MFMA_Q(0, 0); PRIO0();
        BAR();
        // ---- phase 6: 4 ds_reads; stage A1(b0,kt2) ----
        READ_B2(1, 1);
        if (s2) STAGE(REG(0, 1), Abase0 + (size_t)128 * K + (size_t)kt2 * 64);
        BAR(); LGKM0();
        PRIO1(); MFMA_Q(0, 1); PRIO0();
        BAR();
        // ---- phase 7: 8 ds_reads; stage B0(b1,kt3) ----
        READ_A(1, 1);
        if (s3) STAGE(REG(1, 2), Bbase0 + (size_t)kt3 * 64);
        BAR(); LGKM0();
        PRIO1(); MFMA_Q(1, 0); PRIO0();
        BAR();
        // ---- phase 8: 0 ds_reads; stage B1(b1,kt3); vmcnt ----
        if (s3) STAGE(REG(1, 3), Bbase0 + (size_t)128 * K + (size_t)kt3 * 64);
        BAR();
        PRIO1(); MFMA_Q(1, 1); PRIO0();
        if (s3) { asm volatile("s_waitcnt vmcnt(4)" ::: "memory"); }
        else    { asm volatile("s_waitcnt vmcnt(0)" ::: "memory"); }
        BAR();
    }

    #pragma unroll
    for (int m = 0; m < 8; ++m)
        #pragma unroll
        for (int n = 0; n < 4; ++n)
            #pragma unroll
            for (int rr = 0; rr < 4; ++rr) {
                int row = row0 + wm * 128 + m * 16 + kh * 4 + rr;
                int col = col0 + wn * 64 + n * 16 + l15;
                float v = acc[m][n][rr];
                if constexpr (sizeof(OutT) == 2) C[(size_t)row * N + col] = (OutT)f2bf(v);
                else                             C[(size_t)row * N + col] = v;
            }
#undef STAGE
#undef READ_A
#undef READ_B2
#undef MFMA_Q
#undef LGKM0
#undef LGKM8
#undef BAR
#undef PRIO1
#undef PRIO0
}

// ---------------- RoPE; Q pre-scaled by log2(e)/sqrt(hd) for exp2 softmax ----------------
__global__ void k_rope(unsigned short* __restrict__ QKV) {
    const float SCALE = 0.12751779544166854f;  // (1/sqrt(128)) * log2(e)
    int i = blockIdx.x * blockDim.x + threadIdx.x;
    int q4 = i & 15;
    int head = (i >> 4) & (NH - 1);
    int tok = i >> 9;
    int s = tok & (SL - 1);
    int d0 = q4 << 2;
    size_t base = (size_t)tok * LDQ + head * HD;
    unsigned short* Q = QKV + base;
    unsigned short* K = QKV + base + HS;
    float cs[4], sn[4];
    #pragma unroll
    for (int j = 0; j < 4; j++) {
        float invf = expf(-(float)(d0 + j) * 0.14391156831212787f);  // ln(1e4)/64
        float ang = (float)s * invf;
        sn[j] = sinf(ang); cs[j] = cosf(ang);
    }
    {
        u16x4 lo = *(u16x4*)(Q + d0);
        u16x4 hi = *(u16x4*)(Q + d0 + 64);
        u16x4 nlo, nhi;
        #pragma unroll
        for (int j = 0; j < 4; j++) {
            float x0 = bf2f(lo[j]), x1 = bf2f(hi[j]);
            nlo[j] = f2bf((x0 * cs[j] - x1 * sn[j]) * SCALE);
            nhi[j] = f2bf((x1 * cs[j] + x0 * sn[j]) * SCALE);
        }
        *(u16x4*)(Q + d0) = nlo;
        *(u16x4*)(Q + d0 + 64) = nhi;
    }
    {
        u16x4 lo = *(u16x4*)(K + d0);
        u16x4 hi = *(u16x4*)(K + d0 + 64);
        u16x4 nlo, nhi;
        #pragma unroll
        for (int j = 0; j < 4; j++) {
            float x0 = bf2f(lo[j]), x1 = bf2f(hi[j]);
            nlo[j] = f2bf(x0 * cs[j] - x1 * sn[j]);
            nhi[j] = f2bf(x1 * cs[j] + x0 * sn[j]);
        }
        *(u16x4*)(K + d0) = nlo;
        *(u16x4*)(K + d0 + 64) = nhi;
    }
}

// ---------------- V (from QKV) -> Vt ((b,h), d, s) ----------------
__global__ void k_transpose_v(const unsigned short* __restrict__ QKV, unsigned short* __restrict__ Vt) {
    __shared__ unsigned short t[32][36];
    int bh = blockIdx.z; int b = bh >> 5, h = bh & 31;
    int s0 = blockIdx.x << 5, d0 = blockIdx.y << 5;
    int tr = threadIdx.x >> 3, tc = (threadIdx.x & 7) << 2;
    u16x4 v = *(const u16x4*)(QKV + (size_t)(b * SL + s0 + tr) * LDQ + 2 * HS + h * HD + d0 + tc);
    t[tr][tc + 0] = v[0]; t[tr][tc + 1] = v[1]; t[tr][tc + 2] = v[2]; t[tr][tc + 3] = v[3];
    __syncthreads();
    u16x4 o;
    o[0] = t[tc + 0][tr]; o[1] = t[tc + 1][tr]; o[2] = t[tc + 2][tr]; o[3] = t[tc + 3][tr];
    *(u16x4*)(Vt + ((size_t)(b * NH + h) * HD + d0 + tr) * SL + s0 + tc) = o;
}

// ---------------- causal flash attention v5.1 (exp2 softmax) ----------------
__global__ __launch_bounds__(256, 4) void k_attn(
    const unsigned short* __restrict__ QKV,
    const unsigned short* __restrict__ Vt,
    unsigned short* __restrict__ O)
{
    __shared__ unsigned short Ks[64 * 128];      // [kk][d], chunk-swizzled
    __shared__ unsigned short Vs[2][128 * 64];   // [buf][d][kk], chunk-swizzled
    __shared__ unsigned short Ps[4][16][36];     // per-wave P transpose, 2 chunks of 32 cols
    int qt = (int)(gridDim.x - 1) - (int)blockIdx.x;  // big blocks first
    int bh = blockIdx.y;
    int b = bh >> 5, h = bh & 31;
    int tid = threadIdx.x, lane = tid & 63, wave = tid >> 6;
    int l15 = lane & 15, kh = lane >> 4;
    int qrow0 = (qt << 6) + (wave << 4);
    short8 qf[4];
    {
        const unsigned short* qp = QKV + ((size_t)(b * SL) + qrow0 + l15) * LDQ + h * HD + kh * 8;
        #pragma unroll
        for (int f = 0; f < 4; ++f) qf[f] = *(const short8*)(qp + f * 32);
    }
    f32x4 oacc[8] = {};
    float m[4] = {-1e30f, -1e30f, -1e30f, -1e30f};
    float lsum[4] = {0.f, 0.f, 0.f, 0.f};
    int ksrow = tid >> 4, kchunk = tid & 15;
    int vsrow = tid >> 3, vchunk = tid & 7;
    const unsigned short* Kbase = QKV + HS + (size_t)(b * SL) * LDQ + h * HD;
    const unsigned short* Vbase = Vt + (size_t)(b * NH + h) * HD * (size_t)SL;
    char* KsW = (char*)Ks + (wave << 10);

    #pragma unroll
    for (int c = 0; c < 4; ++c) {
        int kr = c * 16 + ksrow;
        gload_lds16(Kbase + (size_t)kr * LDQ + ((kchunk ^ (kr & 7)) << 3), KsW + c * 4096);
        int vr = c * 32 + vsrow;
        gload_lds16(Vbase + (size_t)vr * SL + ((vchunk ^ (vr & 7)) << 3),
                    (char*)Vs[0] + (wave << 10) + c * 4096);
    }
    int buf = 0;
    for (int kt = 0; kt <= qt; ++kt) {
        __syncthreads();
        f32x4 sfr[4];
        __builtin_amdgcn_s_setprio(1);
        #pragma unroll
        for (int c = 0; c < 4; ++c) {
            f32x4 acc = {};
            int krow = c * 16 + l15;
            #pragma unroll
            for (int f = 0; f < 4; ++f) {
                short8 kf = *(const short8*)((const char*)Ks + krow * 256 + ((((f << 2) + kh) ^ (krow & 7)) << 4));
                acc = mfma16(qf[f], kf, acc);
            }
            sfr[c] = acc;
        }
        __builtin_amdgcn_s_setprio(0);
        __syncthreads();
        if (kt < qt) {
            #pragma unroll
            for (int c = 0; c < 4; ++c) {
                int kr = c * 16 + ksrow;
                gload_lds16(Kbase + (size_t)(((kt + 1) << 6) + kr) * LDQ + ((kchunk ^ (kr & 7)) << 3),
                            KsW + c * 4096);
                int vr = c * 32 + vsrow;
                gload_lds16(Vbase + (size_t)vr * SL + ((kt + 1) << 6) + ((vchunk ^ (vr & 7)) << 3),
                            (char*)Vs[buf ^ 1] + (wave << 10) + c * 4096);
            }
        }
        float pm[4] = {-1e30f, -1e30f, -1e30f, -1e30f};
        if (kt == qt) {
            #pragma unroll
            for (int c = 0; c < 4; ++c) {
                int kkg = (kt << 6) + c * 16 + l15;
                #pragma unroll
                for (int r = 0; r < 4; ++r) {
                    int qg = qrow0 + kh * 4 + r;
                    float v = sfr[c][r];
                    v = (kkg > qg) ? -1e30f : v;
                    sfr[c][r] = v;
                    pm[r] = fmaxf(pm[r], v);
                }
            }
        } else {
            #pragma unroll
            for (int c = 0; c < 4; ++c)
                #pragma unroll
                for (int r = 0; r < 4; ++r) pm[r] = fmaxf(pm[r], sfr[c][r]);
        }
        #pragma unroll
        for (int off = 1; off < 16; off <<= 1)
            #pragma unroll
            for (int r = 0; r < 4; ++r) pm[r] = fmaxf(pm[r], __shfl_xor(pm[r], off, 64));
        // defer-max (T13), base-2 units: 8 nats -> 11.5 bits
        bool ok = true;
        #pragma unroll
        for (int r = 0; r < 4; ++r) ok = ok && (pm[r] <= m[r] + 11.5f);
        if (!__all(ok)) {
            #pragma unroll
            for (int r = 0; r < 4; ++r) {
                float mn = fmaxf(m[r], pm[r]);
                float alpha = fexp2(m[r] - mn);
                m[r] = mn;
                lsum[r] *= alpha;
                #pragma unroll
                for (int db = 0; db < 8; ++db) oacc[db][r] *= alpha;
            }
        }
        float rs[4] = {0.f, 0.f, 0.f, 0.f};
        #pragma unroll
        for (int c = 0; c < 4; ++c)
            #pragma unroll
            for (int r = 0; r < 4; ++r) {
                float p = fexp2(sfr[c][r] - m[r]);
                sfr[c][r] = p;
                rs[r] += p;
            }
        #pragma unroll
        for (int off = 1; off < 16; off <<= 1)
            #pragma unroll
            for (int r = 0; r < 4; ++r) rs[r] += __shfl_xor(rs[r], off, 64);
        #pragma unroll
        for (int r = 0; r < 4; ++r) lsum[r] += rs[r];
        short8 pa[2];
        #pragma unroll
        for (int half = 0; half < 2; ++half) {
            #pragma unroll
            for (int c = 0; c < 2; ++c)
                #pragma unroll
                for (int r = 0; r < 4; ++r)
                    Ps[wave][kh * 4 + r][c * 16 + l15] = f2bf(sfr[half * 2 + c][r]);
            pa[half] = *(const short8*)(&Ps[wave][l15][kh * 8]);
        }
        const char* vb = (const char*)Vs[buf];
        __builtin_amdgcn_s_setprio(1);
        #pragma unroll
        for (int db = 0; db < 8; ++db) {
            int vrow = db * 16 + l15;
            #pragma unroll
            for (int f = 0; f < 2; ++f) {
                short8 vf = *(const short8*)(vb + vrow * 128 + ((((f << 2) + kh) ^ (vrow & 7)) << 4));
                oacc[db] = mfma16(pa[f], vf, oacc[db]);
            }
        }
        __builtin_amdgcn_s_setprio(0);
        buf ^= 1;
    }
    #pragma unroll
    for (int db = 0; db < 8; ++db)
        #pragma unroll
        for (int r = 0; r < 4; ++r) {
            int qg = qrow0 + kh * 4 + r;
            float v = oacc[db][r] / lsum[r];
            O[((size_t)(b * SL) + qg) * HS + h * HD + db * 16 + l15] = f2bf(v);
        }
}

extern "C" void kernel_launch(void* const* d_in, const int* in_sizes, int n_in,
                              void* d_out, int out_size, void* d_ws, size_t ws_size,
                              hipStream_t stream)
{
    const float* X  = (const float*)d_in[0];
    const float* Wq = (const float*)d_in[1];
    const float* Wk = (const float*)d_in[2];
    const float* Wv = (const float*)d_in[3];
    const float* Wo = (const float*)d_in[4];
    float* out = (float*)d_out;
    const size_t SLAB = (size_t)NTOK * HS * 2;  // 32 MiB per bf16 slab
    char* ws = (char*)d_ws;
    unsigned short* Xb  = (unsigned short*)(ws + 0 * SLAB);
    unsigned short* Wqt = (unsigned short*)(ws + 1 * SLAB);  // Wqt|Wkt|Wvt contiguous = fused B^T
    unsigned short* Wot = (unsigned short*)(ws + 4 * SLAB);
    unsigned short* QKV = (unsigned short*)(ws + 5 * SLAB);  // 96 MiB: [4096][12288]
    unsigned short* Vtb = Xb;   // alias: Xb dead after fused QKV GEMM
    unsigned short* Ob  = Wqt;  // alias: W*t dead after fused QKV GEMM

    k_convert<<<2048, 256, 0, stream>>>(X, Xb, NTOK * HS / 8);
    k_transpose_w4<<<dim3(128, 128, 4), 256, 0, stream>>>(Wq, Wk, Wv, Wo, Wqt);
    // fused QKV projection: C[4096][12288] = Xb * [Wqt|Wkt|Wvt]^T  (16x48=768 tiles)
    k_gemm256<unsigned short><<<768, 512, 0, stream>>>(Xb, Wqt, QKV, NTOK, 3 * HS, HS);
    k_rope<<<NTOK * NH * 16 / 256, 256, 0, stream>>>(QKV);
    k_transpose_v<<<dim3(SL / 32, HD / 32, BS * NH), 256, 0, stream>>>(QKV, Vtb);
    k_attn<<<dim3(SL / 64, BS * NH), 256, 0, stream>>>(QKV, Vtb, Ob);
    // output projection: out[4096][4096] = Ob * Wot^T  (16x16=256 tiles)
    k_gemm256<float><<<256, 512, 0, stream>>>(Ob, Wot, out, NTOK, HS, HS);
}

// Round 10
// 845.188 us; speedup vs baseline: 1.8337x; 1.0304x over previous
//
#include <hip/hip_runtime.h>
#include <cstdint>
#include <cstddef>

#define SL 2048
#define BS 2
#define NH 32
#define HD 128
#define HS 4096
#define NTOK 4096   // BS*SL
#define LDQ 12288   // fused QKV row stride (3*HS)

typedef __attribute__((ext_vector_type(8))) short short8;
typedef __attribute__((ext_vector_type(4))) float f32x4;
typedef __attribute__((ext_vector_type(4))) unsigned short u16x4;
typedef __attribute__((ext_vector_type(8))) unsigned short u16x8;

static __device__ __forceinline__ unsigned short f2bf(float f) {
    unsigned int u = __builtin_bit_cast(unsigned int, f);
    u = u + 0x7FFFu + ((u >> 16) & 1u);   // RNE
    return (unsigned short)(u >> 16);
}
static __device__ __forceinline__ float bf2f(unsigned short h) {
    unsigned int u = ((unsigned int)h) << 16;
    return __builtin_bit_cast(float, u);
}
static __device__ __forceinline__ float fexp2(float x) {
    return __builtin_amdgcn_exp2f(x);   // v_exp_f32 (base-2)
}

static __device__ __forceinline__ f32x4 mfma16(short8 a, short8 b, f32x4 c) {
    return __builtin_amdgcn_mfma_f32_16x16x32_bf16(a, b, c, 0, 0, 0);
}

static __device__ __forceinline__ void gload_lds16(const void* g, void* dst) {
    __builtin_amdgcn_global_load_lds(
        (const __attribute__((address_space(1))) unsigned int*)g,
        (__attribute__((address_space(3))) unsigned int*)dst,
        16, 0, 0);
}

// ---------------- fp32 -> bf16 convert (X) ----------------
__global__ void k_convert(const float* __restrict__ in, unsigned short* __restrict__ out, int n8) {
    int stride = gridDim.x * blockDim.x;
    for (int i = blockIdx.x * blockDim.x + threadIdx.x; i < n8; i += stride) {
        const f32x4* p = (const f32x4*)in + (size_t)i * 2;
        f32x4 a = p[0], b = p[1];
        u16x8 o;
        o[0] = f2bf(a[0]); o[1] = f2bf(a[1]); o[2] = f2bf(a[2]); o[3] = f2bf(a[3]);
        o[4] = f2bf(b[0]); o[5] = f2bf(b[1]); o[6] = f2bf(b[2]); o[7] = f2bf(b[3]);
        *((u16x8*)out + i) = o;
    }
}

// ---------------- fp32 W[k][n] -> bf16 Wt[n][k], 4 matrices in one launch ----------------
__global__ void k_transpose_w4(const float* __restrict__ w0, const float* __restrict__ w1,
                               const float* __restrict__ w2, const float* __restrict__ w3,
                               unsigned short* __restrict__ wtbase) {
    __shared__ float t[32][33];
    int z = blockIdx.z;
    const float* w = (z == 0) ? w0 : (z == 1) ? w1 : (z == 2) ? w2 : w3;
    unsigned short* wt = wtbase + (size_t)z * HS * HS;
    int r0 = blockIdx.y << 5, c0 = blockIdx.x << 5;
    int tr = threadIdx.x >> 3;
    int tc = (threadIdx.x & 7) << 2;
    f32x4 v = *(const f32x4*)(w + (size_t)(r0 + tr) * HS + c0 + tc);
    t[tr][tc + 0] = v[0]; t[tr][tc + 1] = v[1]; t[tr][tc + 2] = v[2]; t[tr][tc + 3] = v[3];
    __syncthreads();
    u16x4 o;
    o[0] = f2bf(t[tc + 0][tr]); o[1] = f2bf(t[tc + 1][tr]);
    o[2] = f2bf(t[tc + 2][tr]); o[3] = f2bf(t[tc + 3][tr]);
    *(u16x4*)(wt + (size_t)(c0 + tr) * HS + r0 + tc) = o;
}

// =====================================================================
// 256x256 8-phase bf16 GEMM (verified R9; frozen — 1077 TF, conflicts 0)
// =====================================================================
#define REG(b, w) ((b) * 65536 + (w) * 16384)   // w: 0=A0 1=A1 2=B0 3=B1

template <typename OutT>
__global__ __launch_bounds__(512, 2) void k_gemm256(
    const unsigned short* __restrict__ A,
    const unsigned short* __restrict__ Bt,
    OutT* __restrict__ C,
    int M, int N, int K)
{
    __shared__ char lds[131072];
    char* ldsb = lds;
    int tiles_n = N >> 8;
    int bid = blockIdx.x;
    int q8 = gridDim.x >> 3;               // grid % 8 == 0 here
    bid = (bid & 7) * q8 + (bid >> 3);     // XCD-contiguous tile chunks (T1)
    int tm = bid / tiles_n, tn = bid % tiles_n;
    int tid = threadIdx.x, lane = tid & 63, wave = tid >> 6;
    int l15 = lane & 15, kh = lane >> 4;
    int wm = wave >> 2, wn = wave & 3;
    int row0 = tm << 8, col0 = tn << 8;
    f32x4 acc[8][4] = {};

    int sr = tid >> 3;
    int scb = (tid & 7) << 4;
    int scol = (scb ^ ((sr & 7) << 4)) >> 1;
    const unsigned short* Abase0 = A + (size_t)(row0 + sr) * K + scol;
    const unsigned short* Bbase0 = Bt + (size_t)(col0 + sr) * K + scol;

    int rswz = (l15 & 7) << 4;
    int afb = wm * 16384 + l15 * 128 + ((kh * 16) ^ rswz);
    int bfb = 32768 + ((wn >> 1) * 16384) + (((wn & 1) * 64 + l15) * 128) + ((kh * 16) ^ rswz);

    short8 af[4][2], bfr[4][2];

#define STAGE(R, Gp) do { \
    gload_lds16((Gp),                ldsb + (R) + tid * 16); \
    gload_lds16((Gp) + (size_t)64 * K, ldsb + (R) + 8192 + tid * 16); } while (0)

#define READ_A(buf, g) { _Pragma("unroll") for (int mq = 0; mq < 4; ++mq) \
    _Pragma("unroll") for (int ks = 0; ks < 2; ++ks) \
        af[mq][ks] = *(const short8*)(ldsb + (buf) * 65536 + ((afb + (g) * 8192 + mq * 2048) ^ (ks * 64))); }

#define READ_B2(buf, p) { _Pragma("unroll") for (int n = 2*(p); n < 2*(p)+2; ++n) \
    _Pragma("unroll") for (int ks = 0; ks < 2; ++ks) \
        bfr[n][ks] = *(const short8*)(ldsb + (buf) * 65536 + ((bfb + n * 2048) ^ (ks * 64))); }

#define MFMA_Q(g, nh) { _Pragma("unroll") for (int mq = 0; mq < 4; ++mq) \
    _Pragma("unroll") for (int n2 = 0; n2 < 2; ++n2) { \
        acc[(g)*4+mq][(nh)*2+n2] = mfma16(af[mq][0], bfr[(nh)*2+n2][0], acc[(g)*4+mq][(nh)*2+n2]); \
        acc[(g)*4+mq][(nh)*2+n2] = mfma16(af[mq][1], bfr[(nh)*2+n2][1], acc[(g)*4+mq][(nh)*2+n2]); } }

#define LGKM0() do { asm volatile("s_waitcnt lgkmcnt(0)" ::: "memory"); \
                     __builtin_amdgcn_sched_barrier(0); } while (0)
#define LGKM8() asm volatile("s_waitcnt lgkmcnt(8)" ::: "memory")
#define BAR() __builtin_amdgcn_s_barrier()
#define PRIO1() __builtin_amdgcn_s_setprio(1)
#define PRIO0() __builtin_amdgcn_s_setprio(0)

    // prologue: buf0 full tile0 + buf1 {B0,B1} of tile1 (12 loads)
    STAGE(REG(0, 2), Bbase0);
    STAGE(REG(0, 3), Bbase0 + (size_t)128 * K);
    STAGE(REG(0, 0), Abase0);
    STAGE(REG(0, 1), Abase0 + (size_t)128 * K);
    STAGE(REG(1, 2), Bbase0 + 64);
    STAGE(REG(1, 3), Bbase0 + (size_t)128 * K + 64);
    asm volatile("s_waitcnt vmcnt(4)" ::: "memory");
    BAR();

    int nkt = K >> 6;
    int niter = nkt >> 1;
    #pragma unroll 1
    for (int t = 0; t < niter; ++t) {
        int kt1 = 2 * t + 1, kt2 = 2 * t + 2, kt3 = 2 * t + 3;
        bool s2 = kt2 < nkt, s3 = kt3 < nkt;
        // ---- phase 1 (tile 2t, buf0): 12 ds_reads; stage A0(b1,kt1) ----
        READ_B2(0, 0); READ_A(0, 0);
        STAGE(REG(1, 0), Abase0 + (size_t)kt1 * 64);
        LGKM8();
        BAR(); LGKM0();
        PRIO1(); MFMA_Q(0, 0); PRIO0();
        BAR();
        // ---- phase 2: 4 ds_reads; stage A1(b1,kt1) ----
        READ_B2(0, 1);
        STAGE(REG(1, 1), Abase0 + (size_t)128 * K + (size_t)kt1 * 64);
        BAR(); LGKM0();
        PRIO1(); MFMA_Q(0, 1); PRIO0();
        BAR();
        // ---- phase 3: 8 ds_reads; stage B0(b0,kt2) ----
        READ_A(0, 1);
        if (s2) STAGE(REG(0, 2), Bbase0 + (size_t)kt2 * 64);
        BAR(); LGKM0();
        PRIO1(); MFMA_Q(1, 0); PRIO0();
        BAR();
        // ---- phase 4: 0 ds_reads; stage B1(b0,kt2); vmcnt ----
        if (s2) STAGE(REG(0, 3), Bbase0 + (size_t)128 * K + (size_t)kt2 * 64);
        BAR();
        PRIO1(); MFMA_Q(1, 1); PRIO0();
        if (s2) { asm volatile("s_waitcnt vmcnt(4)" ::: "memory"); }
        else    { asm volatile("s_waitcnt vmcnt(0)" ::: "memory"); }
        BAR();
        // ---- phase 5 (tile 2t+1, buf1): 12 ds_reads; stage A0(b0,kt2) ----
        READ_B2(1, 0); READ_A(1, 0);
        if (s2) STAGE(REG(0, 0), Abase0 + (size_t)kt2 * 64);
        LGKM8();
        BAR(); LGKM0();
        PRIO1(); MFMA_Q(0, 0); PRIO0();
        BAR();
        // ---- phase 6: 4 ds_reads; stage A1(b0,kt2) ----
        READ_B2(1, 1);
        if (s2) STAGE(REG(0, 1), Abase0 + (size_t)128 * K + (size_t)kt2 * 64);
        BAR(); LGKM0();
        PRIO1(); MFMA_Q(0, 1); PRIO0();
        BAR();
        // ---- phase 7: 8 ds_reads; stage B0(b1,kt3) ----
        READ_A(1, 1);
        if (s3) STAGE(REG(1, 2), Bbase0 + (size_t)kt3 * 64);
        BAR(); LGKM0();
        PRIO1(); MFMA_Q(1, 0); PRIO0();
        BAR();
        // ---- phase 8: 0 ds_reads; stage B1(b1,kt3); vmcnt ----
        if (s3) STAGE(REG(1, 3), Bbase0 + (size_t)128 * K + (size_t)kt3 * 64);
        BAR();
        PRIO1(); MFMA_Q(1, 1); PRIO0();
        if (s3) { asm volatile("s_waitcnt vmcnt(4)" ::: "memory"); }
        else    { asm volatile("s_waitcnt vmcnt(0)" ::: "memory"); }
        BAR();
    }

    #pragma unroll
    for (int m = 0; m < 8; ++m)
        #pragma unroll
        for (int n = 0; n < 4; ++n)
            #pragma unroll
            for (int rr = 0; rr < 4; ++rr) {
                int row = row0 + wm * 128 + m * 16 + kh * 4 + rr;
                int col = col0 + wn * 64 + n * 16 + l15;
                float v = acc[m][n][rr];
                if constexpr (sizeof(OutT) == 2) C[(size_t)row * N + col] = (OutT)f2bf(v);
                else                             C[(size_t)row * N + col] = v;
            }
#undef STAGE
#undef READ_A
#undef READ_B2
#undef MFMA_Q
#undef LGKM0
#undef LGKM8
#undef BAR
#undef PRIO1
#undef PRIO0
}

// ---------------- RoPE; Q pre-scaled by log2(e)/sqrt(hd) for exp2 softmax ----------------
__global__ void k_rope(unsigned short* __restrict__ QKV) {
    const float SCALE = 0.12751779544166854f;  // (1/sqrt(128)) * log2(e)
    int i = blockIdx.x * blockDim.x + threadIdx.x;
    int q4 = i & 15;
    int head = (i >> 4) & (NH - 1);
    int tok = i >> 9;
    int s = tok & (SL - 1);
    int d0 = q4 << 2;
    size_t base = (size_t)tok * LDQ + head * HD;
    unsigned short* Q = QKV + base;
    unsigned short* K = QKV + base + HS;
    float cs[4], sn[4];
    #pragma unroll
    for (int j = 0; j < 4; j++) {
        float invf = expf(-(float)(d0 + j) * 0.14391156831212787f);  // ln(1e4)/64
        float ang = (float)s * invf;
        sn[j] = sinf(ang); cs[j] = cosf(ang);
    }
    {
        u16x4 lo = *(u16x4*)(Q + d0);
        u16x4 hi = *(u16x4*)(Q + d0 + 64);
        u16x4 nlo, nhi;
        #pragma unroll
        for (int j = 0; j < 4; j++) {
            float x0 = bf2f(lo[j]), x1 = bf2f(hi[j]);
            nlo[j] = f2bf((x0 * cs[j] - x1 * sn[j]) * SCALE);
            nhi[j] = f2bf((x1 * cs[j] + x0 * sn[j]) * SCALE);
        }
        *(u16x4*)(Q + d0) = nlo;
        *(u16x4*)(Q + d0 + 64) = nhi;
    }
    {
        u16x4 lo = *(u16x4*)(K + d0);
        u16x4 hi = *(u16x4*)(K + d0 + 64);
        u16x4 nlo, nhi;
        #pragma unroll
        for (int j = 0; j < 4; j++) {
            float x0 = bf2f(lo[j]), x1 = bf2f(hi[j]);
            nlo[j] = f2bf(x0 * cs[j] - x1 * sn[j]);
            nhi[j] = f2bf(x1 * cs[j] + x0 * sn[j]);
        }
        *(u16x4*)(K + d0) = nlo;
        *(u16x4*)(K + d0 + 64) = nhi;
    }
}

// ---------------- V (from QKV) -> Vt ((b,h), d, s) ----------------
__global__ void k_transpose_v(const unsigned short* __restrict__ QKV, unsigned short* __restrict__ Vt) {
    __shared__ unsigned short t[32][36];
    int bh = blockIdx.z; int b = bh >> 5, h = bh & 31;
    int s0 = blockIdx.x << 5, d0 = blockIdx.y << 5;
    int tr = threadIdx.x >> 3, tc = (threadIdx.x & 7) << 2;
    u16x4 v = *(const u16x4*)(QKV + (size_t)(b * SL + s0 + tr) * LDQ + 2 * HS + h * HD + d0 + tc);
    t[tr][tc + 0] = v[0]; t[tr][tc + 1] = v[1]; t[tr][tc + 2] = v[2]; t[tr][tc + 3] = v[3];
    __syncthreads();
    u16x4 o;
    o[0] = t[tc + 0][tr]; o[1] = t[tc + 1][tr]; o[2] = t[tc + 2][tr]; o[3] = t[tc + 3][tr];
    *(u16x4*)(Vt + ((size_t)(b * NH + h) * HD + d0 + tr) * SL + s0 + tc) = o;
}

// ---------------- causal flash attention v6 ----------------
// 8 waves / 512 threads, QBLK=128 (2 q-subtiles of 64 sharing one K/V stage).
// Per-wave: 16 q-rows (identical register footprint to v5). Staged bytes,
// barriers, and K/V global fetch amortized over 2x the MFMA work; 16 waves/CU
// (58.4 KB LDS -> 2 blocks/CU). Fully-masked (wave,kt) pairs skip compute.
__global__ __launch_bounds__(512, 4) void k_attn(
    const unsigned short* __restrict__ QKV,
    const unsigned short* __restrict__ Vt,
    unsigned short* __restrict__ O)
{
    __shared__ unsigned short Ks[64 * 128];      // [kk][d], chunk-swizzled, 16 KB
    __shared__ unsigned short Vs[2][128 * 64];   // [buf][d][kk], chunk-swizzled, 32 KB
    __shared__ unsigned short Ps[8][16][36];     // per-wave P transpose, 9 KB
    int qt = (int)(gridDim.x - 1) - (int)blockIdx.x;  // big q-tiles first
    int bh = blockIdx.y;
    int b = bh >> 5, h = bh & 31;
    int tid = threadIdx.x, lane = tid & 63, wave = tid >> 6;   // wave 0..7
    int l15 = lane & 15, kh = lane >> 4;
    int qrow0 = (qt << 7) + (wave << 4);
    short8 qf[4];
    {
        const unsigned short* qp = QKV + ((size_t)(b * SL) + qrow0 + l15) * LDQ + h * HD + kh * 8;
        #pragma unroll
        for (int f = 0; f < 4; ++f) qf[f] = *(const short8*)(qp + f * 32);
    }
    f32x4 oacc[8] = {};
    float m[4] = {-1e30f, -1e30f, -1e30f, -1e30f};
    float lsum[4] = {0.f, 0.f, 0.f, 0.f};
    int ksrow = tid >> 4, kchunk = tid & 15;   // K: 2 chunks x 32 rows
    int vsrow = tid >> 3, vchunk = tid & 7;    // V: 2 chunks x 64 rows
    const unsigned short* Kbase = QKV + HS + (size_t)(b * SL) * LDQ + h * HD;
    const unsigned short* Vbase = Vt + (size_t)(b * NH + h) * HD * (size_t)SL;
    int ktmax = (qt << 1) + 1;

    // prologue: stage K(0), V(0) — 512 threads, 2 chunks each
    #pragma unroll
    for (int c = 0; c < 2; ++c) {
        int kr = c * 32 + ksrow;
        gload_lds16(Kbase + (size_t)kr * LDQ + ((kchunk ^ (kr & 7)) << 3),
                    (char*)Ks + c * 8192 + tid * 16);
        int vr = c * 64 + vsrow;
        gload_lds16(Vbase + (size_t)vr * SL + ((vchunk ^ (vr & 7)) << 3),
                    (char*)Vs[0] + c * 8192 + tid * 16);
    }
    int buf = 0;
    for (int kt = 0; kt <= ktmax; ++kt) {
        __syncthreads();   // drains stages issued last iter (vmcnt0 implicit)
        bool active = (kt << 6) <= qrow0 + 15;
        f32x4 sfr[4];
        if (active) {
            __builtin_amdgcn_s_setprio(1);
            #pragma unroll
            for (int c = 0; c < 4; ++c) {
                f32x4 acc = {};
                int krow = c * 16 + l15;
                #pragma unroll
                for (int f = 0; f < 4; ++f) {
                    short8 kf = *(const short8*)((const char*)Ks + krow * 256 + ((((f << 2) + kh) ^ (krow & 7)) << 4));
                    acc = mfma16(qf[f], kf, acc);
                }
                sfr[c] = acc;
            }
            __builtin_amdgcn_s_setprio(0);
        }
        __syncthreads();   // all waves done reading Ks
        if (kt < ktmax) {  // stage next K (over Ks) and next V (other buf)
            #pragma unroll
            for (int c = 0; c < 2; ++c) {
                int kr = c * 32 + ksrow;
                gload_lds16(Kbase + (size_t)(((kt + 1) << 6) + kr) * LDQ + ((kchunk ^ (kr & 7)) << 3),
                            (char*)Ks + c * 8192 + tid * 16);
                int vr = c * 64 + vsrow;
                gload_lds16(Vbase + (size_t)vr * SL + ((kt + 1) << 6) + ((vchunk ^ (vr & 7)) << 3),
                            (char*)Vs[buf ^ 1] + c * 8192 + tid * 16);
            }
        }
        if (active) {
            float pm[4] = {-1e30f, -1e30f, -1e30f, -1e30f};
            bool domask = ((kt << 6) + 63) > qrow0;
            if (domask) {
                #pragma unroll
                for (int c = 0; c < 4; ++c) {
                    int kkg = (kt << 6) + c * 16 + l15;
                    #pragma unroll
                    for (int r = 0; r < 4; ++r) {
                        int qg = qrow0 + kh * 4 + r;
                        float v = sfr[c][r];
                        v = (kkg > qg) ? -1e30f : v;
                        sfr[c][r] = v;
                        pm[r] = fmaxf(pm[r], v);
                    }
                }
            } else {
                #pragma unroll
                for (int c = 0; c < 4; ++c)
                    #pragma unroll
                    for (int r = 0; r < 4; ++r) pm[r] = fmaxf(pm[r], sfr[c][r]);
            }
            #pragma unroll
            for (int off = 1; off < 16; off <<= 1)
                #pragma unroll
                for (int r = 0; r < 4; ++r) pm[r] = fmaxf(pm[r], __shfl_xor(pm[r], off, 64));
            // defer-max (T13), base-2 units
            bool ok = true;
            #pragma unroll
            for (int r = 0; r < 4; ++r) ok = ok && (pm[r] <= m[r] + 11.5f);
            if (!__all(ok)) {
                #pragma unroll
                for (int r = 0; r < 4; ++r) {
                    float mn = fmaxf(m[r], pm[r]);
                    float alpha = fexp2(m[r] - mn);
                    m[r] = mn;
                    lsum[r] *= alpha;
                    #pragma unroll
                    for (int db = 0; db < 8; ++db) oacc[db][r] *= alpha;
                }
            }
            float rs[4] = {0.f, 0.f, 0.f, 0.f};
            #pragma unroll
            for (int c = 0; c < 4; ++c)
                #pragma unroll
                for (int r = 0; r < 4; ++r) {
                    float p = fexp2(sfr[c][r] - m[r]);
                    sfr[c][r] = p;
                    rs[r] += p;
                }
            #pragma unroll
            for (int off = 1; off < 16; off <<= 1)
                #pragma unroll
                for (int r = 0; r < 4; ++r) rs[r] += __shfl_xor(rs[r], off, 64);
            #pragma unroll
            for (int r = 0; r < 4; ++r) lsum[r] += rs[r];
            short8 pa[2];
            #pragma unroll
            for (int half = 0; half < 2; ++half) {
                #pragma unroll
                for (int c = 0; c < 2; ++c)
                    #pragma unroll
                    for (int r = 0; r < 4; ++r)
                        Ps[wave][kh * 4 + r][c * 16 + l15] = f2bf(sfr[half * 2 + c][r]);
                pa[half] = *(const short8*)(&Ps[wave][l15][kh * 8]);
            }
            const char* vb = (const char*)Vs[buf];
            __builtin_amdgcn_s_setprio(1);
            #pragma unroll
            for (int db = 0; db < 8; ++db) {
                int vrow = db * 16 + l15;
                #pragma unroll
                for (int f = 0; f < 2; ++f) {
                    short8 vf = *(const short8*)(vb + vrow * 128 + ((((f << 2) + kh) ^ (vrow & 7)) << 4));
                    oacc[db] = mfma16(pa[f], vf, oacc[db]);
                }
            }
            __builtin_amdgcn_s_setprio(0);
        }
        buf ^= 1;
    }
    #pragma unroll
    for (int db = 0; db < 8; ++db)
        #pragma unroll
        for (int r = 0; r < 4; ++r) {
            int qg = qrow0 + kh * 4 + r;
            float v = oacc[db][r] / lsum[r];
            O[((size_t)(b * SL) + qg) * HS + h * HD + db * 16 + l15] = f2bf(v);
        }
}

extern "C" void kernel_launch(void* const* d_in, const int* in_sizes, int n_in,
                              void* d_out, int out_size, void* d_ws, size_t ws_size,
                              hipStream_t stream)
{
    const float* X  = (const float*)d_in[0];
    const float* Wq = (const float*)d_in[1];
    const float* Wk = (const float*)d_in[2];
    const float* Wv = (const float*)d_in[3];
    const float* Wo = (const float*)d_in[4];
    float* out = (float*)d_out;
    const size_t SLAB = (size_t)NTOK * HS * 2;  // 32 MiB per bf16 slab
    char* ws = (char*)d_ws;
    unsigned short* Xb  = (unsigned short*)(ws + 0 * SLAB);
    unsigned short* Wqt = (unsigned short*)(ws + 1 * SLAB);  // Wqt|Wkt|Wvt contiguous = fused B^T
    unsigned short* Wot = (unsigned short*)(ws + 4 * SLAB);
    unsigned short* QKV = (unsigned short*)(ws + 5 * SLAB);  // 96 MiB: [4096][12288]
    unsigned short* Vtb = Xb;   // alias: Xb dead after fused QKV GEMM
    unsigned short* Ob  = Wqt;  // alias: W*t dead after fused QKV GEMM

    k_convert<<<2048, 256, 0, stream>>>(X, Xb, NTOK * HS / 8);
    k_transpose_w4<<<dim3(128, 128, 4), 256, 0, stream>>>(Wq, Wk, Wv, Wo, Wqt);
    // fused QKV projection: C[4096][12288] = Xb * [Wqt|Wkt|Wvt]^T  (16x48=768 tiles)
    k_gemm256<unsigned short><<<768, 512, 0, stream>>>(Xb, Wqt, QKV, NTOK, 3 * HS, HS);
    k_rope<<<NTOK * NH * 16 / 256, 256, 0, stream>>>(QKV);
    k_transpose_v<<<dim3(SL / 32, HD / 32, BS * NH), 256, 0, stream>>>(QKV, Vtb);
    k_attn<<<dim3(SL / 128, BS * NH), 512, 0, stream>>>(QKV, Vtb, Ob);
    // output projection: out[4096][4096] = Ob * Wot^T  (16x16=256 tiles)
    k_gemm256<float><<<256, 512, 0, stream>>>(Ob, Wot, out, NTOK, HS, HS);
}

// Round 11
// 826.630 us; speedup vs baseline: 1.8748x; 1.0225x over previous
//
#include <hip/hip_runtime.h>
#include <cstdint>
#include <cstddef>

#define SL 2048
#define BS 2
#define NH 32
#define HD 128
#define HS 4096
#define NTOK 4096   // BS*SL
#define LDQ 12288   // fused QKV row stride (3*HS)

typedef __attribute__((ext_vector_type(8))) short short8;
typedef __attribute__((ext_vector_type(4))) float f32x4;
typedef __attribute__((ext_vector_type(4))) unsigned short u16x4;
typedef __attribute__((ext_vector_type(8))) unsigned short u16x8;

static __device__ __forceinline__ unsigned short f2bf(float f) {
    unsigned int u = __builtin_bit_cast(unsigned int, f);
    u = u + 0x7FFFu + ((u >> 16) & 1u);   // RNE
    return (unsigned short)(u >> 16);
}
static __device__ __forceinline__ float bf2f(unsigned short h) {
    unsigned int u = ((unsigned int)h) << 16;
    return __builtin_bit_cast(float, u);
}
static __device__ __forceinline__ float fexp2(float x) {
    return __builtin_amdgcn_exp2f(x);   // v_exp_f32 (base-2)
}

static __device__ __forceinline__ f32x4 mfma16(short8 a, short8 b, f32x4 c) {
    return __builtin_amdgcn_mfma_f32_16x16x32_bf16(a, b, c, 0, 0, 0);
}

static __device__ __forceinline__ void gload_lds16(const void* g, void* dst) {
    __builtin_amdgcn_global_load_lds(
        (const __attribute__((address_space(1))) unsigned int*)g,
        (__attribute__((address_space(3))) unsigned int*)dst,
        16, 0, 0);
}

// ---------------- fp32 -> bf16 convert (X) ----------------
__global__ void k_convert(const float* __restrict__ in, unsigned short* __restrict__ out, int n8) {
    int stride = gridDim.x * blockDim.x;
    for (int i = blockIdx.x * blockDim.x + threadIdx.x; i < n8; i += stride) {
        const f32x4* p = (const f32x4*)in + (size_t)i * 2;
        f32x4 a = p[0], b = p[1];
        u16x8 o;
        o[0] = f2bf(a[0]); o[1] = f2bf(a[1]); o[2] = f2bf(a[2]); o[3] = f2bf(a[3]);
        o[4] = f2bf(b[0]); o[5] = f2bf(b[1]); o[6] = f2bf(b[2]); o[7] = f2bf(b[3]);
        *((u16x8*)out + i) = o;
    }
}

// ---------------- fp32 W[k][n] -> bf16 Wt[n][k], 4 matrices in one launch ----------------
__global__ void k_transpose_w4(const float* __restrict__ w0, const float* __restrict__ w1,
                               const float* __restrict__ w2, const float* __restrict__ w3,
                               unsigned short* __restrict__ wtbase) {
    __shared__ float t[32][33];
    int z = blockIdx.z;
    const float* w = (z == 0) ? w0 : (z == 1) ? w1 : (z == 2) ? w2 : w3;
    unsigned short* wt = wtbase + (size_t)z * HS * HS;
    int r0 = blockIdx.y << 5, c0 = blockIdx.x << 5;
    int tr = threadIdx.x >> 3;
    int tc = (threadIdx.x & 7) << 2;
    f32x4 v = *(const f32x4*)(w + (size_t)(r0 + tr) * HS + c0 + tc);
    t[tr][tc + 0] = v[0]; t[tr][tc + 1] = v[1]; t[tr][tc + 2] = v[2]; t[tr][tc + 3] = v[3];
    __syncthreads();
    u16x4 o;
    o[0] = f2bf(t[tc + 0][tr]); o[1] = f2bf(t[tc + 1][tr]);
    o[2] = f2bf(t[tc + 2][tr]); o[3] = f2bf(t[tc + 3][tr]);
    *(u16x4*)(wt + (size_t)(c0 + tr) * HS + r0 + tc) = o;
}

// =====================================================================
// 256x256 8-phase bf16 GEMM, single barrier per phase (8 bar / 2 K-tiles).
// Interior phase:  [reads; stage; BAR; lgkm0; MFMA]   (reads overlap prior
//   MFMA + barrier wait; WAR safe: stage region last read >=1 phase back,
//   separated by the intervening barrier.)
// Boundary phases ph1/ph5 (buffer switch): [stage; vmcnt(6); BAR; reads;
//   lgkm0; MFMA]  — vmcnt(6) retires exactly the 8 loads of the tile about
//   to be read (14 outstanding at that point); tail -> vmcnt(0).
// Stage positions identical to verified R9 schedule:
//   ph1:A0(b1,2t+1) ph2:A1(b1,2t+1) ph3:B0(b0,2t+2) ph4:B1(b0,2t+2)
//   ph5:A0(b0,2t+2) ph6:A1(b0,2t+2) ph7:B0(b1,2t+3) ph8:B1(b1,2t+3)
// Full row swizzle colbyte ^= (row&7)<<4; conflicts measured 0.
// =====================================================================
#define REG(b, w) ((b) * 65536 + (w) * 16384)   // w: 0=A0 1=A1 2=B0 3=B1

template <typename OutT>
__global__ __launch_bounds__(512, 2) void k_gemm256(
    const unsigned short* __restrict__ A,
    const unsigned short* __restrict__ Bt,
    OutT* __restrict__ C,
    int M, int N, int K)
{
    __shared__ char lds[131072];
    char* ldsb = lds;
    int tiles_n = N >> 8;
    int bid = blockIdx.x;
    int q8 = gridDim.x >> 3;               // grid % 8 == 0 here
    bid = (bid & 7) * q8 + (bid >> 3);     // XCD-contiguous tile chunks (T1)
    int tm = bid / tiles_n, tn = bid % tiles_n;
    int tid = threadIdx.x, lane = tid & 63, wave = tid >> 6;
    int l15 = lane & 15, kh = lane >> 4;
    int wm = wave >> 2, wn = wave & 3;
    int row0 = tm << 8, col0 = tn << 8;
    f32x4 acc[8][4] = {};

    int sr = tid >> 3;
    int scb = (tid & 7) << 4;
    int scol = (scb ^ ((sr & 7) << 4)) >> 1;
    const unsigned short* Abase0 = A + (size_t)(row0 + sr) * K + scol;
    const unsigned short* Bbase0 = Bt + (size_t)(col0 + sr) * K + scol;

    int rswz = (l15 & 7) << 4;
    int afb = wm * 16384 + l15 * 128 + ((kh * 16) ^ rswz);
    int bfb = 32768 + ((wn >> 1) * 16384) + (((wn & 1) * 64 + l15) * 128) + ((kh * 16) ^ rswz);

    short8 af[4][2], bfr[4][2];

#define STAGE(R, Gp) do { \
    gload_lds16((Gp),                ldsb + (R) + tid * 16); \
    gload_lds16((Gp) + (size_t)64 * K, ldsb + (R) + 8192 + tid * 16); } while (0)

#define READ_A(buf, g) { _Pragma("unroll") for (int mq = 0; mq < 4; ++mq) \
    _Pragma("unroll") for (int ks = 0; ks < 2; ++ks) \
        af[mq][ks] = *(const short8*)(ldsb + (buf) * 65536 + ((afb + (g) * 8192 + mq * 2048) ^ (ks * 64))); }

#define READ_B2(buf, p) { _Pragma("unroll") for (int n = 2*(p); n < 2*(p)+2; ++n) \
    _Pragma("unroll") for (int ks = 0; ks < 2; ++ks) \
        bfr[n][ks] = *(const short8*)(ldsb + (buf) * 65536 + ((bfb + n * 2048) ^ (ks * 64))); }

#define MFMA_Q(g, nh) { _Pragma("unroll") for (int mq = 0; mq < 4; ++mq) \
    _Pragma("unroll") for (int n2 = 0; n2 < 2; ++n2) { \
        acc[(g)*4+mq][(nh)*2+n2] = mfma16(af[mq][0], bfr[(nh)*2+n2][0], acc[(g)*4+mq][(nh)*2+n2]); \
        acc[(g)*4+mq][(nh)*2+n2] = mfma16(af[mq][1], bfr[(nh)*2+n2][1], acc[(g)*4+mq][(nh)*2+n2]); } }

#define LGKM0() do { asm volatile("s_waitcnt lgkmcnt(0)" ::: "memory"); \
                     __builtin_amdgcn_sched_barrier(0); } while (0)
#define BAR() __builtin_amdgcn_s_barrier()
#define PRIO1() __builtin_amdgcn_s_setprio(1)
#define PRIO0() __builtin_amdgcn_s_setprio(0)
#define VM6() asm volatile("s_waitcnt vmcnt(6)" ::: "memory")
#define VM0() asm volatile("s_waitcnt vmcnt(0)" ::: "memory")

    // prologue: buf0 full tile0 + buf1 {B0,B1} of tile1 (12 loads, no wait —
    // the loop's ph1 vmcnt(6)+BAR establishes the invariant)
    STAGE(REG(0, 2), Bbase0);
    STAGE(REG(0, 3), Bbase0 + (size_t)128 * K);
    STAGE(REG(0, 0), Abase0);
    STAGE(REG(0, 1), Abase0 + (size_t)128 * K);
    STAGE(REG(1, 2), Bbase0 + 64);
    STAGE(REG(1, 3), Bbase0 + (size_t)128 * K + 64);

    int nkt = K >> 6;
    int niter = nkt >> 1;
    #pragma unroll 1
    for (int t = 0; t < niter; ++t) {
        int kt1 = 2 * t + 1, kt2 = 2 * t + 2, kt3 = 2 * t + 3;
        bool s2 = kt2 < nkt, s3 = kt3 < nkt;
        // ---- ph1 (boundary, buf0): stage A0(b1,kt1); vmcnt; BAR; 12 reads ----
        STAGE(REG(1, 0), Abase0 + (size_t)kt1 * 64);
        VM6();
        BAR();
        READ_B2(0, 0); READ_A(0, 0); LGKM0();
        PRIO1(); MFMA_Q(0, 0); PRIO0();
        // ---- ph2 (interior): 4 reads; stage A1(b1,kt1) ----
        READ_B2(0, 1);
        STAGE(REG(1, 1), Abase0 + (size_t)128 * K + (size_t)kt1 * 64);
        BAR(); LGKM0();
        PRIO1(); MFMA_Q(0, 1); PRIO0();
        // ---- ph3 (interior): 8 reads; stage B0(b0,kt2) ----
        READ_A(0, 1);
        if (s2) STAGE(REG(0, 2), Bbase0 + (size_t)kt2 * 64);
        BAR(); LGKM0();
        PRIO1(); MFMA_Q(1, 0); PRIO0();
        // ---- ph4 (interior): 0 reads; stage B1(b0,kt2) ----
        if (s2) STAGE(REG(0, 3), Bbase0 + (size_t)128 * K + (size_t)kt2 * 64);
        BAR();
        PRIO1(); MFMA_Q(1, 1); PRIO0();
        // ---- ph5 (boundary, buf1): stage A0(b0,kt2); vmcnt; BAR; 12 reads ----
        if (s2) { STAGE(REG(0, 0), Abase0 + (size_t)kt2 * 64); VM6(); }
        else    { VM0(); }
        BAR();
        READ_B2(1, 0); READ_A(1, 0); LGKM0();
        PRIO1(); MFMA_Q(0, 0); PRIO0();
        // ---- ph6 (interior): 4 reads; stage A1(b0,kt2) ----
        READ_B2(1, 1);
        if (s2) STAGE(REG(0, 1), Abase0 + (size_t)128 * K + (size_t)kt2 * 64);
        BAR(); LGKM0();
        PRIO1(); MFMA_Q(0, 1); PRIO0();
        // ---- ph7 (interior): 8 reads; stage B0(b1,kt3) ----
        READ_A(1, 1);
        if (s3) STAGE(REG(1, 2), Bbase0 + (size_t)kt3 * 64);
        BAR(); LGKM0();
        PRIO1(); MFMA_Q(1, 0); PRIO0();
        // ---- ph8 (interior): 0 reads; stage B1(b1,kt3) ----
        if (s3) STAGE(REG(1, 3), Bbase0 + (size_t)128 * K + (size_t)kt3 * 64);
        BAR();
        PRIO1(); MFMA_Q(1, 1); PRIO0();
    }

    #pragma unroll
    for (int m = 0; m < 8; ++m)
        #pragma unroll
        for (int n = 0; n < 4; ++n)
            #pragma unroll
            for (int rr = 0; rr < 4; ++rr) {
                int row = row0 + wm * 128 + m * 16 + kh * 4 + rr;
                int col = col0 + wn * 64 + n * 16 + l15;
                float v = acc[m][n][rr];
                if constexpr (sizeof(OutT) == 2) C[(size_t)row * N + col] = (OutT)f2bf(v);
                else                             C[(size_t)row * N + col] = v;
            }
#undef STAGE
#undef READ_A
#undef READ_B2
#undef MFMA_Q
#undef LGKM0
#undef BAR
#undef PRIO1
#undef PRIO0
#undef VM6
#undef VM0
}

// ---------------- RoPE; Q pre-scaled by log2(e)/sqrt(hd) for exp2 softmax ----------------
__global__ void k_rope(unsigned short* __restrict__ QKV) {
    const float SCALE = 0.12751779544166854f;  // (1/sqrt(128)) * log2(e)
    int i = blockIdx.x * blockDim.x + threadIdx.x;
    int q4 = i & 15;
    int head = (i >> 4) & (NH - 1);
    int tok = i >> 9;
    int s = tok & (SL - 1);
    int d0 = q4 << 2;
    size_t base = (size_t)tok * LDQ + head * HD;
    unsigned short* Q = QKV + base;
    unsigned short* K = QKV + base + HS;
    float cs[4], sn[4];
    #pragma unroll
    for (int j = 0; j < 4; j++) {
        float invf = expf(-(float)(d0 + j) * 0.14391156831212787f);  // ln(1e4)/64
        float ang = (float)s * invf;
        sn[j] = sinf(ang); cs[j] = cosf(ang);
    }
    {
        u16x4 lo = *(u16x4*)(Q + d0);
        u16x4 hi = *(u16x4*)(Q + d0 + 64);
        u16x4 nlo, nhi;
        #pragma unroll
        for (int j = 0; j < 4; j++) {
            float x0 = bf2f(lo[j]), x1 = bf2f(hi[j]);
            nlo[j] = f2bf((x0 * cs[j] - x1 * sn[j]) * SCALE);
            nhi[j] = f2bf((x1 * cs[j] + x0 * sn[j]) * SCALE);
        }
        *(u16x4*)(Q + d0) = nlo;
        *(u16x4*)(Q + d0 + 64) = nhi;
    }
    {
        u16x4 lo = *(u16x4*)(K + d0);
        u16x4 hi = *(u16x4*)(K + d0 + 64);
        u16x4 nlo, nhi;
        #pragma unroll
        for (int j = 0; j < 4; j++) {
            float x0 = bf2f(lo[j]), x1 = bf2f(hi[j]);
            nlo[j] = f2bf(x0 * cs[j] - x1 * sn[j]);
            nhi[j] = f2bf(x1 * cs[j] + x0 * sn[j]);
        }
        *(u16x4*)(K + d0) = nlo;
        *(u16x4*)(K + d0 + 64) = nhi;
    }
}

// ---------------- V (from QKV) -> Vt ((b,h), d, s) ----------------
__global__ void k_transpose_v(const unsigned short* __restrict__ QKV, unsigned short* __restrict__ Vt) {
    __shared__ unsigned short t[32][36];
    int bh = blockIdx.z; int b = bh >> 5, h = bh & 31;
    int s0 = blockIdx.x << 5, d0 = blockIdx.y << 5;
    int tr = threadIdx.x >> 3, tc = (threadIdx.x & 7) << 2;
    u16x4 v = *(const u16x4*)(QKV + (size_t)(b * SL + s0 + tr) * LDQ + 2 * HS + h * HD + d0 + tc);
    t[tr][tc + 0] = v[0]; t[tr][tc + 1] = v[1]; t[tr][tc + 2] = v[2]; t[tr][tc + 3] = v[3];
    __syncthreads();
    u16x4 o;
    o[0] = t[tc + 0][tr]; o[1] = t[tc + 1][tr]; o[2] = t[tc + 2][tr]; o[3] = t[tc + 3][tr];
    *(u16x4*)(Vt + ((size_t)(b * NH + h) * HD + d0 + tr) * SL + s0 + tc) = o;
}

// ---------------- causal flash attention v6 (unchanged from R10) ----------------
__global__ __launch_bounds__(512, 4) void k_attn(
    const unsigned short* __restrict__ QKV,
    const unsigned short* __restrict__ Vt,
    unsigned short* __restrict__ O)
{
    __shared__ unsigned short Ks[64 * 128];      // [kk][d], chunk-swizzled, 16 KB
    __shared__ unsigned short Vs[2][128 * 64];   // [buf][d][kk], chunk-swizzled, 32 KB
    __shared__ unsigned short Ps[8][16][36];     // per-wave P transpose, 9 KB
    int qt = (int)(gridDim.x - 1) - (int)blockIdx.x;  // big q-tiles first
    int bh = blockIdx.y;
    int b = bh >> 5, h = bh & 31;
    int tid = threadIdx.x, lane = tid & 63, wave = tid >> 6;   // wave 0..7
    int l15 = lane & 15, kh = lane >> 4;
    int qrow0 = (qt << 7) + (wave << 4);
    short8 qf[4];
    {
        const unsigned short* qp = QKV + ((size_t)(b * SL) + qrow0 + l15) * LDQ + h * HD + kh * 8;
        #pragma unroll
        for (int f = 0; f < 4; ++f) qf[f] = *(const short8*)(qp + f * 32);
    }
    f32x4 oacc[8] = {};
    float m[4] = {-1e30f, -1e30f, -1e30f, -1e30f};
    float lsum[4] = {0.f, 0.f, 0.f, 0.f};
    int ksrow = tid >> 4, kchunk = tid & 15;   // K: 2 chunks x 32 rows
    int vsrow = tid >> 3, vchunk = tid & 7;    // V: 2 chunks x 64 rows
    const unsigned short* Kbase = QKV + HS + (size_t)(b * SL) * LDQ + h * HD;
    const unsigned short* Vbase = Vt + (size_t)(b * NH + h) * HD * (size_t)SL;
    int ktmax = (qt << 1) + 1;

    #pragma unroll
    for (int c = 0; c < 2; ++c) {
        int kr = c * 32 + ksrow;
        gload_lds16(Kbase + (size_t)kr * LDQ + ((kchunk ^ (kr & 7)) << 3),
                    (char*)Ks + c * 8192 + tid * 16);
        int vr = c * 64 + vsrow;
        gload_lds16(Vbase + (size_t)vr * SL + ((vchunk ^ (vr & 7)) << 3),
                    (char*)Vs[0] + c * 8192 + tid * 16);
    }
    int buf = 0;
    for (int kt = 0; kt <= ktmax; ++kt) {
        __syncthreads();   // drains stages issued last iter (vmcnt0 implicit)
        bool active = (kt << 6) <= qrow0 + 15;
        f32x4 sfr[4];
        if (active) {
            __builtin_amdgcn_s_setprio(1);
            #pragma unroll
            for (int c = 0; c < 4; ++c) {
                f32x4 acc = {};
                int krow = c * 16 + l15;
                #pragma unroll
                for (int f = 0; f < 4; ++f) {
                    short8 kf = *(const short8*)((const char*)Ks + krow * 256 + ((((f << 2) + kh) ^ (krow & 7)) << 4));
                    acc = mfma16(qf[f], kf, acc);
                }
                sfr[c] = acc;
            }
            __builtin_amdgcn_s_setprio(0);
        }
        __syncthreads();   // all waves done reading Ks
        if (kt < ktmax) {  // stage next K (over Ks) and next V (other buf)
            #pragma unroll
            for (int c = 0; c < 2; ++c) {
                int kr = c * 32 + ksrow;
                gload_lds16(Kbase + (size_t)(((kt + 1) << 6) + kr) * LDQ + ((kchunk ^ (kr & 7)) << 3),
                            (char*)Ks + c * 8192 + tid * 16);
                int vr = c * 64 + vsrow;
                gload_lds16(Vbase + (size_t)vr * SL + ((kt + 1) << 6) + ((vchunk ^ (vr & 7)) << 3),
                            (char*)Vs[buf ^ 1] + c * 8192 + tid * 16);
            }
        }
        if (active) {
            float pm[4] = {-1e30f, -1e30f, -1e30f, -1e30f};
            bool domask = ((kt << 6) + 63) > qrow0;
            if (domask) {
                #pragma unroll
                for (int c = 0; c < 4; ++c) {
                    int kkg = (kt << 6) + c * 16 + l15;
                    #pragma unroll
                    for (int r = 0; r < 4; ++r) {
                        int qg = qrow0 + kh * 4 + r;
                        float v = sfr[c][r];
                        v = (kkg > qg) ? -1e30f : v;
                        sfr[c][r] = v;
                        pm[r] = fmaxf(pm[r], v);
                    }
                }
            } else {
                #pragma unroll
                for (int c = 0; c < 4; ++c)
                    #pragma unroll
                    for (int r = 0; r < 4; ++r) pm[r] = fmaxf(pm[r], sfr[c][r]);
            }
            #pragma unroll
            for (int off = 1; off < 16; off <<= 1)
                #pragma unroll
                for (int r = 0; r < 4; ++r) pm[r] = fmaxf(pm[r], __shfl_xor(pm[r], off, 64));
            bool ok = true;
            #pragma unroll
            for (int r = 0; r < 4; ++r) ok = ok && (pm[r] <= m[r] + 11.5f);
            if (!__all(ok)) {
                #pragma unroll
                for (int r = 0; r < 4; ++r) {
                    float mn = fmaxf(m[r], pm[r]);
                    float alpha = fexp2(m[r] - mn);
                    m[r] = mn;
                    lsum[r] *= alpha;
                    #pragma unroll
                    for (int db = 0; db < 8; ++db) oacc[db][r] *= alpha;
                }
            }
            float rs[4] = {0.f, 0.f, 0.f, 0.f};
            #pragma unroll
            for (int c = 0; c < 4; ++c)
                #pragma unroll
                for (int r = 0; r < 4; ++r) {
                    float p = fexp2(sfr[c][r] - m[r]);
                    sfr[c][r] = p;
                    rs[r] += p;
                }
            #pragma unroll
            for (int off = 1; off < 16; off <<= 1)
                #pragma unroll
                for (int r = 0; r < 4; ++r) rs[r] += __shfl_xor(rs[r], off, 64);
            #pragma unroll
            for (int r = 0; r < 4; ++r) lsum[r] += rs[r];
            short8 pa[2];
            #pragma unroll
            for (int half = 0; half < 2; ++half) {
                #pragma unroll
                for (int c = 0; c < 2; ++c)
                    #pragma unroll
                    for (int r = 0; r < 4; ++r)
                        Ps[wave][kh * 4 + r][c * 16 + l15] = f2bf(sfr[half * 2 + c][r]);
                pa[half] = *(const short8*)(&Ps[wave][l15][kh * 8]);
            }
            const char* vb = (const char*)Vs[buf];
            __builtin_amdgcn_s_setprio(1);
            #pragma unroll
            for (int db = 0; db < 8; ++db) {
                int vrow = db * 16 + l15;
                #pragma unroll
                for (int f = 0; f < 2; ++f) {
                    short8 vf = *(const short8*)(vb + vrow * 128 + ((((f << 2) + kh) ^ (vrow & 7)) << 4));
                    oacc[db] = mfma16(pa[f], vf, oacc[db]);
                }
            }
            __builtin_amdgcn_s_setprio(0);
        }
        buf ^= 1;
    }
    #pragma unroll
    for (int db = 0; db < 8; ++db)
        #pragma unroll
        for (int r = 0; r < 4; ++r) {
            int qg = qrow0 + kh * 4 + r;
            float v = oacc[db][r] / lsum[r];
            O[((size_t)(b * SL) + qg) * HS + h * HD + db * 16 + l15] = f2bf(v);
        }
}

extern "C" void kernel_launch(void* const* d_in, const int* in_sizes, int n_in,
                              void* d_out, int out_size, void* d_ws, size_t ws_size,
                              hipStream_t stream)
{
    const float* X  = (const float*)d_in[0];
    const float* Wq = (const float*)d_in[1];
    const float* Wk = (const float*)d_in[2];
    const float* Wv = (const float*)d_in[3];
    const float* Wo = (const float*)d_in[4];
    float* out = (float*)d_out;
    const size_t SLAB = (size_t)NTOK * HS * 2;  // 32 MiB per bf16 slab
    char* ws = (char*)d_ws;
    unsigned short* Xb  = (unsigned short*)(ws + 0 * SLAB);
    unsigned short* Wqt = (unsigned short*)(ws + 1 * SLAB);  // Wqt|Wkt|Wvt contiguous = fused B^T
    unsigned short* Wot = (unsigned short*)(ws + 4 * SLAB);
    unsigned short* QKV = (unsigned short*)(ws + 5 * SLAB);  // 96 MiB: [4096][12288]
    unsigned short* Vtb = Xb;   // alias: Xb dead after fused QKV GEMM
    unsigned short* Ob  = Wqt;  // alias: W*t dead after fused QKV GEMM

    k_convert<<<2048, 256, 0, stream>>>(X, Xb, NTOK * HS / 8);
    k_transpose_w4<<<dim3(128, 128, 4), 256, 0, stream>>>(Wq, Wk, Wv, Wo, Wqt);
    // fused QKV projection: C[4096][12288] = Xb * [Wqt|Wkt|Wvt]^T  (16x48=768 tiles)
    k_gemm256<unsigned short><<<768, 512, 0, stream>>>(Xb, Wqt, QKV, NTOK, 3 * HS, HS);
    k_rope<<<NTOK * NH * 16 / 256, 256, 0, stream>>>(QKV);
    k_transpose_v<<<dim3(SL / 32, HD / 32, BS * NH), 256, 0, stream>>>(QKV, Vtb);
    k_attn<<<dim3(SL / 128, BS * NH), 512, 0, stream>>>(QKV, Vtb, Ob);
    // output projection: out[4096][4096] = Ob * Wot^T  (16x16=256 tiles)
    k_gemm256<float><<<256, 512, 0, stream>>>(Ob, Wot, out, NTOK, HS, HS);
}

// Round 12
// 813.729 us; speedup vs baseline: 1.9046x; 1.0159x over previous
//
#include <hip/hip_runtime.h>
#include <cstdint>
#include <cstddef>

#define SL 2048
#define BS 2
#define NH 32
#define HD 128
#define HS 4096
#define NTOK 4096   // BS*SL
#define LDQ 12288   // fused QKV row stride (3*HS)

typedef __attribute__((ext_vector_type(8))) short short8;
typedef __attribute__((ext_vector_type(4))) float f32x4;
typedef __attribute__((ext_vector_type(4))) unsigned short u16x4;
typedef __attribute__((ext_vector_type(8))) unsigned short u16x8;

static __device__ __forceinline__ unsigned short f2bf(float f) {
    unsigned int u = __builtin_bit_cast(unsigned int, f);
    u = u + 0x7FFFu + ((u >> 16) & 1u);   // RNE
    return (unsigned short)(u >> 16);
}
static __device__ __forceinline__ float bf2f(unsigned short h) {
    unsigned int u = ((unsigned int)h) << 16;
    return __builtin_bit_cast(float, u);
}
static __device__ __forceinline__ float fexp2(float x) {
    return __builtin_amdgcn_exp2f(x);   // v_exp_f32 (base-2)
}

static __device__ __forceinline__ f32x4 mfma16(short8 a, short8 b, f32x4 c) {
    return __builtin_amdgcn_mfma_f32_16x16x32_bf16(a, b, c, 0, 0, 0);
}

static __device__ __forceinline__ void gload_lds16(const void* g, void* dst) {
    __builtin_amdgcn_global_load_lds(
        (const __attribute__((address_space(1))) unsigned int*)g,
        (__attribute__((address_space(3))) unsigned int*)dst,
        16, 0, 0);
}

// ---------------- fp32 -> bf16 convert (X) ----------------
__global__ void k_convert(const float* __restrict__ in, unsigned short* __restrict__ out, int n8) {
    int stride = gridDim.x * blockDim.x;
    for (int i = blockIdx.x * blockDim.x + threadIdx.x; i < n8; i += stride) {
        const f32x4* p = (const f32x4*)in + (size_t)i * 2;
        f32x4 a = p[0], b = p[1];
        u16x8 o;
        o[0] = f2bf(a[0]); o[1] = f2bf(a[1]); o[2] = f2bf(a[2]); o[3] = f2bf(a[3]);
        o[4] = f2bf(b[0]); o[5] = f2bf(b[1]); o[6] = f2bf(b[2]); o[7] = f2bf(b[3]);
        *((u16x8*)out + i) = o;
    }
}

// ---------------- fp32 W[k][n] -> bf16 Wt[n][k], 4 matrices in one launch ----------------
__global__ void k_transpose_w4(const float* __restrict__ w0, const float* __restrict__ w1,
                               const float* __restrict__ w2, const float* __restrict__ w3,
                               unsigned short* __restrict__ wtbase) {
    __shared__ float t[32][33];
    int z = blockIdx.z;
    const float* w = (z == 0) ? w0 : (z == 1) ? w1 : (z == 2) ? w2 : w3;
    unsigned short* wt = wtbase + (size_t)z * HS * HS;
    int r0 = blockIdx.y << 5, c0 = blockIdx.x << 5;
    int tr = threadIdx.x >> 3;
    int tc = (threadIdx.x & 7) << 2;
    f32x4 v = *(const f32x4*)(w + (size_t)(r0 + tr) * HS + c0 + tc);
    t[tr][tc + 0] = v[0]; t[tr][tc + 1] = v[1]; t[tr][tc + 2] = v[2]; t[tr][tc + 3] = v[3];
    __syncthreads();
    u16x4 o;
    o[0] = f2bf(t[tc + 0][tr]); o[1] = f2bf(t[tc + 1][tr]);
    o[2] = f2bf(t[tc + 2][tr]); o[3] = f2bf(t[tc + 3][tr]);
    *(u16x4*)(wt + (size_t)(c0 + tr) * HS + r0 + tc) = o;
}

// =====================================================================
// 256x256 8-phase bf16 GEMM, single barrier per phase (verified R11).
// NEW: near-square per-XCD tile chunks. Tile grid = tiles_m x tiles_n;
// XCD (cr,cc) owns rows [cr*tiles_m/2) x cols [cc*tiles_n/4) — per-XCD
// working set A(tiles_m/2 panels) + B(tiles_n/4 panels), e.g. QKV:
// 8x12 chunk = 16+24 MB vs old 2x48 = 4+96 MB. Cuts HBM fetch ~2.5x.
// Requires tiles_m % 2 == 0, tiles_n % 4 == 0 (holds: 16x48, 16x16).
// =====================================================================
#define REG(b, w) ((b) * 65536 + (w) * 16384)   // w: 0=A0 1=A1 2=B0 3=B1

template <typename OutT>
__global__ __launch_bounds__(512, 2) void k_gemm256(
    const unsigned short* __restrict__ A,
    const unsigned short* __restrict__ Bt,
    OutT* __restrict__ C,
    int M, int N, int K)
{
    __shared__ char lds[131072];
    char* ldsb = lds;
    int tiles_m = M >> 8, tiles_n = N >> 8;
    int xcd = blockIdx.x & 7, idx = blockIdx.x >> 3;   // q8 = grid/8 per XCD
    int rows_per = tiles_m >> 1, cols_per = tiles_n >> 2;
    int cr = xcd >> 2, cc = xcd & 3;
    int tm = cr * rows_per + idx / cols_per;
    int tn = cc * cols_per + idx % cols_per;
    int tid = threadIdx.x, lane = tid & 63, wave = tid >> 6;
    int l15 = lane & 15, kh = lane >> 4;
    int wm = wave >> 2, wn = wave & 3;
    int row0 = tm << 8, col0 = tn << 8;
    f32x4 acc[8][4] = {};

    int sr = tid >> 3;
    int scb = (tid & 7) << 4;
    int scol = (scb ^ ((sr & 7) << 4)) >> 1;
    const unsigned short* Abase0 = A + (size_t)(row0 + sr) * K + scol;
    const unsigned short* Bbase0 = Bt + (size_t)(col0 + sr) * K + scol;

    int rswz = (l15 & 7) << 4;
    int afb = wm * 16384 + l15 * 128 + ((kh * 16) ^ rswz);
    int bfb = 32768 + ((wn >> 1) * 16384) + (((wn & 1) * 64 + l15) * 128) + ((kh * 16) ^ rswz);

    short8 af[4][2], bfr[4][2];

#define STAGE(R, Gp) do { \
    gload_lds16((Gp),                ldsb + (R) + tid * 16); \
    gload_lds16((Gp) + (size_t)64 * K, ldsb + (R) + 8192 + tid * 16); } while (0)

#define READ_A(buf, g) { _Pragma("unroll") for (int mq = 0; mq < 4; ++mq) \
    _Pragma("unroll") for (int ks = 0; ks < 2; ++ks) \
        af[mq][ks] = *(const short8*)(ldsb + (buf) * 65536 + ((afb + (g) * 8192 + mq * 2048) ^ (ks * 64))); }

#define READ_B2(buf, p) { _Pragma("unroll") for (int n = 2*(p); n < 2*(p)+2; ++n) \
    _Pragma("unroll") for (int ks = 0; ks < 2; ++ks) \
        bfr[n][ks] = *(const short8*)(ldsb + (buf) * 65536 + ((bfb + n * 2048) ^ (ks * 64))); }

#define MFMA_Q(g, nh) { _Pragma("unroll") for (int mq = 0; mq < 4; ++mq) \
    _Pragma("unroll") for (int n2 = 0; n2 < 2; ++n2) { \
        acc[(g)*4+mq][(nh)*2+n2] = mfma16(af[mq][0], bfr[(nh)*2+n2][0], acc[(g)*4+mq][(nh)*2+n2]); \
        acc[(g)*4+mq][(nh)*2+n2] = mfma16(af[mq][1], bfr[(nh)*2+n2][1], acc[(g)*4+mq][(nh)*2+n2]); } }

#define LGKM0() do { asm volatile("s_waitcnt lgkmcnt(0)" ::: "memory"); \
                     __builtin_amdgcn_sched_barrier(0); } while (0)
#define BAR() __builtin_amdgcn_s_barrier()
#define PRIO1() __builtin_amdgcn_s_setprio(1)
#define PRIO0() __builtin_amdgcn_s_setprio(0)
#define VM6() asm volatile("s_waitcnt vmcnt(6)" ::: "memory")
#define VM0() asm volatile("s_waitcnt vmcnt(0)" ::: "memory")

    // prologue: buf0 full tile0 + buf1 {B0,B1} of tile1 (12 loads)
    STAGE(REG(0, 2), Bbase0);
    STAGE(REG(0, 3), Bbase0 + (size_t)128 * K);
    STAGE(REG(0, 0), Abase0);
    STAGE(REG(0, 1), Abase0 + (size_t)128 * K);
    STAGE(REG(1, 2), Bbase0 + 64);
    STAGE(REG(1, 3), Bbase0 + (size_t)128 * K + 64);

    int nkt = K >> 6;
    int niter = nkt >> 1;
    #pragma unroll 1
    for (int t = 0; t < niter; ++t) {
        int kt1 = 2 * t + 1, kt2 = 2 * t + 2, kt3 = 2 * t + 3;
        bool s2 = kt2 < nkt, s3 = kt3 < nkt;
        // ---- ph1 (boundary, buf0): stage A0(b1,kt1); vmcnt; BAR; 12 reads ----
        STAGE(REG(1, 0), Abase0 + (size_t)kt1 * 64);
        VM6();
        BAR();
        READ_B2(0, 0); READ_A(0, 0); LGKM0();
        PRIO1(); MFMA_Q(0, 0); PRIO0();
        // ---- ph2 (interior): 4 reads; stage A1(b1,kt1) ----
        READ_B2(0, 1);
        STAGE(REG(1, 1), Abase0 + (size_t)128 * K + (size_t)kt1 * 64);
        BAR(); LGKM0();
        PRIO1(); MFMA_Q(0, 1); PRIO0();
        // ---- ph3 (interior): 8 reads; stage B0(b0,kt2) ----
        READ_A(0, 1);
        if (s2) STAGE(REG(0, 2), Bbase0 + (size_t)kt2 * 64);
        BAR(); LGKM0();
        PRIO1(); MFMA_Q(1, 0); PRIO0();
        // ---- ph4 (interior): 0 reads; stage B1(b0,kt2) ----
        if (s2) STAGE(REG(0, 3), Bbase0 + (size_t)128 * K + (size_t)kt2 * 64);
        BAR();
        PRIO1(); MFMA_Q(1, 1); PRIO0();
        // ---- ph5 (boundary, buf1): stage A0(b0,kt2); vmcnt; BAR; 12 reads ----
        if (s2) { STAGE(REG(0, 0), Abase0 + (size_t)kt2 * 64); VM6(); }
        else    { VM0(); }
        BAR();
        READ_B2(1, 0); READ_A(1, 0); LGKM0();
        PRIO1(); MFMA_Q(0, 0); PRIO0();
        // ---- ph6 (interior): 4 reads; stage A1(b0,kt2) ----
        READ_B2(1, 1);
        if (s2) STAGE(REG(0, 1), Abase0 + (size_t)128 * K + (size_t)kt2 * 64);
        BAR(); LGKM0();
        PRIO1(); MFMA_Q(0, 1); PRIO0();
        // ---- ph7 (interior): 8 reads; stage B0(b1,kt3) ----
        READ_A(1, 1);
        if (s3) STAGE(REG(1, 2), Bbase0 + (size_t)kt3 * 64);
        BAR(); LGKM0();
        PRIO1(); MFMA_Q(1, 0); PRIO0();
        // ---- ph8 (interior): 0 reads; stage B1(b1,kt3) ----
        if (s3) STAGE(REG(1, 3), Bbase0 + (size_t)128 * K + (size_t)kt3 * 64);
        BAR();
        PRIO1(); MFMA_Q(1, 1); PRIO0();
    }

    #pragma unroll
    for (int m = 0; m < 8; ++m)
        #pragma unroll
        for (int n = 0; n < 4; ++n)
            #pragma unroll
            for (int rr = 0; rr < 4; ++rr) {
                int row = row0 + wm * 128 + m * 16 + kh * 4 + rr;
                int col = col0 + wn * 64 + n * 16 + l15;
                float v = acc[m][n][rr];
                if constexpr (sizeof(OutT) == 2) C[(size_t)row * N + col] = (OutT)f2bf(v);
                else                             C[(size_t)row * N + col] = v;
            }
#undef STAGE
#undef READ_A
#undef READ_B2
#undef MFMA_Q
#undef LGKM0
#undef BAR
#undef PRIO1
#undef PRIO0
#undef VM6
#undef VM0
}

// ---------------- fused RoPE (blocks 0..8191) + V transpose (8192..24575) ----------------
__global__ void k_rope_tv(unsigned short* __restrict__ QKV, unsigned short* __restrict__ Vt) {
    __shared__ unsigned short t[32][36];
    if (blockIdx.x < 8192) {
        const float SCALE = 0.12751779544166854f;  // (1/sqrt(128)) * log2(e)
        int i = blockIdx.x * blockDim.x + threadIdx.x;
        int q4 = i & 15;
        int head = (i >> 4) & (NH - 1);
        int tok = i >> 9;
        int s = tok & (SL - 1);
        int d0 = q4 << 2;
        size_t base = (size_t)tok * LDQ + head * HD;
        unsigned short* Q = QKV + base;
        unsigned short* K = QKV + base + HS;
        float cs[4], sn[4];
        #pragma unroll
        for (int j = 0; j < 4; j++) {
            float invf = expf(-(float)(d0 + j) * 0.14391156831212787f);  // ln(1e4)/64
            float ang = (float)s * invf;
            sn[j] = sinf(ang); cs[j] = cosf(ang);
        }
        {
            u16x4 lo = *(u16x4*)(Q + d0);
            u16x4 hi = *(u16x4*)(Q + d0 + 64);
            u16x4 nlo, nhi;
            #pragma unroll
            for (int j = 0; j < 4; j++) {
                float x0 = bf2f(lo[j]), x1 = bf2f(hi[j]);
                nlo[j] = f2bf((x0 * cs[j] - x1 * sn[j]) * SCALE);
                nhi[j] = f2bf((x1 * cs[j] + x0 * sn[j]) * SCALE);
            }
            *(u16x4*)(Q + d0) = nlo;
            *(u16x4*)(Q + d0 + 64) = nhi;
        }
        {
            u16x4 lo = *(u16x4*)(K + d0);
            u16x4 hi = *(u16x4*)(K + d0 + 64);
            u16x4 nlo, nhi;
            #pragma unroll
            for (int j = 0; j < 4; j++) {
                float x0 = bf2f(lo[j]), x1 = bf2f(hi[j]);
                nlo[j] = f2bf(x0 * cs[j] - x1 * sn[j]);
                nhi[j] = f2bf(x1 * cs[j] + x0 * sn[j]);
            }
            *(u16x4*)(K + d0) = nlo;
            *(u16x4*)(K + d0 + 64) = nhi;
        }
    } else {
        int idx = blockIdx.x - 8192;            // 16384 blocks: 64 x 4 x 64
        int bh = idx >> 8;
        int b = bh >> 5, h = bh & 31;
        int s0 = (idx & 63) << 5, d0 = ((idx >> 6) & 3) << 5;
        int tr = threadIdx.x >> 3, tc = (threadIdx.x & 7) << 2;
        u16x4 v = *(const u16x4*)(QKV + (size_t)(b * SL + s0 + tr) * LDQ + 2 * HS + h * HD + d0 + tc);
        t[tr][tc + 0] = v[0]; t[tr][tc + 1] = v[1]; t[tr][tc + 2] = v[2]; t[tr][tc + 3] = v[3];
        __syncthreads();
        u16x4 o;
        o[0] = t[tc + 0][tr]; o[1] = t[tc + 1][tr]; o[2] = t[tc + 2][tr]; o[3] = t[tc + 3][tr];
        *(u16x4*)(Vt + ((size_t)(b * NH + h) * HD + d0 + tr) * SL + s0 + tc) = o;
    }
}

// ---------------- causal flash attention v6 (unchanged from R10/R11) ----------------
__global__ __launch_bounds__(512, 4) void k_attn(
    const unsigned short* __restrict__ QKV,
    const unsigned short* __restrict__ Vt,
    unsigned short* __restrict__ O)
{
    __shared__ unsigned short Ks[64 * 128];      // [kk][d], chunk-swizzled, 16 KB
    __shared__ unsigned short Vs[2][128 * 64];   // [buf][d][kk], chunk-swizzled, 32 KB
    __shared__ unsigned short Ps[8][16][36];     // per-wave P transpose, 9 KB
    int qt = (int)(gridDim.x - 1) - (int)blockIdx.x;  // big q-tiles first
    int bh = blockIdx.y;
    int b = bh >> 5, h = bh & 31;
    int tid = threadIdx.x, lane = tid & 63, wave = tid >> 6;   // wave 0..7
    int l15 = lane & 15, kh = lane >> 4;
    int qrow0 = (qt << 7) + (wave << 4);
    short8 qf[4];
    {
        const unsigned short* qp = QKV + ((size_t)(b * SL) + qrow0 + l15) * LDQ + h * HD + kh * 8;
        #pragma unroll
        for (int f = 0; f < 4; ++f) qf[f] = *(const short8*)(qp + f * 32);
    }
    f32x4 oacc[8] = {};
    float m[4] = {-1e30f, -1e30f, -1e30f, -1e30f};
    float lsum[4] = {0.f, 0.f, 0.f, 0.f};
    int ksrow = tid >> 4, kchunk = tid & 15;   // K: 2 chunks x 32 rows
    int vsrow = tid >> 3, vchunk = tid & 7;    // V: 2 chunks x 64 rows
    const unsigned short* Kbase = QKV + HS + (size_t)(b * SL) * LDQ + h * HD;
    const unsigned short* Vbase = Vt + (size_t)(b * NH + h) * HD * (size_t)SL;
    int ktmax = (qt << 1) + 1;

    #pragma unroll
    for (int c = 0; c < 2; ++c) {
        int kr = c * 32 + ksrow;
        gload_lds16(Kbase + (size_t)kr * LDQ + ((kchunk ^ (kr & 7)) << 3),
                    (char*)Ks + c * 8192 + tid * 16);
        int vr = c * 64 + vsrow;
        gload_lds16(Vbase + (size_t)vr * SL + ((vchunk ^ (vr & 7)) << 3),
                    (char*)Vs[0] + c * 8192 + tid * 16);
    }
    int buf = 0;
    for (int kt = 0; kt <= ktmax; ++kt) {
        __syncthreads();   // drains stages issued last iter (vmcnt0 implicit)
        bool active = (kt << 6) <= qrow0 + 15;
        f32x4 sfr[4];
        if (active) {
            __builtin_amdgcn_s_setprio(1);
            #pragma unroll
            for (int c = 0; c < 4; ++c) {
                f32x4 acc = {};
                int krow = c * 16 + l15;
                #pragma unroll
                for (int f = 0; f < 4; ++f) {
                    short8 kf = *(const short8*)((const char*)Ks + krow * 256 + ((((f << 2) + kh) ^ (krow & 7)) << 4));
                    acc = mfma16(qf[f], kf, acc);
                }
                sfr[c] = acc;
            }
            __builtin_amdgcn_s_setprio(0);
        }
        __syncthreads();   // all waves done reading Ks
        if (kt < ktmax) {  // stage next K (over Ks) and next V (other buf)
            #pragma unroll
            for (int c = 0; c < 2; ++c) {
                int kr = c * 32 + ksrow;
                gload_lds16(Kbase + (size_t)(((kt + 1) << 6) + kr) * LDQ + ((kchunk ^ (kr & 7)) << 3),
                            (char*)Ks + c * 8192 + tid * 16);
                int vr = c * 64 + vsrow;
                gload_lds16(Vbase + (size_t)vr * SL + ((kt + 1) << 6) + ((vchunk ^ (vr & 7)) << 3),
                            (char*)Vs[buf ^ 1] + c * 8192 + tid * 16);
            }
        }
        if (active) {
            float pm[4] = {-1e30f, -1e30f, -1e30f, -1e30f};
            bool domask = ((kt << 6) + 63) > qrow0;
            if (domask) {
                #pragma unroll
                for (int c = 0; c < 4; ++c) {
                    int kkg = (kt << 6) + c * 16 + l15;
                    #pragma unroll
                    for (int r = 0; r < 4; ++r) {
                        int qg = qrow0 + kh * 4 + r;
                        float v = sfr[c][r];
                        v = (kkg > qg) ? -1e30f : v;
                        sfr[c][r] = v;
                        pm[r] = fmaxf(pm[r], v);
                    }
                }
            } else {
                #pragma unroll
                for (int c = 0; c < 4; ++c)
                    #pragma unroll
                    for (int r = 0; r < 4; ++r) pm[r] = fmaxf(pm[r], sfr[c][r]);
            }
            #pragma unroll
            for (int off = 1; off < 16; off <<= 1)
                #pragma unroll
                for (int r = 0; r < 4; ++r) pm[r] = fmaxf(pm[r], __shfl_xor(pm[r], off, 64));
            bool ok = true;
            #pragma unroll
            for (int r = 0; r < 4; ++r) ok = ok && (pm[r] <= m[r] + 11.5f);
            if (!__all(ok)) {
                #pragma unroll
                for (int r = 0; r < 4; ++r) {
                    float mn = fmaxf(m[r], pm[r]);
                    float alpha = fexp2(m[r] - mn);
                    m[r] = mn;
                    lsum[r] *= alpha;
                    #pragma unroll
                    for (int db = 0; db < 8; ++db) oacc[db][r] *= alpha;
                }
            }
            float rs[4] = {0.f, 0.f, 0.f, 0.f};
            #pragma unroll
            for (int c = 0; c < 4; ++c)
                #pragma unroll
                for (int r = 0; r < 4; ++r) {
                    float p = fexp2(sfr[c][r] - m[r]);
                    sfr[c][r] = p;
                    rs[r] += p;
                }
            #pragma unroll
            for (int off = 1; off < 16; off <<= 1)
                #pragma unroll
                for (int r = 0; r < 4; ++r) rs[r] += __shfl_xor(rs[r], off, 64);
            #pragma unroll
            for (int r = 0; r < 4; ++r) lsum[r] += rs[r];
            short8 pa[2];
            #pragma unroll
            for (int half = 0; half < 2; ++half) {
                #pragma unroll
                for (int c = 0; c < 2; ++c)
                    #pragma unroll
                    for (int r = 0; r < 4; ++r)
                        Ps[wave][kh * 4 + r][c * 16 + l15] = f2bf(sfr[half * 2 + c][r]);
                pa[half] = *(const short8*)(&Ps[wave][l15][kh * 8]);
            }
            const char* vb = (const char*)Vs[buf];
            __builtin_amdgcn_s_setprio(1);
            #pragma unroll
            for (int db = 0; db < 8; ++db) {
                int vrow = db * 16 + l15;
                #pragma unroll
                for (int f = 0; f < 2; ++f) {
                    short8 vf = *(const short8*)(vb + vrow * 128 + ((((f << 2) + kh) ^ (vrow & 7)) << 4));
                    oacc[db] = mfma16(pa[f], vf, oacc[db]);
                }
            }
            __builtin_amdgcn_s_setprio(0);
        }
        buf ^= 1;
    }
    #pragma unroll
    for (int db = 0; db < 8; ++db)
        #pragma unroll
        for (int r = 0; r < 4; ++r) {
            int qg = qrow0 + kh * 4 + r;
            float v = oacc[db][r] / lsum[r];
            O[((size_t)(b * SL) + qg) * HS + h * HD + db * 16 + l15] = f2bf(v);
        }
}

extern "C" void kernel_launch(void* const* d_in, const int* in_sizes, int n_in,
                              void* d_out, int out_size, void* d_ws, size_t ws_size,
                              hipStream_t stream)
{
    const float* X  = (const float*)d_in[0];
    const float* Wq = (const float*)d_in[1];
    const float* Wk = (const float*)d_in[2];
    const float* Wv = (const float*)d_in[3];
    const float* Wo = (const float*)d_in[4];
    float* out = (float*)d_out;
    const size_t SLAB = (size_t)NTOK * HS * 2;  // 32 MiB per bf16 slab
    char* ws = (char*)d_ws;
    unsigned short* Xb  = (unsigned short*)(ws + 0 * SLAB);
    unsigned short* Wqt = (unsigned short*)(ws + 1 * SLAB);  // Wqt|Wkt|Wvt contiguous = fused B^T
    unsigned short* Wot = (unsigned short*)(ws + 4 * SLAB);
    unsigned short* QKV = (unsigned short*)(ws + 5 * SLAB);  // 96 MiB: [4096][12288]
    unsigned short* Vtb = Xb;   // alias: Xb dead after fused QKV GEMM
    unsigned short* Ob  = Wqt;  // alias: W*t dead after fused QKV GEMM

    k_convert<<<2048, 256, 0, stream>>>(X, Xb, NTOK * HS / 8);
    k_transpose_w4<<<dim3(128, 128, 4), 256, 0, stream>>>(Wq, Wk, Wv, Wo, Wqt);
    // fused QKV projection: C[4096][12288] = Xb * [Wqt|Wkt|Wvt]^T  (16x48=768 tiles)
    k_gemm256<unsigned short><<<768, 512, 0, stream>>>(Xb, Wqt, QKV, NTOK, 3 * HS, HS);
    // fused RoPE + V transpose (8192 + 16384 blocks)
    k_rope_tv<<<24576, 256, 0, stream>>>(QKV, Vtb);
    k_attn<<<dim3(SL / 128, BS * NH), 512, 0, stream>>>(QKV, Vtb, Ob);
    // output projection: out[4096][4096] = Ob * Wot^T  (16x16=256 tiles)
    k_gemm256<float><<<256, 512, 0, stream>>>(Ob, Wot, out, NTOK, HS, HS);
}